// Round 9
// baseline (353.094 us; speedup 1.0000x reference)
//
#include <hip/hip_runtime.h>
#include <math.h>
#include <stdint.h>

#define NHEADS 16
#define DK 128
#define TSEQ 2048
#define DMODEL 2048

typedef __attribute__((ext_vector_type(8))) short short8;
typedef __attribute__((ext_vector_type(4))) float floatx4;

__device__ __forceinline__ float bf2f(unsigned short h) {
    return __uint_as_float(((unsigned int)h) << 16);
}
__device__ __forceinline__ unsigned short f2bf(float f) {
    unsigned int u = __float_as_uint(f);
    u += 0x7FFFu + ((u >> 16) & 1u);
    return (unsigned short)(u >> 16);
}
__device__ __forceinline__ void async16(unsigned short* lds, const unsigned short* g) {
    __builtin_amdgcn_global_load_lds(
        (const __attribute__((address_space(1))) uint32_t*)g,
        (__attribute__((address_space(3))) uint32_t*)lds, 16, 0, 0);
}

// ===================== merged cast f32 -> bf16 (x, Wqkv, Wo) =====================
#define NX8 1048576
#define NW8 1572864
#define NO8 524288
__global__ __launch_bounds__(256) void cast_all_bf16(
    const float* __restrict__ x, const float* __restrict__ wqkv, const float* __restrict__ wo,
    unsigned short* __restrict__ xb, unsigned short* __restrict__ wqkvb, unsigned short* __restrict__ wob)
{
    const int i = blockIdx.x * 256 + threadIdx.x;
    const float* src; unsigned short* dst; int k;
    if (i < NX8)            { src = x;    dst = xb;    k = i; }
    else if (i < NX8 + NW8) { src = wqkv; dst = wqkvb; k = i - NX8; }
    else                    { src = wo;   dst = wob;   k = i - NX8 - NW8; }
    const float4* p4 = reinterpret_cast<const float4*>(src) + 2 * (size_t)k;
    const float4 a = p4[0], b = p4[1];
    uint32_t w0 = (uint32_t)f2bf(a.x) | ((uint32_t)f2bf(a.y) << 16);
    uint32_t w1 = (uint32_t)f2bf(a.z) | ((uint32_t)f2bf(a.w) << 16);
    uint32_t w2 = (uint32_t)f2bf(b.x) | ((uint32_t)f2bf(b.y) << 16);
    uint32_t w3 = (uint32_t)f2bf(b.z) | ((uint32_t)f2bf(b.w) << 16);
    uint4 o; o.x = w0; o.y = w1; o.z = w2; o.w = w3;
    *reinterpret_cast<uint4*>(dst + 8 * (size_t)k) = o;
}

// ===================== RoPE table =====================
__global__ __launch_bounds__(256) void rope_table_kernel(
    const int* __restrict__ pos, float2* __restrict__ tab)
{
    const int idx = blockIdx.x * 256 + threadIdx.x;   // 2048*64
    const int tt = idx >> 6, i = idx & 63;
    const double inv_freq = exp(-log(10000.0) * (double)i / 64.0);
    const double ang = (double)pos[tt] * inv_freq;
    tab[idx] = make_float2((float)cos(ang), (float)sin(ang));
}

// ===================== fused QKV GEMM, m201-cadence 256x192 =====================
// C = x @ Wqkv^T (4096 x 6144 x 2048). 512 tiles = 2 uniform CU-waves.
// 4 phases/K-tile (m-half x k-chunk), 12 MFMA/phase, 2 barriers/phase,
// staging spread A0@p1 A1@p2 B@p3, boundary wait vmcnt(2) (never 0 mid-loop).
__global__ __launch_bounds__(512, 1) void gemm_qkv_8ph(
    const unsigned short* __restrict__ A, const unsigned short* __restrict__ B,
    unsigned short* __restrict__ qkvb, unsigned short* __restrict__ vt,
    const float2* __restrict__ tab)
{
    const int K = DMODEL, N = 3 * DMODEL;
    __shared__ unsigned short As[2][256 * 64];   // 64 KB
    __shared__ unsigned short Bs[2][192 * 64];   // 48 KB

    const int t = threadIdx.x;
    const int lane = t & 63, w = t >> 6;
    const int wr = w >> 2, wc = w & 3;          // 2M x 4N waves
    const int lr = lane & 15, hi = lane >> 4;

    // XCD col-panel swizzle
    const int bid = (int)blockIdx.x;
    const int xcd = bid & 7, local = bid >> 3;   // local in [0,64)
    const int row0 = (local & 15) * 256;
    const int col0 = ((xcd << 2) | (local >> 4)) * 192;

    const int rr = t >> 3;
    const int cc = ((t & 7) ^ (rr & 7)) << 3;
    const unsigned short* aP = A + (size_t)(row0 + rr) * K + cc;
    const unsigned short* bP = B + (size_t)(col0 + rr) * K + cc;
    const size_t rstep = (size_t)64 * K;

    floatx4 acc[8][3];
#pragma unroll
    for (int m = 0; m < 8; m++)
#pragma unroll
        for (int n = 0; n < 3; n++)
#pragma unroll
            for (int e = 0; e < 4; e++) acc[m][n][e] = 0.f;

#define STAGE_A0(nb, k0n) do { \
        async16(&As[nb][t * 8],          aP + (k0n)); \
        async16(&As[nb][(t + 512) * 8],  aP + rstep + (k0n)); \
    } while (0)
#define STAGE_A1(nb, k0n) do { \
        async16(&As[nb][(t + 1024) * 8], aP + 2 * rstep + (k0n)); \
        async16(&As[nb][(t + 1536) * 8], aP + 3 * rstep + (k0n)); \
    } while (0)
#define STAGE_B3(nb, k0n) do { \
        async16(&Bs[nb][t * 8],          bP + (k0n)); \
        async16(&Bs[nb][(t + 512) * 8],  bP + rstep + (k0n)); \
        async16(&Bs[nb][(t + 1024) * 8], bP + 2 * rstep + (k0n)); \
    } while (0)

    const int NT = K >> 6;   // 32
    const int ch0 = (hi ^ (lr & 7)) * 8;
    const int ch1 = ((4 + hi) ^ (lr & 7)) * 8;

    short8 av[4], bv[3];

#define RD_AV(Ac, mh, ch) do { \
        _Pragma("unroll") \
        for (int m = 0; m < 4; m++) \
            av[m] = *(const short8*)&(Ac)[(wr * 128 + (mh) * 64 + m * 16 + lr) * 64 + (ch)]; \
    } while (0)
#define RD_BV(Bc, ch) do { \
        _Pragma("unroll") \
        for (int n = 0; n < 3; n++) \
            bv[n] = *(const short8*)&(Bc)[(wc * 48 + n * 16 + lr) * 64 + (ch)]; \
    } while (0)
#define MFMA_Q(mh) do { \
        _Pragma("unroll") \
        for (int m = 0; m < 4; m++) \
            _Pragma("unroll") \
            for (int n = 0; n < 3; n++) \
                acc[(mh) * 4 + m][n] = __builtin_amdgcn_mfma_f32_16x16x32_bf16(av[m], bv[n], acc[(mh) * 4 + m][n], 0, 0, 0); \
    } while (0)
#define PH_MFMA(mh) do { \
        asm volatile("s_waitcnt lgkmcnt(0)" ::: "memory"); \
        __builtin_amdgcn_sched_barrier(0); \
        __builtin_amdgcn_s_setprio(1); \
        MFMA_Q(mh); \
        __builtin_amdgcn_s_setprio(0); \
        __builtin_amdgcn_s_barrier(); \
    } while (0)

    // prologue: stage tile 0 fully
    STAGE_A0(0, 0); STAGE_A1(0, 0); STAGE_B3(0, 0);
    asm volatile("s_waitcnt vmcnt(0)" ::: "memory");
    __builtin_amdgcn_s_barrier();

    for (int kt = 0; kt < NT; ++kt) {
        const int cur = kt & 1;
        const unsigned short* __restrict__ Ac = &As[cur][0];
        const unsigned short* __restrict__ Bc = &Bs[cur][0];
        const bool more = (kt + 1 < NT);
        const int nk = (kt + 1) << 6;

        // ---- phase 1 (m0, k0): A0-prefetch, boundary wait ----
        if (more) {
            STAGE_A0(cur ^ 1, nk);
            asm volatile("s_waitcnt vmcnt(2)" ::: "memory");   // prior tile's 7 landed
        } else {
            asm volatile("s_waitcnt vmcnt(0)" ::: "memory");
        }
        __builtin_amdgcn_s_barrier();
        RD_AV(Ac, 0, ch0); RD_BV(Bc, ch0);
        PH_MFMA(0);

        // ---- phase 2 (m1, k0): A1-prefetch ----
        if (more) STAGE_A1(cur ^ 1, nk);
        RD_AV(Ac, 1, ch0);
        __builtin_amdgcn_s_barrier();
        PH_MFMA(1);

        // ---- phase 3 (m0, k1): B-prefetch ----
        if (more) STAGE_B3(cur ^ 1, nk);
        RD_AV(Ac, 0, ch1); RD_BV(Bc, ch1);
        __builtin_amdgcn_s_barrier();
        PH_MFMA(0);

        // ---- phase 4 (m1, k1) ----
        RD_AV(Ac, 1, ch1);
        __builtin_amdgcn_s_barrier();
        PH_MFMA(1);
    }
#undef STAGE_A0
#undef STAGE_A1
#undef STAGE_B3
#undef RD_AV
#undef RD_BV
#undef MFMA_Q
#undef PH_MFMA

    // ---- fused epilogue (D layout: col=lr, row=hi*4+j) ----
    const int par = lr & 1;
#pragma unroll
    for (int mi = 0; mi < 8; mi++) {
        const int row = row0 + wr * 128 + mi * 16 + hi * 4;
        const int tt = row & (TSEQ - 1);
        const int bb = row >> 11;
#pragma unroll
        for (int ni = 0; ni < 3; ni++) {
            const int col = col0 + wc * 48 + ni * 16 + lr;
            if (col < 2 * DMODEL) {
                const int pi = (col & 127) >> 1;
#pragma unroll
                for (int j = 0; j < 4; j++) {
                    const float2 cs = tab[(tt + j) * 64 + pi];
                    const float v = acc[mi][ni][j];
                    const float p = __shfl_xor(v, 1, 64);
                    const float o = par ? (p * cs.y + v * cs.x)
                                        : (v * cs.x - p * cs.y);
                    qkvb[(size_t)(row + j) * N + col] = f2bf(o);
                }
            } else {
                const int vcol = col - 2 * DMODEL;
                const int h = vcol >> 7, d = vcol & 127;
                uint2 pw;
                pw.x = (uint32_t)f2bf(acc[mi][ni][0]) | ((uint32_t)f2bf(acc[mi][ni][1]) << 16);
                pw.y = (uint32_t)f2bf(acc[mi][ni][2]) | ((uint32_t)f2bf(acc[mi][ni][3]) << 16);
                *(uint2*)&vt[(size_t)((bb * NHEADS + h) * DK + d) * TSEQ + tt] = pw;
            }
        }
    }
}

// ===================== output projection, m201-cadence 256x128, f32 out =====================
// C = attn @ Wo^T (4096 x 2048 x 2048). Grid 256 = exactly 1 CU-wave.
__global__ __launch_bounds__(512, 1) void gemm_o_8ph(
    const unsigned short* __restrict__ A, const unsigned short* __restrict__ B,
    float* __restrict__ C)
{
    const int K = DMODEL, N = DMODEL;
    __shared__ unsigned short As[2][256 * 64];   // 64 KB
    __shared__ unsigned short Bs[2][128 * 64];   // 32 KB

    const int t = threadIdx.x;
    const int lane = t & 63, w = t >> 6;
    const int wr = w >> 2, wc = w & 3;
    const int lr = lane & 15, hi = lane >> 4;

    const int bid = (int)blockIdx.x;
    const int xcd = bid & 7, local = bid >> 3;   // local in [0,32)
    const int row0 = (local & 15) * 256;
    const int col0 = ((xcd << 1) | (local >> 4)) * 128;

    const int rr = t >> 3;
    const int cc = ((t & 7) ^ (rr & 7)) << 3;
    const unsigned short* aP = A + (size_t)(row0 + rr) * K + cc;
    const unsigned short* bP = B + (size_t)(col0 + rr) * K + cc;
    const size_t rstep = (size_t)64 * K;

    floatx4 acc[8][2];
#pragma unroll
    for (int m = 0; m < 8; m++)
#pragma unroll
        for (int n = 0; n < 2; n++)
#pragma unroll
            for (int e = 0; e < 4; e++) acc[m][n][e] = 0.f;

#define STAGE_A0(nb, k0n) do { \
        async16(&As[nb][t * 8],          aP + (k0n)); \
        async16(&As[nb][(t + 512) * 8],  aP + rstep + (k0n)); \
    } while (0)
#define STAGE_A1(nb, k0n) do { \
        async16(&As[nb][(t + 1024) * 8], aP + 2 * rstep + (k0n)); \
        async16(&As[nb][(t + 1536) * 8], aP + 3 * rstep + (k0n)); \
    } while (0)
#define STAGE_B2(nb, k0n) do { \
        async16(&Bs[nb][t * 8],          bP + (k0n)); \
        async16(&Bs[nb][(t + 512) * 8],  bP + rstep + (k0n)); \
    } while (0)

    const int NT = K >> 6;   // 32
    const int ch0 = (hi ^ (lr & 7)) * 8;
    const int ch1 = ((4 + hi) ^ (lr & 7)) * 8;

    short8 av[4], bv[2];

#define RD_AV(Ac, mh, ch) do { \
        _Pragma("unroll") \
        for (int m = 0; m < 4; m++) \
            av[m] = *(const short8*)&(Ac)[(wr * 128 + (mh) * 64 + m * 16 + lr) * 64 + (ch)]; \
    } while (0)
#define RD_BV(Bc, ch) do { \
        _Pragma("unroll") \
        for (int n = 0; n < 2; n++) \
            bv[n] = *(const short8*)&(Bc)[(wc * 32 + n * 16 + lr) * 64 + (ch)]; \
    } while (0)
#define MFMA_Q(mh) do { \
        _Pragma("unroll") \
        for (int m = 0; m < 4; m++) \
            _Pragma("unroll") \
            for (int n = 0; n < 2; n++) \
                acc[(mh) * 4 + m][n] = __builtin_amdgcn_mfma_f32_16x16x32_bf16(av[m], bv[n], acc[(mh) * 4 + m][n], 0, 0, 0); \
    } while (0)
#define PH_MFMA(mh) do { \
        asm volatile("s_waitcnt lgkmcnt(0)" ::: "memory"); \
        __builtin_amdgcn_sched_barrier(0); \
        __builtin_amdgcn_s_setprio(1); \
        MFMA_Q(mh); \
        __builtin_amdgcn_s_setprio(0); \
        __builtin_amdgcn_s_barrier(); \
    } while (0)

    STAGE_A0(0, 0); STAGE_A1(0, 0); STAGE_B2(0, 0);
    asm volatile("s_waitcnt vmcnt(0)" ::: "memory");
    __builtin_amdgcn_s_barrier();

    for (int kt = 0; kt < NT; ++kt) {
        const int cur = kt & 1;
        const unsigned short* __restrict__ Ac = &As[cur][0];
        const unsigned short* __restrict__ Bc = &Bs[cur][0];
        const bool more = (kt + 1 < NT);
        const int nk = (kt + 1) << 6;

        // ---- phase 1 (m0, k0) ----
        if (more) {
            STAGE_A0(cur ^ 1, nk);
            asm volatile("s_waitcnt vmcnt(2)" ::: "memory");
        } else {
            asm volatile("s_waitcnt vmcnt(0)" ::: "memory");
        }
        __builtin_amdgcn_s_barrier();
        RD_AV(Ac, 0, ch0); RD_BV(Bc, ch0);
        PH_MFMA(0);

        // ---- phase 2 (m1, k0) ----
        if (more) STAGE_A1(cur ^ 1, nk);
        RD_AV(Ac, 1, ch0);
        __builtin_amdgcn_s_barrier();
        PH_MFMA(1);

        // ---- phase 3 (m0, k1) ----
        if (more) STAGE_B2(cur ^ 1, nk);
        RD_AV(Ac, 0, ch1); RD_BV(Bc, ch1);
        __builtin_amdgcn_s_barrier();
        PH_MFMA(0);

        // ---- phase 4 (m1, k1) ----
        RD_AV(Ac, 1, ch1);
        __builtin_amdgcn_s_barrier();
        PH_MFMA(1);
    }
#undef STAGE_A0
#undef STAGE_A1
#undef STAGE_B2
#undef RD_AV
#undef RD_BV
#undef MFMA_Q
#undef PH_MFMA

    // ---- epilogue: f32 write (D layout: col=lr, row=hi*4+j) ----
#pragma unroll
    for (int mi = 0; mi < 8; mi++) {
        const int row = row0 + wr * 128 + mi * 16 + hi * 4;
#pragma unroll
        for (int ni = 0; ni < 2; ni++) {
            const int col = col0 + wc * 32 + ni * 16 + lr;
#pragma unroll
            for (int j = 0; j < 4; j++)
                C[(size_t)(row + j) * N + col] = acc[mi][ni][j];
        }
    }
}

// ===================== MFMA flash attention (counted-vmcnt barriers) =====================
__global__ __launch_bounds__(256, 2) void attn_mfma2_kernel(
    const unsigned short* __restrict__ qkvb, const unsigned short* __restrict__ vt,
    unsigned short* __restrict__ outb)
{
    __shared__ unsigned short Ks[2][64 * 128];
    __shared__ unsigned short Vs[128 * 64];
    __shared__ unsigned short Ps[4][32 * 64];

    const int t = threadIdx.x;
    const int lane = t & 63, w = t >> 6;
    const int lr = lane & 15, hi = lane >> 4;
    const int bh = blockIdx.y, b = bh >> 4, h = bh & 15;
    const int qc = (int)gridDim.x - 1 - (int)blockIdx.x;
    const int q0 = qc * 128;
    const int q0w = q0 + w * 32;
    const float scale = 0.08838834764831845f;
    const size_t QROW = 3 * DMODEL;

    const unsigned short* kg = qkvb + (size_t)b * TSEQ * QROW + DMODEL + h * DK;
    const unsigned short* vg = vt + (size_t)bh * DK * TSEQ;

    short8 qf[2][4];
    {
        const unsigned short* qbase = qkvb + (size_t)(b * TSEQ + q0w) * QROW + h * DK;
#pragma unroll
        for (int nt = 0; nt < 2; nt++)
#pragma unroll
            for (int ks = 0; ks < 4; ks++) {
                short8 raw = *(const short8*)(qbase + (size_t)(nt * 16 + lr) * QROW + ks * 32 + hi * 8);
                short8 sc;
#pragma unroll
                for (int e = 0; e < 8; e++)
                    sc[e] = (short)f2bf(bf2f((unsigned short)raw[e]) * scale);
                qf[nt][ks] = sc;
            }
    }

    auto stageK = [&](int bufi, int kv0s) {
#pragma unroll
        for (int i = 0; i < 4; i++) {
            const int s = i * 256 + t;
            const int r = s >> 4;
            const int cc = (s & 15) ^ (r & 7);
            async16(&Ks[bufi][s * 8], kg + (size_t)(kv0s + r) * QROW + cc * 8);
        }
    };
    auto stageV = [&](int kv0s) {
#pragma unroll
        for (int i = 0; i < 4; i++) {
            const int s = i * 256 + t;
            const int r = s >> 3;
            const int cc = (s & 7) ^ (r & 7);
            async16(&Vs[s * 8], vg + (size_t)r * TSEQ + kv0s + cc * 8);
        }
    };

    floatx4 accO[2][8];
#pragma unroll
    for (int nt = 0; nt < 2; nt++)
#pragma unroll
        for (int dt = 0; dt < 8; dt++)
#pragma unroll
            for (int e = 0; e < 4; e++) accO[nt][dt][e] = 0.f;
    float mrun[2] = {-1e30f, -1e30f};
    float lrun[2] = {0.f, 0.f};

    const int ntiles = (q0 + 128) / 64;
    int kbuf = 0;

    stageK(0, 0);
    __syncthreads();

    const int pswz = (lr & 7) << 1;

    for (int ti = 0; ti < ntiles; ti++) {
        const int kv0 = ti * 64;
        const bool havK = (ti + 1 < ntiles);
        stageV(kv0);
        if (havK) stageK(kbuf ^ 1, kv0 + 64);

        const bool active = (kv0 <= q0w + 31);
        float al[2] = {1.f, 1.f};

        if (active) {
            floatx4 st[4][2];
#pragma unroll
            for (int mt = 0; mt < 4; mt++)
#pragma unroll
                for (int nt = 0; nt < 2; nt++)
#pragma unroll
                    for (int e = 0; e < 4; e++) st[mt][nt][e] = 0.f;
#pragma unroll
            for (int mt = 0; mt < 4; mt++) {
                const int r = mt * 16 + lr;
#pragma unroll
                for (int ks = 0; ks < 4; ks++) {
                    const int ch = (ks * 4 + hi) ^ (r & 7);
                    const short8 kf = *(const short8*)&Ks[kbuf][(r * 16 + ch) * 8];
                    st[mt][0] = __builtin_amdgcn_mfma_f32_16x16x32_bf16(kf, qf[0][ks], st[mt][0], 0, 0, 0);
                    st[mt][1] = __builtin_amdgcn_mfma_f32_16x16x32_bf16(kf, qf[1][ks], st[mt][1], 0, 0, 0);
                }
            }
            if (kv0 + 63 > q0w) {
#pragma unroll
                for (int nt = 0; nt < 2; nt++) {
                    const int qg = q0w + nt * 16 + lr;
#pragma unroll
                    for (int mt = 0; mt < 4; mt++)
#pragma unroll
                        for (int rg = 0; rg < 4; rg++) {
                            const int kvg = kv0 + mt * 16 + hi * 4 + rg;
                            if (kvg > qg) st[mt][nt][rg] = -1e30f;
                        }
                }
            }
            float pm[2];
#pragma unroll
            for (int nt = 0; nt < 2; nt++) {
                float m = -1e30f;
#pragma unroll
                for (int mt = 0; mt < 4; mt++)
#pragma unroll
                    for (int rg = 0; rg < 4; rg++) m = fmaxf(m, st[mt][nt][rg]);
                m = fmaxf(m, __shfl_xor(m, 16, 64));
                m = fmaxf(m, __shfl_xor(m, 32, 64));
                pm[nt] = m;
            }
            if (__any((pm[0] > mrun[0] + 8.f) || (pm[1] > mrun[1] + 8.f))) {
#pragma unroll
                for (int nt = 0; nt < 2; nt++) {
                    const float mn = fmaxf(mrun[nt], pm[nt]);
                    al[nt] = __expf(mrun[nt] - mn);
                    mrun[nt] = mn;
                }
#pragma unroll
                for (int rg = 0; rg < 4; rg++) {
                    const float a0 = __shfl(al[0], hi * 4 + rg, 64);
                    const float a1 = __shfl(al[1], hi * 4 + rg, 64);
#pragma unroll
                    for (int dt = 0; dt < 8; dt++) {
                        accO[0][dt][rg] *= a0;
                        accO[1][dt][rg] *= a1;
                    }
                }
            }
#pragma unroll
            for (int nt = 0; nt < 2; nt++) {
                float ls = 0.f;
                const int prow = nt * 16 + lr;
#pragma unroll
                for (int mt = 0; mt < 4; mt++) {
                    float pv[4];
#pragma unroll
                    for (int rg = 0; rg < 4; rg++) {
                        pv[rg] = __expf(st[mt][nt][rg] - mrun[nt]);
                        ls += pv[rg];
                    }
                    uint2 pw;
                    pw.x = (uint32_t)f2bf(pv[0]) | ((uint32_t)f2bf(pv[1]) << 16);
                    pw.y = (uint32_t)f2bf(pv[2]) | ((uint32_t)f2bf(pv[3]) << 16);
                    const int chunk = (mt * 4 + hi) ^ pswz;
                    *(uint2*)&Ps[w][prow * 64 + chunk * 4] = pw;
                }
                ls += __shfl_xor(ls, 16, 64);
                ls += __shfl_xor(ls, 32, 64);
                lrun[nt] = lrun[nt] * al[nt] + ls;
            }
        }
        // mid barrier: V must be landed; next-tile K may stay in flight
        if (havK) asm volatile("s_waitcnt vmcnt(4)" ::: "memory");
        else      asm volatile("s_waitcnt vmcnt(0)" ::: "memory");
        __builtin_amdgcn_s_barrier();

        if (active) {
#pragma unroll
            for (int ks2 = 0; ks2 < 2; ks2++) {
                const int ch0 = ((ks2 * 8 + hi * 2) ^ pswz) * 4;
                const short8 pa0 = *(const short8*)&Ps[w][(0 * 16 + lr) * 64 + ch0];
                const short8 pa1 = *(const short8*)&Ps[w][(1 * 16 + lr) * 64 + ch0];
#pragma unroll
                for (int dt = 0; dt < 8; dt++) {
                    const int r = dt * 16 + lr;
                    const int ch = (ks2 * 4 + hi) ^ (r & 7);
                    const short8 vf = *(const short8*)&Vs[(r * 8 + ch) * 8];
                    accO[0][dt] = __builtin_amdgcn_mfma_f32_16x16x32_bf16(pa0, vf, accO[0][dt], 0, 0, 0);
                    accO[1][dt] = __builtin_amdgcn_mfma_f32_16x16x32_bf16(pa1, vf, accO[1][dt], 0, 0, 0);
                }
            }
        }
        // end barrier: next-tile K landed; all waves done reading Vs
        asm volatile("s_waitcnt vmcnt(0)" ::: "memory");
        __builtin_amdgcn_s_barrier();
        kbuf ^= 1;
    }

#pragma unroll
    for (int nt = 0; nt < 2; nt++) {
        const float lv_own = 1.f / lrun[nt];
#pragma unroll
        for (int rg = 0; rg < 4; rg++) {
            const float lv = __shfl(lv_own, hi * 4 + rg, 64);
            unsigned short* orow = outb + (size_t)(b * TSEQ + q0w + nt * 16 + hi * 4 + rg) * DMODEL + h * DK;
#pragma unroll
            for (int dt = 0; dt < 8; dt++)
                orow[dt * 16 + lr] = f2bf(accO[nt][dt][rg] * lv);
        }
    }
}

// ===================== launch =====================
extern "C" void kernel_launch(void* const* d_in, const int* in_sizes, int n_in,
                              void* d_out, int out_size, void* d_ws, size_t ws_size,
                              hipStream_t stream)
{
    const float* x    = (const float*)d_in[0];
    const int*   pos  = (const int*)d_in[1];
    const float* Wqkv = (const float*)d_in[2];
    const float* Wo   = (const float*)d_in[3];
    float* out = (float*)d_out;

    unsigned short* qkvb  = (unsigned short*)d_ws;
    unsigned short* vtb   = qkvb + (size_t)25165824;
    unsigned short* xb    = vtb + (size_t)8388608;
    unsigned short* attnb = xb;                         // alias: xb dead after GEMM1
    unsigned short* wqkvb = xb + (size_t)8388608;
    unsigned short* wob   = wqkvb + (size_t)12582912;
    float2* tab = (float2*)(wob + (size_t)4194304);

    cast_all_bf16<<<12288, 256, 0, stream>>>(x, Wqkv, Wo, xb, wqkvb, wob);
    rope_table_kernel<<<512, 256, 0, stream>>>(pos, tab);

    // fused QKV projection + RoPE + V-transpose (4096 x 6144 x 2048)
    gemm_qkv_8ph<<<dim3(512), 512, 0, stream>>>(xb, wqkvb, qkvb, vtb, tab);

    attn_mfma2_kernel<<<dim3(16, 32), 256, 0, stream>>>(qkvb, vtb, attnb);

    // out = attn @ Wo^T (4096 x 2048 x 2048), grid 256 = 1 CU-wave
    gemm_o_8ph<<<dim3(256), 512, 0, stream>>>(attnb, wob, out);
}

// Round 10
// 266.599 us; speedup vs baseline: 1.3244x; 1.3244x over previous
//
#include <hip/hip_runtime.h>
#include <math.h>
#include <stdint.h>

#define NHEADS 16
#define DK 128
#define TSEQ 2048
#define DMODEL 2048

typedef __attribute__((ext_vector_type(8))) short short8;
typedef __attribute__((ext_vector_type(4))) float floatx4;

__device__ __forceinline__ float bf2f(unsigned short h) {
    return __uint_as_float(((unsigned int)h) << 16);
}
__device__ __forceinline__ unsigned short f2bf(float f) {
    unsigned int u = __float_as_uint(f);
    u += 0x7FFFu + ((u >> 16) & 1u);
    return (unsigned short)(u >> 16);
}
__device__ __forceinline__ void async16(unsigned short* lds, const unsigned short* g) {
    __builtin_amdgcn_global_load_lds(
        (const __attribute__((address_space(1))) uint32_t*)g,
        (__attribute__((address_space(3))) uint32_t*)lds, 16, 0, 0);
}

// ===================== merged cast f32 -> bf16 (x, Wqkv, Wo) =====================
#define NX8 1048576
#define NW8 1572864
#define NO8 524288
__global__ __launch_bounds__(256) void cast_all_bf16(
    const float* __restrict__ x, const float* __restrict__ wqkv, const float* __restrict__ wo,
    unsigned short* __restrict__ xb, unsigned short* __restrict__ wqkvb, unsigned short* __restrict__ wob)
{
    const int i = blockIdx.x * 256 + threadIdx.x;
    const float* src; unsigned short* dst; int k;
    if (i < NX8)            { src = x;    dst = xb;    k = i; }
    else if (i < NX8 + NW8) { src = wqkv; dst = wqkvb; k = i - NX8; }
    else                    { src = wo;   dst = wob;   k = i - NX8 - NW8; }
    const float4* p4 = reinterpret_cast<const float4*>(src) + 2 * (size_t)k;
    const float4 a = p4[0], b = p4[1];
    uint32_t w0 = (uint32_t)f2bf(a.x) | ((uint32_t)f2bf(a.y) << 16);
    uint32_t w1 = (uint32_t)f2bf(a.z) | ((uint32_t)f2bf(a.w) << 16);
    uint32_t w2 = (uint32_t)f2bf(b.x) | ((uint32_t)f2bf(b.y) << 16);
    uint32_t w3 = (uint32_t)f2bf(b.z) | ((uint32_t)f2bf(b.w) << 16);
    uint4 o; o.x = w0; o.y = w1; o.z = w2; o.w = w3;
    *reinterpret_cast<uint4*>(dst + 8 * (size_t)k) = o;
}

// ===================== RoPE table =====================
__global__ __launch_bounds__(256) void rope_table_kernel(
    const int* __restrict__ pos, float2* __restrict__ tab)
{
    const int idx = blockIdx.x * 256 + threadIdx.x;   // 2048*64
    const int tt = idx >> 6, i = idx & 63;
    const double inv_freq = exp(-log(10000.0) * (double)i / 64.0);
    const double ang = (double)pos[tt] * inv_freq;
    tab[idx] = make_float2((float)cos(ang), (float)sin(ang));
}

// ===================== fused QKV GEMM, 128x192 x 2-blocks/CU =====================
// C = x @ Wqkv^T (4096 x 6144 x 2048). 1024 tiles = 2 dispatch waves at 2 blocks/CU.
// 256 thr = 4 waves (2M x 2N), per-wave 64x96 (acc[4][6]). BK=64, LDS 80KB dbuf.
// Independent co-resident blocks provide MFMA<->LDS pipe overlap (m114 mechanism).
__global__ __launch_bounds__(256, 2) void gemm_qkv_x(
    const unsigned short* __restrict__ A, const unsigned short* __restrict__ B,
    unsigned short* __restrict__ qkvb, unsigned short* __restrict__ vt,
    const float2* __restrict__ tab)
{
    const int K = DMODEL, N = 3 * DMODEL;
    __shared__ unsigned short As[2][128 * 64];   // 32 KB
    __shared__ unsigned short Bs[2][192 * 64];   // 48 KB

    const int t = threadIdx.x;
    const int lane = t & 63, w = t >> 6;
    const int wr = w >> 1, wc = w & 1;          // 2M x 2N waves
    const int lr = lane & 15, hi = lane >> 4;

    // XCD col-panel swizzle: xcd owns 4 contiguous 192-col panels
    const int bid = (int)blockIdx.x;
    const int xcd = bid & 7, local = bid >> 3;   // local in [0,128)
    const int row0 = (local & 31) * 128;
    const int col0 = ((xcd << 2) | (local >> 5)) * 192;

    // staging: rows rr+32i; source pre-swizzled (chunk ^= row&7), LDS dest linear
    const int rr = t >> 3;
    const int cc = ((t & 7) ^ (rr & 7)) << 3;
    const unsigned short* aP = A + (size_t)(row0 + rr) * K + cc;
    const unsigned short* bP = B + (size_t)(col0 + rr) * K + cc;
    const size_t rstep = (size_t)32 * K;

    floatx4 acc[4][6];
#pragma unroll
    for (int m = 0; m < 4; m++)
#pragma unroll
        for (int n = 0; n < 6; n++)
#pragma unroll
            for (int e = 0; e < 4; e++) acc[m][n][e] = 0.f;

#define STAGE(nb, k0n) do { \
        async16(&As[nb][t * 8],          aP + (k0n)); \
        async16(&As[nb][(t + 256) * 8],  aP + rstep + (k0n)); \
        async16(&As[nb][(t + 512) * 8],  aP + 2 * rstep + (k0n)); \
        async16(&As[nb][(t + 768) * 8],  aP + 3 * rstep + (k0n)); \
        async16(&Bs[nb][t * 8],          bP + (k0n)); \
        async16(&Bs[nb][(t + 256) * 8],  bP + rstep + (k0n)); \
        async16(&Bs[nb][(t + 512) * 8],  bP + 2 * rstep + (k0n)); \
        async16(&Bs[nb][(t + 768) * 8],  bP + 3 * rstep + (k0n)); \
        async16(&Bs[nb][(t + 1024) * 8], bP + 4 * rstep + (k0n)); \
        async16(&Bs[nb][(t + 1280) * 8], bP + 5 * rstep + (k0n)); \
    } while (0)

    const int NT = K >> 6;   // 32
    const int ch0 = (hi ^ (lr & 7)) * 8;         // k-chunk 0
    const int ch1 = ((4 + hi) ^ (lr & 7)) * 8;   // k-chunk 1

    short8 av[4], bv[6];

#define RD_AV(Ac, ch) do { \
        _Pragma("unroll") \
        for (int m = 0; m < 4; m++) \
            av[m] = *(const short8*)&(Ac)[(wr * 64 + m * 16 + lr) * 64 + (ch)]; \
    } while (0)
#define RD_BV(Bc, ch) do { \
        _Pragma("unroll") \
        for (int n = 0; n < 6; n++) \
            bv[n] = *(const short8*)&(Bc)[(wc * 96 + n * 16 + lr) * 64 + (ch)]; \
    } while (0)
#define MFMA_ALL() do { \
        _Pragma("unroll") \
        for (int m = 0; m < 4; m++) \
            _Pragma("unroll") \
            for (int n = 0; n < 6; n++) \
                acc[m][n] = __builtin_amdgcn_mfma_f32_16x16x32_bf16(av[m], bv[n], acc[m][n], 0, 0, 0); \
    } while (0)

    STAGE(0, 0);

    for (int kt = 0; kt < NT; ++kt) {
        const int cur = kt & 1;
        const unsigned short* __restrict__ Ac = &As[cur][0];
        const unsigned short* __restrict__ Bc = &Bs[cur][0];
        const bool more = (kt + 1 < NT);

        if (more) {
            STAGE(cur ^ 1, (kt + 1) << 6);
            asm volatile("s_waitcnt vmcnt(10)" ::: "memory");   // prior tile's 10 landed
        } else {
            asm volatile("s_waitcnt vmcnt(0)" ::: "memory");
        }
        __builtin_amdgcn_s_barrier();

        // k-chunk 0
        RD_AV(Ac, ch0); RD_BV(Bc, ch0);
        asm volatile("s_waitcnt lgkmcnt(0)" ::: "memory");
        __builtin_amdgcn_sched_barrier(0);
        __builtin_amdgcn_s_setprio(1);
        MFMA_ALL();
        __builtin_amdgcn_s_setprio(0);

        // k-chunk 1
        RD_AV(Ac, ch1); RD_BV(Bc, ch1);
        asm volatile("s_waitcnt lgkmcnt(0)" ::: "memory");
        __builtin_amdgcn_sched_barrier(0);
        __builtin_amdgcn_s_setprio(1);
        MFMA_ALL();
        __builtin_amdgcn_s_setprio(0);

        __builtin_amdgcn_s_barrier();   // all reads of buf[cur] done -> next iter may overwrite
    }
#undef STAGE
#undef RD_AV
#undef RD_BV
#undef MFMA_ALL

    // ---- fused epilogue (D layout: col=lr, row=hi*4+j) ----
    const int par = lr & 1;
#pragma unroll
    for (int mi = 0; mi < 4; mi++) {
        const int row = row0 + wr * 64 + mi * 16 + hi * 4;
        const int tt = row & (TSEQ - 1);
        const int bb = row >> 11;
#pragma unroll
        for (int ni = 0; ni < 6; ni++) {
            const int col = col0 + wc * 96 + ni * 16 + lr;
            if (col < 2 * DMODEL) {
                // q/k: RoPE in f32 via adjacent-lane exchange
                const int pi = (col & 127) >> 1;
#pragma unroll
                for (int j = 0; j < 4; j++) {
                    const float2 cs = tab[(tt + j) * 64 + pi];
                    const float v = acc[mi][ni][j];
                    const float p = __shfl_xor(v, 1, 64);
                    const float o = par ? (p * cs.y + v * cs.x)
                                        : (v * cs.x - p * cs.y);
                    qkvb[(size_t)(row + j) * N + col] = f2bf(o);
                }
            } else {
                // v: transposed packed write -> vt[bh][d][token]
                const int vcol = col - 2 * DMODEL;
                const int h = vcol >> 7, d = vcol & 127;
                uint2 pw;
                pw.x = (uint32_t)f2bf(acc[mi][ni][0]) | ((uint32_t)f2bf(acc[mi][ni][1]) << 16);
                pw.y = (uint32_t)f2bf(acc[mi][ni][2]) | ((uint32_t)f2bf(acc[mi][ni][3]) << 16);
                *(uint2*)&vt[(size_t)((bb * NHEADS + h) * DK + d) * TSEQ + tt] = pw;
            }
        }
    }
}

// ===================== output projection, 128x128 x 2-blocks/CU, f32 out =====================
// C = attn @ Wo^T (4096 x 2048 x 2048). 512 tiles = 2 dispatch waves at 2/CU.
__global__ __launch_bounds__(256, 2) void gemm_o_x(
    const unsigned short* __restrict__ A, const unsigned short* __restrict__ B,
    float* __restrict__ C)
{
    const int K = DMODEL, N = DMODEL;
    __shared__ unsigned short As[2][128 * 64];   // 32 KB
    __shared__ unsigned short Bs[2][128 * 64];   // 32 KB

    const int t = threadIdx.x;
    const int lane = t & 63, w = t >> 6;
    const int wr = w >> 1, wc = w & 1;
    const int lr = lane & 15, hi = lane >> 4;

    const int bid = (int)blockIdx.x;
    const int xcd = bid & 7, local = bid >> 3;   // local in [0,64)
    const int row0 = (local & 31) * 128;
    const int col0 = ((xcd << 1) | (local >> 5)) * 128;

    const int rr = t >> 3;
    const int cc = ((t & 7) ^ (rr & 7)) << 3;
    const unsigned short* aP = A + (size_t)(row0 + rr) * K + cc;
    const unsigned short* bP = B + (size_t)(col0 + rr) * K + cc;
    const size_t rstep = (size_t)32 * K;

    floatx4 acc[4][4];
#pragma unroll
    for (int m = 0; m < 4; m++)
#pragma unroll
        for (int n = 0; n < 4; n++)
#pragma unroll
            for (int e = 0; e < 4; e++) acc[m][n][e] = 0.f;

#define STAGE(nb, k0n) do { \
        async16(&As[nb][t * 8],          aP + (k0n)); \
        async16(&As[nb][(t + 256) * 8],  aP + rstep + (k0n)); \
        async16(&As[nb][(t + 512) * 8],  aP + 2 * rstep + (k0n)); \
        async16(&As[nb][(t + 768) * 8],  aP + 3 * rstep + (k0n)); \
        async16(&Bs[nb][t * 8],          bP + (k0n)); \
        async16(&Bs[nb][(t + 256) * 8],  bP + rstep + (k0n)); \
        async16(&Bs[nb][(t + 512) * 8],  bP + 2 * rstep + (k0n)); \
        async16(&Bs[nb][(t + 768) * 8],  bP + 3 * rstep + (k0n)); \
    } while (0)

    const int NT = K >> 6;   // 32
    const int ch0 = (hi ^ (lr & 7)) * 8;
    const int ch1 = ((4 + hi) ^ (lr & 7)) * 8;

    short8 av[4], bv[4];

#define RD_AV(Ac, ch) do { \
        _Pragma("unroll") \
        for (int m = 0; m < 4; m++) \
            av[m] = *(const short8*)&(Ac)[(wr * 64 + m * 16 + lr) * 64 + (ch)]; \
    } while (0)
#define RD_BV(Bc, ch) do { \
        _Pragma("unroll") \
        for (int n = 0; n < 4; n++) \
            bv[n] = *(const short8*)&(Bc)[(wc * 64 + n * 16 + lr) * 64 + (ch)]; \
    } while (0)
#define MFMA_ALL() do { \
        _Pragma("unroll") \
        for (int m = 0; m < 4; m++) \
            _Pragma("unroll") \
            for (int n = 0; n < 4; n++) \
                acc[m][n] = __builtin_amdgcn_mfma_f32_16x16x32_bf16(av[m], bv[n], acc[m][n], 0, 0, 0); \
    } while (0)

    STAGE(0, 0);

    for (int kt = 0; kt < NT; ++kt) {
        const int cur = kt & 1;
        const unsigned short* __restrict__ Ac = &As[cur][0];
        const unsigned short* __restrict__ Bc = &Bs[cur][0];
        const bool more = (kt + 1 < NT);

        if (more) {
            STAGE(cur ^ 1, (kt + 1) << 6);
            asm volatile("s_waitcnt vmcnt(8)" ::: "memory");
        } else {
            asm volatile("s_waitcnt vmcnt(0)" ::: "memory");
        }
        __builtin_amdgcn_s_barrier();

        RD_AV(Ac, ch0); RD_BV(Bc, ch0);
        asm volatile("s_waitcnt lgkmcnt(0)" ::: "memory");
        __builtin_amdgcn_sched_barrier(0);
        __builtin_amdgcn_s_setprio(1);
        MFMA_ALL();
        __builtin_amdgcn_s_setprio(0);

        RD_AV(Ac, ch1); RD_BV(Bc, ch1);
        asm volatile("s_waitcnt lgkmcnt(0)" ::: "memory");
        __builtin_amdgcn_sched_barrier(0);
        __builtin_amdgcn_s_setprio(1);
        MFMA_ALL();
        __builtin_amdgcn_s_setprio(0);

        __builtin_amdgcn_s_barrier();
    }
#undef STAGE
#undef RD_AV
#undef RD_BV
#undef MFMA_ALL

    // ---- epilogue: f32 write (D layout: col=lr, row=hi*4+j) ----
#pragma unroll
    for (int mi = 0; mi < 4; mi++) {
        const int row = row0 + wr * 64 + mi * 16 + hi * 4;
#pragma unroll
        for (int ni = 0; ni < 4; ni++) {
            const int col = col0 + wc * 64 + ni * 16 + lr;
#pragma unroll
            for (int j = 0; j < 4; j++)
                C[(size_t)(row + j) * N + col] = acc[mi][ni][j];
        }
    }
}

// ===================== MFMA flash attention (counted-vmcnt barriers) =====================
__global__ __launch_bounds__(256, 2) void attn_mfma2_kernel(
    const unsigned short* __restrict__ qkvb, const unsigned short* __restrict__ vt,
    unsigned short* __restrict__ outb)
{
    __shared__ unsigned short Ks[2][64 * 128];
    __shared__ unsigned short Vs[128 * 64];
    __shared__ unsigned short Ps[4][32 * 64];

    const int t = threadIdx.x;
    const int lane = t & 63, w = t >> 6;
    const int lr = lane & 15, hi = lane >> 4;
    const int bh = blockIdx.y, b = bh >> 4, h = bh & 15;
    const int qc = (int)gridDim.x - 1 - (int)blockIdx.x;
    const int q0 = qc * 128;
    const int q0w = q0 + w * 32;
    const float scale = 0.08838834764831845f;
    const size_t QROW = 3 * DMODEL;

    const unsigned short* kg = qkvb + (size_t)b * TSEQ * QROW + DMODEL + h * DK;
    const unsigned short* vg = vt + (size_t)bh * DK * TSEQ;

    short8 qf[2][4];
    {
        const unsigned short* qbase = qkvb + (size_t)(b * TSEQ + q0w) * QROW + h * DK;
#pragma unroll
        for (int nt = 0; nt < 2; nt++)
#pragma unroll
            for (int ks = 0; ks < 4; ks++) {
                short8 raw = *(const short8*)(qbase + (size_t)(nt * 16 + lr) * QROW + ks * 32 + hi * 8);
                short8 sc;
#pragma unroll
                for (int e = 0; e < 8; e++)
                    sc[e] = (short)f2bf(bf2f((unsigned short)raw[e]) * scale);
                qf[nt][ks] = sc;
            }
    }

    auto stageK = [&](int bufi, int kv0s) {
#pragma unroll
        for (int i = 0; i < 4; i++) {
            const int s = i * 256 + t;
            const int r = s >> 4;
            const int cc = (s & 15) ^ (r & 7);
            async16(&Ks[bufi][s * 8], kg + (size_t)(kv0s + r) * QROW + cc * 8);
        }
    };
    auto stageV = [&](int kv0s) {
#pragma unroll
        for (int i = 0; i < 4; i++) {
            const int s = i * 256 + t;
            const int r = s >> 3;
            const int cc = (s & 7) ^ (r & 7);
            async16(&Vs[s * 8], vg + (size_t)r * TSEQ + kv0s + cc * 8);
        }
    };

    floatx4 accO[2][8];
#pragma unroll
    for (int nt = 0; nt < 2; nt++)
#pragma unroll
        for (int dt = 0; dt < 8; dt++)
#pragma unroll
            for (int e = 0; e < 4; e++) accO[nt][dt][e] = 0.f;
    float mrun[2] = {-1e30f, -1e30f};
    float lrun[2] = {0.f, 0.f};

    const int ntiles = (q0 + 128) / 64;
    int kbuf = 0;

    stageK(0, 0);
    __syncthreads();

    const int pswz = (lr & 7) << 1;

    for (int ti = 0; ti < ntiles; ti++) {
        const int kv0 = ti * 64;
        const bool havK = (ti + 1 < ntiles);
        stageV(kv0);
        if (havK) stageK(kbuf ^ 1, kv0 + 64);

        const bool active = (kv0 <= q0w + 31);
        float al[2] = {1.f, 1.f};

        if (active) {
            floatx4 st[4][2];
#pragma unroll
            for (int mt = 0; mt < 4; mt++)
#pragma unroll
                for (int nt = 0; nt < 2; nt++)
#pragma unroll
                    for (int e = 0; e < 4; e++) st[mt][nt][e] = 0.f;
#pragma unroll
            for (int mt = 0; mt < 4; mt++) {
                const int r = mt * 16 + lr;
#pragma unroll
                for (int ks = 0; ks < 4; ks++) {
                    const int ch = (ks * 4 + hi) ^ (r & 7);
                    const short8 kf = *(const short8*)&Ks[kbuf][(r * 16 + ch) * 8];
                    st[mt][0] = __builtin_amdgcn_mfma_f32_16x16x32_bf16(kf, qf[0][ks], st[mt][0], 0, 0, 0);
                    st[mt][1] = __builtin_amdgcn_mfma_f32_16x16x32_bf16(kf, qf[1][ks], st[mt][1], 0, 0, 0);
                }
            }
            if (kv0 + 63 > q0w) {
#pragma unroll
                for (int nt = 0; nt < 2; nt++) {
                    const int qg = q0w + nt * 16 + lr;
#pragma unroll
                    for (int mt = 0; mt < 4; mt++)
#pragma unroll
                        for (int rg = 0; rg < 4; rg++) {
                            const int kvg = kv0 + mt * 16 + hi * 4 + rg;
                            if (kvg > qg) st[mt][nt][rg] = -1e30f;
                        }
                }
            }
            float pm[2];
#pragma unroll
            for (int nt = 0; nt < 2; nt++) {
                float m = -1e30f;
#pragma unroll
                for (int mt = 0; mt < 4; mt++)
#pragma unroll
                    for (int rg = 0; rg < 4; rg++) m = fmaxf(m, st[mt][nt][rg]);
                m = fmaxf(m, __shfl_xor(m, 16, 64));
                m = fmaxf(m, __shfl_xor(m, 32, 64));
                pm[nt] = m;
            }
            if (__any((pm[0] > mrun[0] + 8.f) || (pm[1] > mrun[1] + 8.f))) {
#pragma unroll
                for (int nt = 0; nt < 2; nt++) {
                    const float mn = fmaxf(mrun[nt], pm[nt]);
                    al[nt] = __expf(mrun[nt] - mn);
                    mrun[nt] = mn;
                }
#pragma unroll
                for (int rg = 0; rg < 4; rg++) {
                    const float a0 = __shfl(al[0], hi * 4 + rg, 64);
                    const float a1 = __shfl(al[1], hi * 4 + rg, 64);
#pragma unroll
                    for (int dt = 0; dt < 8; dt++) {
                        accO[0][dt][rg] *= a0;
                        accO[1][dt][rg] *= a1;
                    }
                }
            }
#pragma unroll
            for (int nt = 0; nt < 2; nt++) {
                float ls = 0.f;
                const int prow = nt * 16 + lr;
#pragma unroll
                for (int mt = 0; mt < 4; mt++) {
                    float pv[4];
#pragma unroll
                    for (int rg = 0; rg < 4; rg++) {
                        pv[rg] = __expf(st[mt][nt][rg] - mrun[nt]);
                        ls += pv[rg];
                    }
                    uint2 pw;
                    pw.x = (uint32_t)f2bf(pv[0]) | ((uint32_t)f2bf(pv[1]) << 16);
                    pw.y = (uint32_t)f2bf(pv[2]) | ((uint32_t)f2bf(pv[3]) << 16);
                    const int chunk = (mt * 4 + hi) ^ pswz;
                    *(uint2*)&Ps[w][prow * 64 + chunk * 4] = pw;
                }
                ls += __shfl_xor(ls, 16, 64);
                ls += __shfl_xor(ls, 32, 64);
                lrun[nt] = lrun[nt] * al[nt] + ls;
            }
        }
        // mid barrier: V must be landed; next-tile K may stay in flight
        if (havK) asm volatile("s_waitcnt vmcnt(4)" ::: "memory");
        else      asm volatile("s_waitcnt vmcnt(0)" ::: "memory");
        __builtin_amdgcn_s_barrier();

        if (active) {
#pragma unroll
            for (int ks2 = 0; ks2 < 2; ks2++) {
                const int ch0 = ((ks2 * 8 + hi * 2) ^ pswz) * 4;
                const short8 pa0 = *(const short8*)&Ps[w][(0 * 16 + lr) * 64 + ch0];
                const short8 pa1 = *(const short8*)&Ps[w][(1 * 16 + lr) * 64 + ch0];
#pragma unroll
                for (int dt = 0; dt < 8; dt++) {
                    const int r = dt * 16 + lr;
                    const int ch = (ks2 * 4 + hi) ^ (r & 7);
                    const short8 vf = *(const short8*)&Vs[(r * 8 + ch) * 8];
                    accO[0][dt] = __builtin_amdgcn_mfma_f32_16x16x32_bf16(pa0, vf, accO[0][dt], 0, 0, 0);
                    accO[1][dt] = __builtin_amdgcn_mfma_f32_16x16x32_bf16(pa1, vf, accO[1][dt], 0, 0, 0);
                }
            }
        }
        // end barrier: next-tile K landed; all waves done reading Vs
        asm volatile("s_waitcnt vmcnt(0)" ::: "memory");
        __builtin_amdgcn_s_barrier();
        kbuf ^= 1;
    }

#pragma unroll
    for (int nt = 0; nt < 2; nt++) {
        const float lv_own = 1.f / lrun[nt];
#pragma unroll
        for (int rg = 0; rg < 4; rg++) {
            const float lv = __shfl(lv_own, hi * 4 + rg, 64);
            unsigned short* orow = outb + (size_t)(b * TSEQ + q0w + nt * 16 + hi * 4 + rg) * DMODEL + h * DK;
#pragma unroll
            for (int dt = 0; dt < 8; dt++)
                orow[dt * 16 + lr] = f2bf(accO[nt][dt][rg] * lv);
        }
    }
}

// ===================== launch =====================
extern "C" void kernel_launch(void* const* d_in, const int* in_sizes, int n_in,
                              void* d_out, int out_size, void* d_ws, size_t ws_size,
                              hipStream_t stream)
{
    const float* x    = (const float*)d_in[0];
    const int*   pos  = (const int*)d_in[1];
    const float* Wqkv = (const float*)d_in[2];
    const float* Wo   = (const float*)d_in[3];
    float* out = (float*)d_out;

    unsigned short* qkvb  = (unsigned short*)d_ws;
    unsigned short* vtb   = qkvb + (size_t)25165824;
    unsigned short* xb    = vtb + (size_t)8388608;
    unsigned short* attnb = xb;                         // alias: xb dead after GEMM1
    unsigned short* wqkvb = xb + (size_t)8388608;
    unsigned short* wob   = wqkvb + (size_t)12582912;
    float2* tab = (float2*)(wob + (size_t)4194304);

    cast_all_bf16<<<12288, 256, 0, stream>>>(x, Wqkv, Wo, xb, wqkvb, wob);
    rope_table_kernel<<<512, 256, 0, stream>>>(pos, tab);

    // fused QKV projection + RoPE + V-transpose (4096 x 6144 x 2048), 1024 tiles of 128x192
    gemm_qkv_x<<<dim3(1024), 256, 0, stream>>>(xb, wqkvb, qkvb, vtb, tab);

    attn_mfma2_kernel<<<dim3(16, 32), 256, 0, stream>>>(qkvb, vtb, attnb);

    // out = attn @ Wo^T (4096 x 2048 x 2048), 512 tiles of 128x128
    gemm_o_x<<<dim3(512), 256, 0, stream>>>(attnb, wob, out);
}

// Round 11
// 260.235 us; speedup vs baseline: 1.3568x; 1.0245x over previous
//
#include <hip/hip_runtime.h>
#include <math.h>
#include <stdint.h>

#define NHEADS 16
#define DK 128
#define TSEQ 2048
#define DMODEL 2048

typedef __attribute__((ext_vector_type(8))) short short8;
typedef __attribute__((ext_vector_type(4))) float floatx4;

__device__ __forceinline__ float bf2f(unsigned short h) {
    return __uint_as_float(((unsigned int)h) << 16);
}
__device__ __forceinline__ unsigned short f2bf(float f) {
    unsigned int u = __float_as_uint(f);
    u += 0x7FFFu + ((u >> 16) & 1u);
    return (unsigned short)(u >> 16);
}
__device__ __forceinline__ void async16(unsigned short* lds, const unsigned short* g) {
    __builtin_amdgcn_global_load_lds(
        (const __attribute__((address_space(1))) uint32_t*)g,
        (__attribute__((address_space(3))) uint32_t*)lds, 16, 0, 0);
}

// ===================== merged cast f32 -> bf16 (x, Wqkv, Wo) =====================
#define NX8 1048576
#define NW8 1572864
#define NO8 524288
__global__ __launch_bounds__(256) void cast_all_bf16(
    const float* __restrict__ x, const float* __restrict__ wqkv, const float* __restrict__ wo,
    unsigned short* __restrict__ xb, unsigned short* __restrict__ wqkvb, unsigned short* __restrict__ wob)
{
    const int i = blockIdx.x * 256 + threadIdx.x;
    const float* src; unsigned short* dst; int k;
    if (i < NX8)            { src = x;    dst = xb;    k = i; }
    else if (i < NX8 + NW8) { src = wqkv; dst = wqkvb; k = i - NX8; }
    else                    { src = wo;   dst = wob;   k = i - NX8 - NW8; }
    const float4* p4 = reinterpret_cast<const float4*>(src) + 2 * (size_t)k;
    const float4 a = p4[0], b = p4[1];
    uint32_t w0 = (uint32_t)f2bf(a.x) | ((uint32_t)f2bf(a.y) << 16);
    uint32_t w1 = (uint32_t)f2bf(a.z) | ((uint32_t)f2bf(a.w) << 16);
    uint32_t w2 = (uint32_t)f2bf(b.x) | ((uint32_t)f2bf(b.y) << 16);
    uint32_t w3 = (uint32_t)f2bf(b.z) | ((uint32_t)f2bf(b.w) << 16);
    uint4 o; o.x = w0; o.y = w1; o.z = w2; o.w = w3;
    *reinterpret_cast<uint4*>(dst + 8 * (size_t)k) = o;
}

// ===================== RoPE table =====================
__global__ __launch_bounds__(256) void rope_table_kernel(
    const int* __restrict__ pos, float2* __restrict__ tab)
{
    const int idx = blockIdx.x * 256 + threadIdx.x;   // 2048*64
    const int tt = idx >> 6, i = idx & 63;
    const double inv_freq = exp(-log(10000.0) * (double)i / 64.0);
    const double ang = (double)pos[tt] * inv_freq;
    tab[idx] = make_float2((float)cos(ang), (float)sin(ang));
}

// ===================== fused QKV GEMM, 128x192 x 2-blocks/CU (round-10, unchanged) =====================
__global__ __launch_bounds__(256, 2) void gemm_qkv_x(
    const unsigned short* __restrict__ A, const unsigned short* __restrict__ B,
    unsigned short* __restrict__ qkvb, unsigned short* __restrict__ vt,
    const float2* __restrict__ tab)
{
    const int K = DMODEL, N = 3 * DMODEL;
    __shared__ unsigned short As[2][128 * 64];   // 32 KB
    __shared__ unsigned short Bs[2][192 * 64];   // 48 KB

    const int t = threadIdx.x;
    const int lane = t & 63, w = t >> 6;
    const int wr = w >> 1, wc = w & 1;          // 2M x 2N waves
    const int lr = lane & 15, hi = lane >> 4;

    const int bid = (int)blockIdx.x;
    const int xcd = bid & 7, local = bid >> 3;   // local in [0,128)
    const int row0 = (local & 31) * 128;
    const int col0 = ((xcd << 2) | (local >> 5)) * 192;

    const int rr = t >> 3;
    const int cc = ((t & 7) ^ (rr & 7)) << 3;
    const unsigned short* aP = A + (size_t)(row0 + rr) * K + cc;
    const unsigned short* bP = B + (size_t)(col0 + rr) * K + cc;
    const size_t rstep = (size_t)32 * K;

    floatx4 acc[4][6];
#pragma unroll
    for (int m = 0; m < 4; m++)
#pragma unroll
        for (int n = 0; n < 6; n++)
#pragma unroll
            for (int e = 0; e < 4; e++) acc[m][n][e] = 0.f;

#define STAGE(nb, k0n) do { \
        async16(&As[nb][t * 8],          aP + (k0n)); \
        async16(&As[nb][(t + 256) * 8],  aP + rstep + (k0n)); \
        async16(&As[nb][(t + 512) * 8],  aP + 2 * rstep + (k0n)); \
        async16(&As[nb][(t + 768) * 8],  aP + 3 * rstep + (k0n)); \
        async16(&Bs[nb][t * 8],          bP + (k0n)); \
        async16(&Bs[nb][(t + 256) * 8],  bP + rstep + (k0n)); \
        async16(&Bs[nb][(t + 512) * 8],  bP + 2 * rstep + (k0n)); \
        async16(&Bs[nb][(t + 768) * 8],  bP + 3 * rstep + (k0n)); \
        async16(&Bs[nb][(t + 1024) * 8], bP + 4 * rstep + (k0n)); \
        async16(&Bs[nb][(t + 1280) * 8], bP + 5 * rstep + (k0n)); \
    } while (0)

    const int NT = K >> 6;   // 32
    const int ch0 = (hi ^ (lr & 7)) * 8;
    const int ch1 = ((4 + hi) ^ (lr & 7)) * 8;

    short8 av[4], bv[6];

#define RD_AV(Ac, ch) do { \
        _Pragma("unroll") \
        for (int m = 0; m < 4; m++) \
            av[m] = *(const short8*)&(Ac)[(wr * 64 + m * 16 + lr) * 64 + (ch)]; \
    } while (0)
#define RD_BV(Bc, ch) do { \
        _Pragma("unroll") \
        for (int n = 0; n < 6; n++) \
            bv[n] = *(const short8*)&(Bc)[(wc * 96 + n * 16 + lr) * 64 + (ch)]; \
    } while (0)
#define MFMA_ALL() do { \
        _Pragma("unroll") \
        for (int m = 0; m < 4; m++) \
            _Pragma("unroll") \
            for (int n = 0; n < 6; n++) \
                acc[m][n] = __builtin_amdgcn_mfma_f32_16x16x32_bf16(av[m], bv[n], acc[m][n], 0, 0, 0); \
    } while (0)

    STAGE(0, 0);

    for (int kt = 0; kt < NT; ++kt) {
        const int cur = kt & 1;
        const unsigned short* __restrict__ Ac = &As[cur][0];
        const unsigned short* __restrict__ Bc = &Bs[cur][0];
        const bool more = (kt + 1 < NT);

        if (more) {
            STAGE(cur ^ 1, (kt + 1) << 6);
            asm volatile("s_waitcnt vmcnt(10)" ::: "memory");
        } else {
            asm volatile("s_waitcnt vmcnt(0)" ::: "memory");
        }
        __builtin_amdgcn_s_barrier();

        RD_AV(Ac, ch0); RD_BV(Bc, ch0);
        asm volatile("s_waitcnt lgkmcnt(0)" ::: "memory");
        __builtin_amdgcn_sched_barrier(0);
        __builtin_amdgcn_s_setprio(1);
        MFMA_ALL();
        __builtin_amdgcn_s_setprio(0);

        RD_AV(Ac, ch1); RD_BV(Bc, ch1);
        asm volatile("s_waitcnt lgkmcnt(0)" ::: "memory");
        __builtin_amdgcn_sched_barrier(0);
        __builtin_amdgcn_s_setprio(1);
        MFMA_ALL();
        __builtin_amdgcn_s_setprio(0);

        __builtin_amdgcn_s_barrier();
    }
#undef STAGE
#undef RD_AV
#undef RD_BV
#undef MFMA_ALL

    const int par = lr & 1;
#pragma unroll
    for (int mi = 0; mi < 4; mi++) {
        const int row = row0 + wr * 64 + mi * 16 + hi * 4;
        const int tt = row & (TSEQ - 1);
        const int bb = row >> 11;
#pragma unroll
        for (int ni = 0; ni < 6; ni++) {
            const int col = col0 + wc * 96 + ni * 16 + lr;
            if (col < 2 * DMODEL) {
                const int pi = (col & 127) >> 1;
#pragma unroll
                for (int j = 0; j < 4; j++) {
                    const float2 cs = tab[(tt + j) * 64 + pi];
                    const float v = acc[mi][ni][j];
                    const float p = __shfl_xor(v, 1, 64);
                    const float o = par ? (p * cs.y + v * cs.x)
                                        : (v * cs.x - p * cs.y);
                    qkvb[(size_t)(row + j) * N + col] = f2bf(o);
                }
            } else {
                const int vcol = col - 2 * DMODEL;
                const int h = vcol >> 7, d = vcol & 127;
                uint2 pw;
                pw.x = (uint32_t)f2bf(acc[mi][ni][0]) | ((uint32_t)f2bf(acc[mi][ni][1]) << 16);
                pw.y = (uint32_t)f2bf(acc[mi][ni][2]) | ((uint32_t)f2bf(acc[mi][ni][3]) << 16);
                *(uint2*)&vt[(size_t)((bb * NHEADS + h) * DK + d) * TSEQ + tt] = pw;
            }
        }
    }
}

// ===================== output projection, 128x128 x 2-blocks/CU, f32 out (unchanged) =====================
__global__ __launch_bounds__(256, 2) void gemm_o_x(
    const unsigned short* __restrict__ A, const unsigned short* __restrict__ B,
    float* __restrict__ C)
{
    const int K = DMODEL, N = DMODEL;
    __shared__ unsigned short As[2][128 * 64];
    __shared__ unsigned short Bs[2][128 * 64];

    const int t = threadIdx.x;
    const int lane = t & 63, w = t >> 6;
    const int wr = w >> 1, wc = w & 1;
    const int lr = lane & 15, hi = lane >> 4;

    const int bid = (int)blockIdx.x;
    const int xcd = bid & 7, local = bid >> 3;
    const int row0 = (local & 31) * 128;
    const int col0 = ((xcd << 1) | (local >> 5)) * 128;

    const int rr = t >> 3;
    const int cc = ((t & 7) ^ (rr & 7)) << 3;
    const unsigned short* aP = A + (size_t)(row0 + rr) * K + cc;
    const unsigned short* bP = B + (size_t)(col0 + rr) * K + cc;
    const size_t rstep = (size_t)32 * K;

    floatx4 acc[4][4];
#pragma unroll
    for (int m = 0; m < 4; m++)
#pragma unroll
        for (int n = 0; n < 4; n++)
#pragma unroll
            for (int e = 0; e < 4; e++) acc[m][n][e] = 0.f;

#define STAGE(nb, k0n) do { \
        async16(&As[nb][t * 8],          aP + (k0n)); \
        async16(&As[nb][(t + 256) * 8],  aP + rstep + (k0n)); \
        async16(&As[nb][(t + 512) * 8],  aP + 2 * rstep + (k0n)); \
        async16(&As[nb][(t + 768) * 8],  aP + 3 * rstep + (k0n)); \
        async16(&Bs[nb][t * 8],          bP + (k0n)); \
        async16(&Bs[nb][(t + 256) * 8],  bP + rstep + (k0n)); \
        async16(&Bs[nb][(t + 512) * 8],  bP + 2 * rstep + (k0n)); \
        async16(&Bs[nb][(t + 768) * 8],  bP + 3 * rstep + (k0n)); \
    } while (0)

    const int NT = K >> 6;
    const int ch0 = (hi ^ (lr & 7)) * 8;
    const int ch1 = ((4 + hi) ^ (lr & 7)) * 8;

    short8 av[4], bv[4];

#define RD_AV(Ac, ch) do { \
        _Pragma("unroll") \
        for (int m = 0; m < 4; m++) \
            av[m] = *(const short8*)&(Ac)[(wr * 64 + m * 16 + lr) * 64 + (ch)]; \
    } while (0)
#define RD_BV(Bc, ch) do { \
        _Pragma("unroll") \
        for (int n = 0; n < 4; n++) \
            bv[n] = *(const short8*)&(Bc)[(wc * 64 + n * 16 + lr) * 64 + (ch)]; \
    } while (0)
#define MFMA_ALL() do { \
        _Pragma("unroll") \
        for (int m = 0; m < 4; m++) \
            _Pragma("unroll") \
            for (int n = 0; n < 4; n++) \
                acc[m][n] = __builtin_amdgcn_mfma_f32_16x16x32_bf16(av[m], bv[n], acc[m][n], 0, 0, 0); \
    } while (0)

    STAGE(0, 0);

    for (int kt = 0; kt < NT; ++kt) {
        const int cur = kt & 1;
        const unsigned short* __restrict__ Ac = &As[cur][0];
        const unsigned short* __restrict__ Bc = &Bs[cur][0];
        const bool more = (kt + 1 < NT);

        if (more) {
            STAGE(cur ^ 1, (kt + 1) << 6);
            asm volatile("s_waitcnt vmcnt(8)" ::: "memory");
        } else {
            asm volatile("s_waitcnt vmcnt(0)" ::: "memory");
        }
        __builtin_amdgcn_s_barrier();

        RD_AV(Ac, ch0); RD_BV(Bc, ch0);
        asm volatile("s_waitcnt lgkmcnt(0)" ::: "memory");
        __builtin_amdgcn_sched_barrier(0);
        __builtin_amdgcn_s_setprio(1);
        MFMA_ALL();
        __builtin_amdgcn_s_setprio(0);

        RD_AV(Ac, ch1); RD_BV(Bc, ch1);
        asm volatile("s_waitcnt lgkmcnt(0)" ::: "memory");
        __builtin_amdgcn_sched_barrier(0);
        __builtin_amdgcn_s_setprio(1);
        MFMA_ALL();
        __builtin_amdgcn_s_setprio(0);

        __builtin_amdgcn_s_barrier();
    }
#undef STAGE
#undef RD_AV
#undef RD_BV
#undef MFMA_ALL

#pragma unroll
    for (int mi = 0; mi < 4; mi++) {
        const int row = row0 + wr * 64 + mi * 16 + hi * 4;
#pragma unroll
        for (int ni = 0; ni < 4; ni++) {
            const int col = col0 + wc * 64 + ni * 16 + lr;
#pragma unroll
            for (int j = 0; j < 4; j++)
                C[(size_t)(row + j) * N + col] = acc[mi][ni][j];
        }
    }
}

// ===================== MFMA flash attention, paired q-chunks =====================
// 256 blocks = 1/CU. 512 thr = 8 waves: waves 0-3 own q-chunk p, waves 4-7 own
// chunk 15-p -> per-block wave work constant (triangle pairing). Shared K/V
// staging serves 256 q-rows. Counted-vmcnt barriers as before.
__global__ __launch_bounds__(512, 1) void attn_mfma3_kernel(
    const unsigned short* __restrict__ qkvb, const unsigned short* __restrict__ vt,
    unsigned short* __restrict__ outb)
{
    __shared__ unsigned short Ks[2][64 * 128];   // 32 KB
    __shared__ unsigned short Vs[128 * 64];      // 16 KB
    __shared__ unsigned short Ps[8][32 * 64];    // 32 KB

    const int t = threadIdx.x;
    const int lane = t & 63, w = t >> 6;         // w in 0..7
    const int lr = lane & 15, hi = lane >> 4;
    const int bh = (int)blockIdx.x >> 3;         // 0..31
    const int p  = (int)blockIdx.x & 7;          // pair index
    const int b = bh >> 4, h = bh & 15;
    const int chunk = (w < 4) ? p : (15 - p);
    const int q0w = chunk * 128 + (w & 3) * 32;
    const float scale = 0.08838834764831845f;
    const size_t QROW = 3 * DMODEL;

    const unsigned short* kg = qkvb + (size_t)b * TSEQ * QROW + DMODEL + h * DK;
    const unsigned short* vg = vt + (size_t)bh * DK * TSEQ;

    short8 qf[2][4];
    {
        const unsigned short* qbase = qkvb + (size_t)(b * TSEQ + q0w) * QROW + h * DK;
#pragma unroll
        for (int nt = 0; nt < 2; nt++)
#pragma unroll
            for (int ks = 0; ks < 4; ks++) {
                short8 raw = *(const short8*)(qbase + (size_t)(nt * 16 + lr) * QROW + ks * 32 + hi * 8);
                short8 sc;
#pragma unroll
                for (int e = 0; e < 8; e++)
                    sc[e] = (short)f2bf(bf2f((unsigned short)raw[e]) * scale);
                qf[nt][ks] = sc;
            }
    }

    // staging: 512 threads, 2 chunks each
    auto stageK = [&](int bufi, int kv0s) {
#pragma unroll
        for (int i = 0; i < 2; i++) {
            const int s = i * 512 + t;
            const int r = s >> 4;
            const int cc = (s & 15) ^ (r & 7);
            async16(&Ks[bufi][s * 8], kg + (size_t)(kv0s + r) * QROW + cc * 8);
        }
    };
    auto stageV = [&](int kv0s) {
#pragma unroll
        for (int i = 0; i < 2; i++) {
            const int s = i * 512 + t;
            const int r = s >> 3;
            const int cc = (s & 7) ^ (r & 7);
            async16(&Vs[s * 8], vg + (size_t)r * TSEQ + kv0s + cc * 8);
        }
    };

    floatx4 accO[2][8];
#pragma unroll
    for (int nt = 0; nt < 2; nt++)
#pragma unroll
        for (int dt = 0; dt < 8; dt++)
#pragma unroll
            for (int e = 0; e < 4; e++) accO[nt][dt][e] = 0.f;
    float mrun[2] = {-1e30f, -1e30f};
    float lrun[2] = {0.f, 0.f};

    const int ntiles = (15 - p) * 2 + 2;   // driven by the heavy chunk
    int kbuf = 0;

    stageK(0, 0);
    __syncthreads();

    const int pswz = (lr & 7) << 1;

    for (int ti = 0; ti < ntiles; ti++) {
        const int kv0 = ti * 64;
        const bool havK = (ti + 1 < ntiles);
        stageV(kv0);
        if (havK) stageK(kbuf ^ 1, kv0 + 64);

        const bool active = (kv0 <= q0w + 31);
        float al[2] = {1.f, 1.f};

        if (active) {
            floatx4 st[4][2];
#pragma unroll
            for (int mt = 0; mt < 4; mt++)
#pragma unroll
                for (int nt = 0; nt < 2; nt++)
#pragma unroll
                    for (int e = 0; e < 4; e++) st[mt][nt][e] = 0.f;
#pragma unroll
            for (int mt = 0; mt < 4; mt++) {
                const int r = mt * 16 + lr;
#pragma unroll
                for (int ks = 0; ks < 4; ks++) {
                    const int ch = (ks * 4 + hi) ^ (r & 7);
                    const short8 kf = *(const short8*)&Ks[kbuf][(r * 16 + ch) * 8];
                    st[mt][0] = __builtin_amdgcn_mfma_f32_16x16x32_bf16(kf, qf[0][ks], st[mt][0], 0, 0, 0);
                    st[mt][1] = __builtin_amdgcn_mfma_f32_16x16x32_bf16(kf, qf[1][ks], st[mt][1], 0, 0, 0);
                }
            }
            if (kv0 + 63 > q0w) {
#pragma unroll
                for (int nt = 0; nt < 2; nt++) {
                    const int qg = q0w + nt * 16 + lr;
#pragma unroll
                    for (int mt = 0; mt < 4; mt++)
#pragma unroll
                        for (int rg = 0; rg < 4; rg++) {
                            const int kvg = kv0 + mt * 16 + hi * 4 + rg;
                            if (kvg > qg) st[mt][nt][rg] = -1e30f;
                        }
                }
            }
            float pm[2];
#pragma unroll
            for (int nt = 0; nt < 2; nt++) {
                float m = -1e30f;
#pragma unroll
                for (int mt = 0; mt < 4; mt++)
#pragma unroll
                    for (int rg = 0; rg < 4; rg++) m = fmaxf(m, st[mt][nt][rg]);
                m = fmaxf(m, __shfl_xor(m, 16, 64));
                m = fmaxf(m, __shfl_xor(m, 32, 64));
                pm[nt] = m;
            }
            if (__any((pm[0] > mrun[0] + 8.f) || (pm[1] > mrun[1] + 8.f))) {
#pragma unroll
                for (int nt = 0; nt < 2; nt++) {
                    const float mn = fmaxf(mrun[nt], pm[nt]);
                    al[nt] = __expf(mrun[nt] - mn);
                    mrun[nt] = mn;
                }
#pragma unroll
                for (int rg = 0; rg < 4; rg++) {
                    const float a0 = __shfl(al[0], hi * 4 + rg, 64);
                    const float a1 = __shfl(al[1], hi * 4 + rg, 64);
#pragma unroll
                    for (int dt = 0; dt < 8; dt++) {
                        accO[0][dt][rg] *= a0;
                        accO[1][dt][rg] *= a1;
                    }
                }
            }
#pragma unroll
            for (int nt = 0; nt < 2; nt++) {
                float ls = 0.f;
                const int prow = nt * 16 + lr;
#pragma unroll
                for (int mt = 0; mt < 4; mt++) {
                    float pv[4];
#pragma unroll
                    for (int rg = 0; rg < 4; rg++) {
                        pv[rg] = __expf(st[mt][nt][rg] - mrun[nt]);
                        ls += pv[rg];
                    }
                    uint2 pw;
                    pw.x = (uint32_t)f2bf(pv[0]) | ((uint32_t)f2bf(pv[1]) << 16);
                    pw.y = (uint32_t)f2bf(pv[2]) | ((uint32_t)f2bf(pv[3]) << 16);
                    const int chunkx = (mt * 4 + hi) ^ pswz;
                    *(uint2*)&Ps[w][prow * 64 + chunkx * 4] = pw;
                }
                ls += __shfl_xor(ls, 16, 64);
                ls += __shfl_xor(ls, 32, 64);
                lrun[nt] = lrun[nt] * al[nt] + ls;
            }
        }
        // mid barrier: V landed (2 oldest of 4); next-tile K may stay in flight
        if (havK) asm volatile("s_waitcnt vmcnt(2)" ::: "memory");
        else      asm volatile("s_waitcnt vmcnt(0)" ::: "memory");
        __builtin_amdgcn_s_barrier();

        if (active) {
#pragma unroll
            for (int ks2 = 0; ks2 < 2; ks2++) {
                const int ch0 = ((ks2 * 8 + hi * 2) ^ pswz) * 4;
                const short8 pa0 = *(const short8*)&Ps[w][(0 * 16 + lr) * 64 + ch0];
                const short8 pa1 = *(const short8*)&Ps[w][(1 * 16 + lr) * 64 + ch0];
#pragma unroll
                for (int dt = 0; dt < 8; dt++) {
                    const int r = dt * 16 + lr;
                    const int ch = (ks2 * 4 + hi) ^ (r & 7);
                    const short8 vf = *(const short8*)&Vs[(r * 8 + ch) * 8];
                    accO[0][dt] = __builtin_amdgcn_mfma_f32_16x16x32_bf16(pa0, vf, accO[0][dt], 0, 0, 0);
                    accO[1][dt] = __builtin_amdgcn_mfma_f32_16x16x32_bf16(pa1, vf, accO[1][dt], 0, 0, 0);
                }
            }
        }
        // end barrier: next-tile K landed; all waves done reading Vs
        asm volatile("s_waitcnt vmcnt(0)" ::: "memory");
        __builtin_amdgcn_s_barrier();
        kbuf ^= 1;
    }

#pragma unroll
    for (int nt = 0; nt < 2; nt++) {
        const float lv_own = 1.f / lrun[nt];
#pragma unroll
        for (int rg = 0; rg < 4; rg++) {
            const float lv = __shfl(lv_own, hi * 4 + rg, 64);
            unsigned short* orow = outb + (size_t)(b * TSEQ + q0w + nt * 16 + hi * 4 + rg) * DMODEL + h * DK;
#pragma unroll
            for (int dt = 0; dt < 8; dt++)
                orow[dt * 16 + lr] = f2bf(accO[nt][dt][rg] * lv);
        }
    }
}

// ===================== launch =====================
extern "C" void kernel_launch(void* const* d_in, const int* in_sizes, int n_in,
                              void* d_out, int out_size, void* d_ws, size_t ws_size,
                              hipStream_t stream)
{
    const float* x    = (const float*)d_in[0];
    const int*   pos  = (const int*)d_in[1];
    const float* Wqkv = (const float*)d_in[2];
    const float* Wo   = (const float*)d_in[3];
    float* out = (float*)d_out;

    unsigned short* qkvb  = (unsigned short*)d_ws;
    unsigned short* vtb   = qkvb + (size_t)25165824;
    unsigned short* xb    = vtb + (size_t)8388608;
    unsigned short* attnb = xb;                         // alias: xb dead after GEMM1
    unsigned short* wqkvb = xb + (size_t)8388608;
    unsigned short* wob   = wqkvb + (size_t)12582912;
    float2* tab = (float2*)(wob + (size_t)4194304);

    cast_all_bf16<<<12288, 256, 0, stream>>>(x, Wqkv, Wo, xb, wqkvb, wob);
    rope_table_kernel<<<512, 256, 0, stream>>>(pos, tab);

    // fused QKV projection + RoPE + V-transpose (4096 x 6144 x 2048)
    gemm_qkv_x<<<dim3(1024), 256, 0, stream>>>(xb, wqkvb, qkvb, vtb, tab);

    // paired-chunk flash attention: 256 blocks (32 bh x 8 pairs), 512 thr
    attn_mfma3_kernel<<<dim3(256), 512, 0, stream>>>(qkvb, vtb, attnb);

    // out = attn @ Wo^T (4096 x 2048 x 2048), 512 tiles of 128x128
    gemm_o_x<<<dim3(512), 256, 0, stream>>>(attnb, wob, out);
}

// Round 12
// 256.825 us; speedup vs baseline: 1.3748x; 1.0133x over previous
//
#include <hip/hip_runtime.h>
#include <math.h>
#include <stdint.h>

#define NHEADS 16
#define DK 128
#define TSEQ 2048
#define DMODEL 2048

typedef __attribute__((ext_vector_type(8))) short short8;
typedef __attribute__((ext_vector_type(4))) float floatx4;

__device__ __forceinline__ float bf2f(unsigned short h) {
    return __uint_as_float(((unsigned int)h) << 16);
}
__device__ __forceinline__ unsigned short f2bf(float f) {
    unsigned int u = __float_as_uint(f);
    u += 0x7FFFu + ((u >> 16) & 1u);
    return (unsigned short)(u >> 16);
}
__device__ __forceinline__ void async16(unsigned short* lds, const unsigned short* g) {
    __builtin_amdgcn_global_load_lds(
        (const __attribute__((address_space(1))) uint32_t*)g,
        (__attribute__((address_space(3))) uint32_t*)lds, 16, 0, 0);
}

// ===================== merged cast f32 -> bf16 (x, Wqkv, Wo) =====================
#define NX8 1048576
#define NW8 1572864
#define NO8 524288
__global__ __launch_bounds__(256) void cast_all_bf16(
    const float* __restrict__ x, const float* __restrict__ wqkv, const float* __restrict__ wo,
    unsigned short* __restrict__ xb, unsigned short* __restrict__ wqkvb, unsigned short* __restrict__ wob)
{
    const int i = blockIdx.x * 256 + threadIdx.x;
    const float* src; unsigned short* dst; int k;
    if (i < NX8)            { src = x;    dst = xb;    k = i; }
    else if (i < NX8 + NW8) { src = wqkv; dst = wqkvb; k = i - NX8; }
    else                    { src = wo;   dst = wob;   k = i - NX8 - NW8; }
    const float4* p4 = reinterpret_cast<const float4*>(src) + 2 * (size_t)k;
    const float4 a = p4[0], b = p4[1];
    uint32_t w0 = (uint32_t)f2bf(a.x) | ((uint32_t)f2bf(a.y) << 16);
    uint32_t w1 = (uint32_t)f2bf(a.z) | ((uint32_t)f2bf(a.w) << 16);
    uint32_t w2 = (uint32_t)f2bf(b.x) | ((uint32_t)f2bf(b.y) << 16);
    uint32_t w3 = (uint32_t)f2bf(b.z) | ((uint32_t)f2bf(b.w) << 16);
    uint4 o; o.x = w0; o.y = w1; o.z = w2; o.w = w3;
    *reinterpret_cast<uint4*>(dst + 8 * (size_t)k) = o;
}

// ===================== RoPE table =====================
__global__ __launch_bounds__(256) void rope_table_kernel(
    const int* __restrict__ pos, float2* __restrict__ tab)
{
    const int idx = blockIdx.x * 256 + threadIdx.x;   // 2048*64
    const int tt = idx >> 6, i = idx & 63;
    const double inv_freq = exp(-log(10000.0) * (double)i / 64.0);
    const double ang = (double)pos[tt] * inv_freq;
    tab[idx] = make_float2((float)cos(ang), (float)sin(ang));
}

// ===================== fused QKV GEMM, 128x192 x 2-blocks/CU (unchanged) =====================
__global__ __launch_bounds__(256, 2) void gemm_qkv_x(
    const unsigned short* __restrict__ A, const unsigned short* __restrict__ B,
    unsigned short* __restrict__ qkvb, unsigned short* __restrict__ vt,
    const float2* __restrict__ tab)
{
    const int K = DMODEL, N = 3 * DMODEL;
    __shared__ unsigned short As[2][128 * 64];   // 32 KB
    __shared__ unsigned short Bs[2][192 * 64];   // 48 KB

    const int t = threadIdx.x;
    const int lane = t & 63, w = t >> 6;
    const int wr = w >> 1, wc = w & 1;
    const int lr = lane & 15, hi = lane >> 4;

    const int bid = (int)blockIdx.x;
    const int xcd = bid & 7, local = bid >> 3;
    const int row0 = (local & 31) * 128;
    const int col0 = ((xcd << 2) | (local >> 5)) * 192;

    const int rr = t >> 3;
    const int cc = ((t & 7) ^ (rr & 7)) << 3;
    const unsigned short* aP = A + (size_t)(row0 + rr) * K + cc;
    const unsigned short* bP = B + (size_t)(col0 + rr) * K + cc;
    const size_t rstep = (size_t)32 * K;

    floatx4 acc[4][6];
#pragma unroll
    for (int m = 0; m < 4; m++)
#pragma unroll
        for (int n = 0; n < 6; n++)
#pragma unroll
            for (int e = 0; e < 4; e++) acc[m][n][e] = 0.f;

#define STAGE(nb, k0n) do { \
        async16(&As[nb][t * 8],          aP + (k0n)); \
        async16(&As[nb][(t + 256) * 8],  aP + rstep + (k0n)); \
        async16(&As[nb][(t + 512) * 8],  aP + 2 * rstep + (k0n)); \
        async16(&As[nb][(t + 768) * 8],  aP + 3 * rstep + (k0n)); \
        async16(&Bs[nb][t * 8],          bP + (k0n)); \
        async16(&Bs[nb][(t + 256) * 8],  bP + rstep + (k0n)); \
        async16(&Bs[nb][(t + 512) * 8],  bP + 2 * rstep + (k0n)); \
        async16(&Bs[nb][(t + 768) * 8],  bP + 3 * rstep + (k0n)); \
        async16(&Bs[nb][(t + 1024) * 8], bP + 4 * rstep + (k0n)); \
        async16(&Bs[nb][(t + 1280) * 8], bP + 5 * rstep + (k0n)); \
    } while (0)

    const int NT = K >> 6;
    const int ch0 = (hi ^ (lr & 7)) * 8;
    const int ch1 = ((4 + hi) ^ (lr & 7)) * 8;

    short8 av[4], bv[6];

#define RD_AV(Ac, ch) do { \
        _Pragma("unroll") \
        for (int m = 0; m < 4; m++) \
            av[m] = *(const short8*)&(Ac)[(wr * 64 + m * 16 + lr) * 64 + (ch)]; \
    } while (0)
#define RD_BV(Bc, ch) do { \
        _Pragma("unroll") \
        for (int n = 0; n < 6; n++) \
            bv[n] = *(const short8*)&(Bc)[(wc * 96 + n * 16 + lr) * 64 + (ch)]; \
    } while (0)
#define MFMA_ALL() do { \
        _Pragma("unroll") \
        for (int m = 0; m < 4; m++) \
            _Pragma("unroll") \
            for (int n = 0; n < 6; n++) \
                acc[m][n] = __builtin_amdgcn_mfma_f32_16x16x32_bf16(av[m], bv[n], acc[m][n], 0, 0, 0); \
    } while (0)

    STAGE(0, 0);

    for (int kt = 0; kt < NT; ++kt) {
        const int cur = kt & 1;
        const unsigned short* __restrict__ Ac = &As[cur][0];
        const unsigned short* __restrict__ Bc = &Bs[cur][0];
        const bool more = (kt + 1 < NT);

        if (more) {
            STAGE(cur ^ 1, (kt + 1) << 6);
            asm volatile("s_waitcnt vmcnt(10)" ::: "memory");
        } else {
            asm volatile("s_waitcnt vmcnt(0)" ::: "memory");
        }
        __builtin_amdgcn_s_barrier();

        RD_AV(Ac, ch0); RD_BV(Bc, ch0);
        asm volatile("s_waitcnt lgkmcnt(0)" ::: "memory");
        __builtin_amdgcn_sched_barrier(0);
        __builtin_amdgcn_s_setprio(1);
        MFMA_ALL();
        __builtin_amdgcn_s_setprio(0);

        RD_AV(Ac, ch1); RD_BV(Bc, ch1);
        asm volatile("s_waitcnt lgkmcnt(0)" ::: "memory");
        __builtin_amdgcn_sched_barrier(0);
        __builtin_amdgcn_s_setprio(1);
        MFMA_ALL();
        __builtin_amdgcn_s_setprio(0);

        __builtin_amdgcn_s_barrier();
    }
#undef STAGE
#undef RD_AV
#undef RD_BV
#undef MFMA_ALL

    const int par = lr & 1;
#pragma unroll
    for (int mi = 0; mi < 4; mi++) {
        const int row = row0 + wr * 64 + mi * 16 + hi * 4;
        const int tt = row & (TSEQ - 1);
        const int bb = row >> 11;
#pragma unroll
        for (int ni = 0; ni < 6; ni++) {
            const int col = col0 + wc * 96 + ni * 16 + lr;
            if (col < 2 * DMODEL) {
                const int pi = (col & 127) >> 1;
#pragma unroll
                for (int j = 0; j < 4; j++) {
                    const float2 cs = tab[(tt + j) * 64 + pi];
                    const float v = acc[mi][ni][j];
                    const float p = __shfl_xor(v, 1, 64);
                    const float o = par ? (p * cs.y + v * cs.x)
                                        : (v * cs.x - p * cs.y);
                    qkvb[(size_t)(row + j) * N + col] = f2bf(o);
                }
            } else {
                const int vcol = col - 2 * DMODEL;
                const int h = vcol >> 7, d = vcol & 127;
                uint2 pw;
                pw.x = (uint32_t)f2bf(acc[mi][ni][0]) | ((uint32_t)f2bf(acc[mi][ni][1]) << 16);
                pw.y = (uint32_t)f2bf(acc[mi][ni][2]) | ((uint32_t)f2bf(acc[mi][ni][3]) << 16);
                *(uint2*)&vt[(size_t)((bb * NHEADS + h) * DK + d) * TSEQ + tt] = pw;
            }
        }
    }
}

// ===================== output projection, 128x128 x 2-blocks/CU, f32 out (unchanged) =====================
__global__ __launch_bounds__(256, 2) void gemm_o_x(
    const unsigned short* __restrict__ A, const unsigned short* __restrict__ B,
    float* __restrict__ C)
{
    const int K = DMODEL, N = DMODEL;
    __shared__ unsigned short As[2][128 * 64];
    __shared__ unsigned short Bs[2][128 * 64];

    const int t = threadIdx.x;
    const int lane = t & 63, w = t >> 6;
    const int wr = w >> 1, wc = w & 1;
    const int lr = lane & 15, hi = lane >> 4;

    const int bid = (int)blockIdx.x;
    const int xcd = bid & 7, local = bid >> 3;
    const int row0 = (local & 31) * 128;
    const int col0 = ((xcd << 1) | (local >> 5)) * 128;

    const int rr = t >> 3;
    const int cc = ((t & 7) ^ (rr & 7)) << 3;
    const unsigned short* aP = A + (size_t)(row0 + rr) * K + cc;
    const unsigned short* bP = B + (size_t)(col0 + rr) * K + cc;
    const size_t rstep = (size_t)32 * K;

    floatx4 acc[4][4];
#pragma unroll
    for (int m = 0; m < 4; m++)
#pragma unroll
        for (int n = 0; n < 4; n++)
#pragma unroll
            for (int e = 0; e < 4; e++) acc[m][n][e] = 0.f;

#define STAGE(nb, k0n) do { \
        async16(&As[nb][t * 8],          aP + (k0n)); \
        async16(&As[nb][(t + 256) * 8],  aP + rstep + (k0n)); \
        async16(&As[nb][(t + 512) * 8],  aP + 2 * rstep + (k0n)); \
        async16(&As[nb][(t + 768) * 8],  aP + 3 * rstep + (k0n)); \
        async16(&Bs[nb][t * 8],          bP + (k0n)); \
        async16(&Bs[nb][(t + 256) * 8],  bP + rstep + (k0n)); \
        async16(&Bs[nb][(t + 512) * 8],  bP + 2 * rstep + (k0n)); \
        async16(&Bs[nb][(t + 768) * 8],  bP + 3 * rstep + (k0n)); \
    } while (0)

    const int NT = K >> 6;
    const int ch0 = (hi ^ (lr & 7)) * 8;
    const int ch1 = ((4 + hi) ^ (lr & 7)) * 8;

    short8 av[4], bv[4];

#define RD_AV(Ac, ch) do { \
        _Pragma("unroll") \
        for (int m = 0; m < 4; m++) \
            av[m] = *(const short8*)&(Ac)[(wr * 64 + m * 16 + lr) * 64 + (ch)]; \
    } while (0)
#define RD_BV(Bc, ch) do { \
        _Pragma("unroll") \
        for (int n = 0; n < 4; n++) \
            bv[n] = *(const short8*)&(Bc)[(wc * 64 + n * 16 + lr) * 64 + (ch)]; \
    } while (0)
#define MFMA_ALL() do { \
        _Pragma("unroll") \
        for (int m = 0; m < 4; m++) \
            _Pragma("unroll") \
            for (int n = 0; n < 4; n++) \
                acc[m][n] = __builtin_amdgcn_mfma_f32_16x16x32_bf16(av[m], bv[n], acc[m][n], 0, 0, 0); \
    } while (0)

    STAGE(0, 0);

    for (int kt = 0; kt < NT; ++kt) {
        const int cur = kt & 1;
        const unsigned short* __restrict__ Ac = &As[cur][0];
        const unsigned short* __restrict__ Bc = &Bs[cur][0];
        const bool more = (kt + 1 < NT);

        if (more) {
            STAGE(cur ^ 1, (kt + 1) << 6);
            asm volatile("s_waitcnt vmcnt(8)" ::: "memory");
        } else {
            asm volatile("s_waitcnt vmcnt(0)" ::: "memory");
        }
        __builtin_amdgcn_s_barrier();

        RD_AV(Ac, ch0); RD_BV(Bc, ch0);
        asm volatile("s_waitcnt lgkmcnt(0)" ::: "memory");
        __builtin_amdgcn_sched_barrier(0);
        __builtin_amdgcn_s_setprio(1);
        MFMA_ALL();
        __builtin_amdgcn_s_setprio(0);

        RD_AV(Ac, ch1); RD_BV(Bc, ch1);
        asm volatile("s_waitcnt lgkmcnt(0)" ::: "memory");
        __builtin_amdgcn_sched_barrier(0);
        __builtin_amdgcn_s_setprio(1);
        MFMA_ALL();
        __builtin_amdgcn_s_setprio(0);

        __builtin_amdgcn_s_barrier();
    }
#undef STAGE
#undef RD_AV
#undef RD_BV
#undef MFMA_ALL

#pragma unroll
    for (int mi = 0; mi < 4; mi++) {
        const int row = row0 + wr * 64 + mi * 16 + hi * 4;
#pragma unroll
        for (int ni = 0; ni < 4; ni++) {
            const int col = col0 + wc * 64 + ni * 16 + lr;
#pragma unroll
            for (int j = 0; j < 4; j++)
                C[(size_t)(row + j) * N + col] = acc[mi][ni][j];
        }
    }
}

// ===================== MFMA flash attention v4: K+V dbuf, 1 barrier/tile =====================
// 256 blocks (bh = bid&31 -> all 8 pair-blocks of a bh on one XCD for KV L2 reuse).
// 512 thr = 8 waves: waves 0-3 q-chunk p, waves 4-7 chunk 15-p. K[t+1],V[t+1]
// prefetched at tile-t start; single vmcnt(0)+barrier at tile end.
__global__ __launch_bounds__(512, 1) void attn_mfma4_kernel(
    const unsigned short* __restrict__ qkvb, const unsigned short* __restrict__ vt,
    unsigned short* __restrict__ outb)
{
    __shared__ unsigned short Ks[2][64 * 128];   // 32 KB
    __shared__ unsigned short Vs[2][128 * 64];   // 32 KB
    __shared__ unsigned short Ps[8][32 * 64];    // 32 KB

    const int t = threadIdx.x;
    const int lane = t & 63, w = t >> 6;
    const int lr = lane & 15, hi = lane >> 4;
    const int bh = (int)blockIdx.x & 31;         // same-bh blocks share an XCD
    const int p  = (int)blockIdx.x >> 5;         // pair index 0..7
    const int b = bh >> 4, h = bh & 15;
    const int chunk = (w < 4) ? p : (15 - p);
    const int q0w = chunk * 128 + (w & 3) * 32;
    const float scale = 0.08838834764831845f;
    const size_t QROW = 3 * DMODEL;

    const unsigned short* kg = qkvb + (size_t)b * TSEQ * QROW + DMODEL + h * DK;
    const unsigned short* vg = vt + (size_t)bh * DK * TSEQ;

    short8 qf[2][4];
    {
        const unsigned short* qbase = qkvb + (size_t)(b * TSEQ + q0w) * QROW + h * DK;
#pragma unroll
        for (int nt = 0; nt < 2; nt++)
#pragma unroll
            for (int ks = 0; ks < 4; ks++) {
                short8 raw = *(const short8*)(qbase + (size_t)(nt * 16 + lr) * QROW + ks * 32 + hi * 8);
                short8 sc;
#pragma unroll
                for (int e = 0; e < 8; e++)
                    sc[e] = (short)f2bf(bf2f((unsigned short)raw[e]) * scale);
                qf[nt][ks] = sc;
            }
    }

    auto stageK = [&](int bufi, int kv0s) {
#pragma unroll
        for (int i = 0; i < 2; i++) {
            const int s = i * 512 + t;
            const int r = s >> 4;
            const int cc = (s & 15) ^ (r & 7);
            async16(&Ks[bufi][s * 8], kg + (size_t)(kv0s + r) * QROW + cc * 8);
        }
    };
    auto stageV = [&](int bufi, int kv0s) {
#pragma unroll
        for (int i = 0; i < 2; i++) {
            const int s = i * 512 + t;
            const int r = s >> 3;
            const int cc = (s & 7) ^ (r & 7);
            async16(&Vs[bufi][s * 8], vg + (size_t)r * TSEQ + kv0s + cc * 8);
        }
    };

    floatx4 accO[2][8];
#pragma unroll
    for (int nt = 0; nt < 2; nt++)
#pragma unroll
        for (int dt = 0; dt < 8; dt++)
#pragma unroll
            for (int e = 0; e < 4; e++) accO[nt][dt][e] = 0.f;
    float mrun[2] = {-1e30f, -1e30f};
    float lrun[2] = {0.f, 0.f};

    const int ntiles = (16 - p) * 2;   // heavy-chunk span
    int buf = 0;

    stageK(0, 0);
    stageV(0, 0);
    asm volatile("s_waitcnt vmcnt(0)" ::: "memory");
    __builtin_amdgcn_s_barrier();

    const int pswz = (lr & 7) << 1;

    for (int ti = 0; ti < ntiles; ti++) {
        const int kv0 = ti * 64;
        // prefetch next tile's K and V into the other buffer
        if (ti + 1 < ntiles) {
            stageK(buf ^ 1, kv0 + 64);
            stageV(buf ^ 1, kv0 + 64);
        }

        const bool active = (kv0 <= q0w + 31);

        if (active) {
            float al[2] = {1.f, 1.f};
            floatx4 st[4][2];
#pragma unroll
            for (int mt = 0; mt < 4; mt++)
#pragma unroll
                for (int nt = 0; nt < 2; nt++)
#pragma unroll
                    for (int e = 0; e < 4; e++) st[mt][nt][e] = 0.f;
#pragma unroll
            for (int mt = 0; mt < 4; mt++) {
                const int r = mt * 16 + lr;
#pragma unroll
                for (int ks = 0; ks < 4; ks++) {
                    const int ch = (ks * 4 + hi) ^ (r & 7);
                    const short8 kf = *(const short8*)&Ks[buf][(r * 16 + ch) * 8];
                    st[mt][0] = __builtin_amdgcn_mfma_f32_16x16x32_bf16(kf, qf[0][ks], st[mt][0], 0, 0, 0);
                    st[mt][1] = __builtin_amdgcn_mfma_f32_16x16x32_bf16(kf, qf[1][ks], st[mt][1], 0, 0, 0);
                }
            }
            if (kv0 + 63 > q0w) {
#pragma unroll
                for (int nt = 0; nt < 2; nt++) {
                    const int qg = q0w + nt * 16 + lr;
#pragma unroll
                    for (int mt = 0; mt < 4; mt++)
#pragma unroll
                        for (int rg = 0; rg < 4; rg++) {
                            const int kvg = kv0 + mt * 16 + hi * 4 + rg;
                            if (kvg > qg) st[mt][nt][rg] = -1e30f;
                        }
                }
            }
            float pm[2];
#pragma unroll
            for (int nt = 0; nt < 2; nt++) {
                float m = -1e30f;
#pragma unroll
                for (int mt = 0; mt < 4; mt++)
#pragma unroll
                    for (int rg = 0; rg < 4; rg++) m = fmaxf(m, st[mt][nt][rg]);
                m = fmaxf(m, __shfl_xor(m, 16, 64));
                m = fmaxf(m, __shfl_xor(m, 32, 64));
                pm[nt] = m;
            }
            if (__any((pm[0] > mrun[0] + 8.f) || (pm[1] > mrun[1] + 8.f))) {
#pragma unroll
                for (int nt = 0; nt < 2; nt++) {
                    const float mn = fmaxf(mrun[nt], pm[nt]);
                    al[nt] = __expf(mrun[nt] - mn);
                    mrun[nt] = mn;
                }
#pragma unroll
                for (int rg = 0; rg < 4; rg++) {
                    const float a0 = __shfl(al[0], hi * 4 + rg, 64);
                    const float a1 = __shfl(al[1], hi * 4 + rg, 64);
#pragma unroll
                    for (int dt = 0; dt < 8; dt++) {
                        accO[0][dt][rg] *= a0;
                        accO[1][dt][rg] *= a1;
                    }
                }
            }
#pragma unroll
            for (int nt = 0; nt < 2; nt++) {
                float ls = 0.f;
                const int prow = nt * 16 + lr;
#pragma unroll
                for (int mt = 0; mt < 4; mt++) {
                    float pv[4];
#pragma unroll
                    for (int rg = 0; rg < 4; rg++) {
                        pv[rg] = __expf(st[mt][nt][rg] - mrun[nt]);
                        ls += pv[rg];
                    }
                    uint2 pw;
                    pw.x = (uint32_t)f2bf(pv[0]) | ((uint32_t)f2bf(pv[1]) << 16);
                    pw.y = (uint32_t)f2bf(pv[2]) | ((uint32_t)f2bf(pv[3]) << 16);
                    const int chunkx = (mt * 4 + hi) ^ pswz;
                    *(uint2*)&Ps[w][prow * 64 + chunkx * 4] = pw;
                }
                ls += __shfl_xor(ls, 16, 64);
                ls += __shfl_xor(ls, 32, 64);
                lrun[nt] = lrun[nt] * al[nt] + ls;
            }

            // PV directly from the resident V buffer (no wait needed)
#pragma unroll
            for (int ks2 = 0; ks2 < 2; ks2++) {
                const int chp = ((ks2 * 8 + hi * 2) ^ pswz) * 4;
                const short8 pa0 = *(const short8*)&Ps[w][(0 * 16 + lr) * 64 + chp];
                const short8 pa1 = *(const short8*)&Ps[w][(1 * 16 + lr) * 64 + chp];
#pragma unroll
                for (int dt = 0; dt < 8; dt++) {
                    const int r = dt * 16 + lr;
                    const int ch = (ks2 * 4 + hi) ^ (r & 7);
                    const short8 vf = *(const short8*)&Vs[buf][(r * 8 + ch) * 8];
                    accO[0][dt] = __builtin_amdgcn_mfma_f32_16x16x32_bf16(pa0, vf, accO[0][dt], 0, 0, 0);
                    accO[1][dt] = __builtin_amdgcn_mfma_f32_16x16x32_bf16(pa1, vf, accO[1][dt], 0, 0, 0);
                }
            }
        }

        // single tile-end sync: my prefetch landed; all waves done reading buf
        asm volatile("s_waitcnt vmcnt(0)" ::: "memory");
        __builtin_amdgcn_s_barrier();
        buf ^= 1;
    }

#pragma unroll
    for (int nt = 0; nt < 2; nt++) {
        const float lv_own = 1.f / lrun[nt];
#pragma unroll
        for (int rg = 0; rg < 4; rg++) {
            const float lv = __shfl(lv_own, hi * 4 + rg, 64);
            unsigned short* orow = outb + (size_t)(b * TSEQ + q0w + nt * 16 + hi * 4 + rg) * DMODEL + h * DK;
#pragma unroll
            for (int dt = 0; dt < 8; dt++)
                orow[dt * 16 + lr] = f2bf(accO[nt][dt][rg] * lv);
        }
    }
}

// ===================== launch =====================
extern "C" void kernel_launch(void* const* d_in, const int* in_sizes, int n_in,
                              void* d_out, int out_size, void* d_ws, size_t ws_size,
                              hipStream_t stream)
{
    const float* x    = (const float*)d_in[0];
    const int*   pos  = (const int*)d_in[1];
    const float* Wqkv = (const float*)d_in[2];
    const float* Wo   = (const float*)d_in[3];
    float* out = (float*)d_out;

    unsigned short* qkvb  = (unsigned short*)d_ws;
    unsigned short* vtb   = qkvb + (size_t)25165824;
    unsigned short* xb    = vtb + (size_t)8388608;
    unsigned short* attnb = xb;                         // alias: xb dead after GEMM1
    unsigned short* wqkvb = xb + (size_t)8388608;
    unsigned short* wob   = wqkvb + (size_t)12582912;
    float2* tab = (float2*)(wob + (size_t)4194304);

    cast_all_bf16<<<12288, 256, 0, stream>>>(x, Wqkv, Wo, xb, wqkvb, wob);
    rope_table_kernel<<<512, 256, 0, stream>>>(pos, tab);

    // fused QKV projection + RoPE + V-transpose (4096 x 6144 x 2048)
    gemm_qkv_x<<<dim3(1024), 256, 0, stream>>>(xb, wqkvb, qkvb, vtb, tab);

    // paired-chunk flash attention: 256 blocks, KV-local XCD mapping
    attn_mfma4_kernel<<<dim3(256), 512, 0, stream>>>(qkvb, vtb, attnb);

    // out = attn @ Wo^T (4096 x 2048 x 2048), 512 tiles of 128x128
    gemm_o_x<<<dim3(512), 256, 0, stream>>>(attnb, wob, out);
}

// Round 13
// 254.766 us; speedup vs baseline: 1.3860x; 1.0081x over previous
//
#include <hip/hip_runtime.h>
#include <math.h>
#include <stdint.h>

#define NHEADS 16
#define DK 128
#define TSEQ 2048
#define DMODEL 2048

typedef __attribute__((ext_vector_type(8))) short short8;
typedef __attribute__((ext_vector_type(4))) float floatx4;

__device__ __forceinline__ float bf2f(unsigned short h) {
    return __uint_as_float(((unsigned int)h) << 16);
}
__device__ __forceinline__ unsigned short f2bf(float f) {
    unsigned int u = __float_as_uint(f);
    u += 0x7FFFu + ((u >> 16) & 1u);
    return (unsigned short)(u >> 16);
}
__device__ __forceinline__ void async16(unsigned short* lds, const unsigned short* g) {
    __builtin_amdgcn_global_load_lds(
        (const __attribute__((address_space(1))) uint32_t*)g,
        (__attribute__((address_space(3))) uint32_t*)lds, 16, 0, 0);
}

// ===================== merged cast f32->bf16 (x, Wqkv, Wo) + RoPE table =====================
#define NX8 1048576
#define NW8 1572864
#define NO8 524288
#define NCAST (NX8 + NW8 + NO8)
__global__ __launch_bounds__(256) void cast_rope_kernel(
    const float* __restrict__ x, const float* __restrict__ wqkv, const float* __restrict__ wo,
    const int* __restrict__ pos,
    unsigned short* __restrict__ xb, unsigned short* __restrict__ wqkvb,
    unsigned short* __restrict__ wob, float2* __restrict__ tab)
{
    const int i = blockIdx.x * 256 + threadIdx.x;
    if (i < NCAST) {
        const float* src; unsigned short* dst; int k;
        if (i < NX8)            { src = x;    dst = xb;    k = i; }
        else if (i < NX8 + NW8) { src = wqkv; dst = wqkvb; k = i - NX8; }
        else                    { src = wo;   dst = wob;   k = i - NX8 - NW8; }
        const float4* p4 = reinterpret_cast<const float4*>(src) + 2 * (size_t)k;
        const float4 a = p4[0], b = p4[1];
        uint32_t w0 = (uint32_t)f2bf(a.x) | ((uint32_t)f2bf(a.y) << 16);
        uint32_t w1 = (uint32_t)f2bf(a.z) | ((uint32_t)f2bf(a.w) << 16);
        uint32_t w2 = (uint32_t)f2bf(b.x) | ((uint32_t)f2bf(b.y) << 16);
        uint32_t w3 = (uint32_t)f2bf(b.z) | ((uint32_t)f2bf(b.w) << 16);
        uint4 o; o.x = w0; o.y = w1; o.z = w2; o.w = w3;
        *reinterpret_cast<uint4*>(dst + 8 * (size_t)k) = o;
    } else {
        const int idx = i - NCAST;              // 0 .. 2048*64-1
        const int tt = idx >> 6, pi = idx & 63;
        const double inv_freq = exp(-log(10000.0) * (double)pi / 64.0);
        const double ang = (double)pos[tt] * inv_freq;
        tab[idx] = make_float2((float)cos(ang), (float)sin(ang));
    }
}

// ===================== fused QKV GEMM, 128x192 x 2-blocks/CU (unchanged) =====================
__global__ __launch_bounds__(256, 2) void gemm_qkv_x(
    const unsigned short* __restrict__ A, const unsigned short* __restrict__ B,
    unsigned short* __restrict__ qkvb, unsigned short* __restrict__ vt,
    const float2* __restrict__ tab)
{
    const int K = DMODEL, N = 3 * DMODEL;
    __shared__ unsigned short As[2][128 * 64];   // 32 KB
    __shared__ unsigned short Bs[2][192 * 64];   // 48 KB

    const int t = threadIdx.x;
    const int lane = t & 63, w = t >> 6;
    const int wr = w >> 1, wc = w & 1;
    const int lr = lane & 15, hi = lane >> 4;

    const int bid = (int)blockIdx.x;
    const int xcd = bid & 7, local = bid >> 3;
    const int row0 = (local & 31) * 128;
    const int col0 = ((xcd << 2) | (local >> 5)) * 192;

    const int rr = t >> 3;
    const int cc = ((t & 7) ^ (rr & 7)) << 3;
    const unsigned short* aP = A + (size_t)(row0 + rr) * K + cc;
    const unsigned short* bP = B + (size_t)(col0 + rr) * K + cc;
    const size_t rstep = (size_t)32 * K;

    floatx4 acc[4][6];
#pragma unroll
    for (int m = 0; m < 4; m++)
#pragma unroll
        for (int n = 0; n < 6; n++)
#pragma unroll
            for (int e = 0; e < 4; e++) acc[m][n][e] = 0.f;

#define STAGE(nb, k0n) do { \
        async16(&As[nb][t * 8],          aP + (k0n)); \
        async16(&As[nb][(t + 256) * 8],  aP + rstep + (k0n)); \
        async16(&As[nb][(t + 512) * 8],  aP + 2 * rstep + (k0n)); \
        async16(&As[nb][(t + 768) * 8],  aP + 3 * rstep + (k0n)); \
        async16(&Bs[nb][t * 8],          bP + (k0n)); \
        async16(&Bs[nb][(t + 256) * 8],  bP + rstep + (k0n)); \
        async16(&Bs[nb][(t + 512) * 8],  bP + 2 * rstep + (k0n)); \
        async16(&Bs[nb][(t + 768) * 8],  bP + 3 * rstep + (k0n)); \
        async16(&Bs[nb][(t + 1024) * 8], bP + 4 * rstep + (k0n)); \
        async16(&Bs[nb][(t + 1280) * 8], bP + 5 * rstep + (k0n)); \
    } while (0)

    const int NT = K >> 6;
    const int ch0 = (hi ^ (lr & 7)) * 8;
    const int ch1 = ((4 + hi) ^ (lr & 7)) * 8;

    short8 av[4], bv[6];

#define RD_AV(Ac, ch) do { \
        _Pragma("unroll") \
        for (int m = 0; m < 4; m++) \
            av[m] = *(const short8*)&(Ac)[(wr * 64 + m * 16 + lr) * 64 + (ch)]; \
    } while (0)
#define RD_BV(Bc, ch) do { \
        _Pragma("unroll") \
        for (int n = 0; n < 6; n++) \
            bv[n] = *(const short8*)&(Bc)[(wc * 96 + n * 16 + lr) * 64 + (ch)]; \
    } while (0)
#define MFMA_ALL() do { \
        _Pragma("unroll") \
        for (int m = 0; m < 4; m++) \
            _Pragma("unroll") \
            for (int n = 0; n < 6; n++) \
                acc[m][n] = __builtin_amdgcn_mfma_f32_16x16x32_bf16(av[m], bv[n], acc[m][n], 0, 0, 0); \
    } while (0)

    STAGE(0, 0);

    for (int kt = 0; kt < NT; ++kt) {
        const int cur = kt & 1;
        const unsigned short* __restrict__ Ac = &As[cur][0];
        const unsigned short* __restrict__ Bc = &Bs[cur][0];
        const bool more = (kt + 1 < NT);

        if (more) {
            STAGE(cur ^ 1, (kt + 1) << 6);
            asm volatile("s_waitcnt vmcnt(10)" ::: "memory");
        } else {
            asm volatile("s_waitcnt vmcnt(0)" ::: "memory");
        }
        __builtin_amdgcn_s_barrier();

        RD_AV(Ac, ch0); RD_BV(Bc, ch0);
        asm volatile("s_waitcnt lgkmcnt(0)" ::: "memory");
        __builtin_amdgcn_sched_barrier(0);
        __builtin_amdgcn_s_setprio(1);
        MFMA_ALL();
        __builtin_amdgcn_s_setprio(0);

        RD_AV(Ac, ch1); RD_BV(Bc, ch1);
        asm volatile("s_waitcnt lgkmcnt(0)" ::: "memory");
        __builtin_amdgcn_sched_barrier(0);
        __builtin_amdgcn_s_setprio(1);
        MFMA_ALL();
        __builtin_amdgcn_s_setprio(0);

        __builtin_amdgcn_s_barrier();
    }
#undef STAGE
#undef RD_AV
#undef RD_BV
#undef MFMA_ALL

    const int par = lr & 1;
#pragma unroll
    for (int mi = 0; mi < 4; mi++) {
        const int row = row0 + wr * 64 + mi * 16 + hi * 4;
        const int tt = row & (TSEQ - 1);
        const int bb = row >> 11;
#pragma unroll
        for (int ni = 0; ni < 6; ni++) {
            const int col = col0 + wc * 96 + ni * 16 + lr;
            if (col < 2 * DMODEL) {
                const int pi = (col & 127) >> 1;
#pragma unroll
                for (int j = 0; j < 4; j++) {
                    const float2 cs = tab[(tt + j) * 64 + pi];
                    const float v = acc[mi][ni][j];
                    const float p = __shfl_xor(v, 1, 64);
                    const float o = par ? (p * cs.y + v * cs.x)
                                        : (v * cs.x - p * cs.y);
                    qkvb[(size_t)(row + j) * N + col] = f2bf(o);
                }
            } else {
                const int vcol = col - 2 * DMODEL;
                const int h = vcol >> 7, d = vcol & 127;
                uint2 pw;
                pw.x = (uint32_t)f2bf(acc[mi][ni][0]) | ((uint32_t)f2bf(acc[mi][ni][1]) << 16);
                pw.y = (uint32_t)f2bf(acc[mi][ni][2]) | ((uint32_t)f2bf(acc[mi][ni][3]) << 16);
                *(uint2*)&vt[(size_t)((bb * NHEADS + h) * DK + d) * TSEQ + tt] = pw;
            }
        }
    }
}

// ===================== output projection, 128x128 x 2-blocks/CU, f32 out (unchanged) =====================
__global__ __launch_bounds__(256, 2) void gemm_o_x(
    const unsigned short* __restrict__ A, const unsigned short* __restrict__ B,
    float* __restrict__ C)
{
    const int K = DMODEL, N = DMODEL;
    __shared__ unsigned short As[2][128 * 64];
    __shared__ unsigned short Bs[2][128 * 64];

    const int t = threadIdx.x;
    const int lane = t & 63, w = t >> 6;
    const int wr = w >> 1, wc = w & 1;
    const int lr = lane & 15, hi = lane >> 4;

    const int bid = (int)blockIdx.x;
    const int xcd = bid & 7, local = bid >> 3;
    const int row0 = (local & 31) * 128;
    const int col0 = ((xcd << 1) | (local >> 5)) * 128;

    const int rr = t >> 3;
    const int cc = ((t & 7) ^ (rr & 7)) << 3;
    const unsigned short* aP = A + (size_t)(row0 + rr) * K + cc;
    const unsigned short* bP = B + (size_t)(col0 + rr) * K + cc;
    const size_t rstep = (size_t)32 * K;

    floatx4 acc[4][4];
#pragma unroll
    for (int m = 0; m < 4; m++)
#pragma unroll
        for (int n = 0; n < 4; n++)
#pragma unroll
            for (int e = 0; e < 4; e++) acc[m][n][e] = 0.f;

#define STAGE(nb, k0n) do { \
        async16(&As[nb][t * 8],          aP + (k0n)); \
        async16(&As[nb][(t + 256) * 8],  aP + rstep + (k0n)); \
        async16(&As[nb][(t + 512) * 8],  aP + 2 * rstep + (k0n)); \
        async16(&As[nb][(t + 768) * 8],  aP + 3 * rstep + (k0n)); \
        async16(&Bs[nb][t * 8],          bP + (k0n)); \
        async16(&Bs[nb][(t + 256) * 8],  bP + rstep + (k0n)); \
        async16(&Bs[nb][(t + 512) * 8],  bP + 2 * rstep + (k0n)); \
        async16(&Bs[nb][(t + 768) * 8],  bP + 3 * rstep + (k0n)); \
    } while (0)

    const int NT = K >> 6;
    const int ch0 = (hi ^ (lr & 7)) * 8;
    const int ch1 = ((4 + hi) ^ (lr & 7)) * 8;

    short8 av[4], bv[4];

#define RD_AV(Ac, ch) do { \
        _Pragma("unroll") \
        for (int m = 0; m < 4; m++) \
            av[m] = *(const short8*)&(Ac)[(wr * 64 + m * 16 + lr) * 64 + (ch)]; \
    } while (0)
#define RD_BV(Bc, ch) do { \
        _Pragma("unroll") \
        for (int n = 0; n < 4; n++) \
            bv[n] = *(const short8*)&(Bc)[(wc * 64 + n * 16 + lr) * 64 + (ch)]; \
    } while (0)
#define MFMA_ALL() do { \
        _Pragma("unroll") \
        for (int m = 0; m < 4; m++) \
            _Pragma("unroll") \
            for (int n = 0; n < 4; n++) \
                acc[m][n] = __builtin_amdgcn_mfma_f32_16x16x32_bf16(av[m], bv[n], acc[m][n], 0, 0, 0); \
    } while (0)

    STAGE(0, 0);

    for (int kt = 0; kt < NT; ++kt) {
        const int cur = kt & 1;
        const unsigned short* __restrict__ Ac = &As[cur][0];
        const unsigned short* __restrict__ Bc = &Bs[cur][0];
        const bool more = (kt + 1 < NT);

        if (more) {
            STAGE(cur ^ 1, (kt + 1) << 6);
            asm volatile("s_waitcnt vmcnt(8)" ::: "memory");
        } else {
            asm volatile("s_waitcnt vmcnt(0)" ::: "memory");
        }
        __builtin_amdgcn_s_barrier();

        RD_AV(Ac, ch0); RD_BV(Bc, ch0);
        asm volatile("s_waitcnt lgkmcnt(0)" ::: "memory");
        __builtin_amdgcn_sched_barrier(0);
        __builtin_amdgcn_s_setprio(1);
        MFMA_ALL();
        __builtin_amdgcn_s_setprio(0);

        RD_AV(Ac, ch1); RD_BV(Bc, ch1);
        asm volatile("s_waitcnt lgkmcnt(0)" ::: "memory");
        __builtin_amdgcn_sched_barrier(0);
        __builtin_amdgcn_s_setprio(1);
        MFMA_ALL();
        __builtin_amdgcn_s_setprio(0);

        __builtin_amdgcn_s_barrier();
    }
#undef STAGE
#undef RD_AV
#undef RD_BV
#undef MFMA_ALL

#pragma unroll
    for (int mi = 0; mi < 4; mi++) {
        const int row = row0 + wr * 64 + mi * 16 + hi * 4;
#pragma unroll
        for (int ni = 0; ni < 4; ni++) {
            const int col = col0 + wc * 64 + ni * 16 + lr;
#pragma unroll
            for (int j = 0; j < 4; j++)
                C[(size_t)(row + j) * N + col] = acc[mi][ni][j];
        }
    }
}

// ===================== MFMA flash attention v5: 4-wave blocks, 2 blocks/CU =====================
// 512 blocks of 256 thr. Block = (bh, p, half): waves 0-1 own chunk p, waves 2-3
// own chunk 15-p; `half` selects 64-row half of each chunk. Per-block work constant;
// 2 independent blocks/CU overlap each other's tile-end drains. K+V dbuf,
// single vmcnt(0)+barrier per tile. bid&7 == bh&7 -> all blocks of a bh on one XCD.
__global__ __launch_bounds__(256, 2) void attn_mfma5_kernel(
    const unsigned short* __restrict__ qkvb, const unsigned short* __restrict__ vt,
    unsigned short* __restrict__ outb)
{
    __shared__ unsigned short Ks[2][64 * 128];   // 32 KB
    __shared__ unsigned short Vs[2][128 * 64];   // 32 KB
    __shared__ unsigned short Ps[4][32 * 64];    // 16 KB

    const int t = threadIdx.x;
    const int lane = t & 63, w = t >> 6;         // w in 0..3
    const int lr = lane & 15, hi = lane >> 4;
    const int bid  = (int)blockIdx.x;
    const int bh   = bid & 31;
    const int rest = bid >> 5;                   // 0..15
    const int p    = rest >> 1;                  // 0..7
    const int half = rest & 1;
    const int b = bh >> 4, h = bh & 15;
    const int chunk = (w < 2) ? p : (15 - p);
    const int q0w = chunk * 128 + half * 64 + (w & 1) * 32;
    const float scale = 0.08838834764831845f;
    const size_t QROW = 3 * DMODEL;

    const unsigned short* kg = qkvb + (size_t)b * TSEQ * QROW + DMODEL + h * DK;
    const unsigned short* vg = vt + (size_t)bh * DK * TSEQ;

    short8 qf[2][4];
    {
        const unsigned short* qbase = qkvb + (size_t)(b * TSEQ + q0w) * QROW + h * DK;
#pragma unroll
        for (int nt = 0; nt < 2; nt++)
#pragma unroll
            for (int ks = 0; ks < 4; ks++) {
                short8 raw = *(const short8*)(qbase + (size_t)(nt * 16 + lr) * QROW + ks * 32 + hi * 8);
                short8 sc;
#pragma unroll
                for (int e = 0; e < 8; e++)
                    sc[e] = (short)f2bf(bf2f((unsigned short)raw[e]) * scale);
                qf[nt][ks] = sc;
            }
    }

    // staging: 256 threads, 4 chunks each per matrix
    auto stageK = [&](int bufi, int kv0s) {
#pragma unroll
        for (int i = 0; i < 4; i++) {
            const int s = i * 256 + t;
            const int r = s >> 4;
            const int cc = (s & 15) ^ (r & 7);
            async16(&Ks[bufi][s * 8], kg + (size_t)(kv0s + r) * QROW + cc * 8);
        }
    };
    auto stageV = [&](int bufi, int kv0s) {
#pragma unroll
        for (int i = 0; i < 4; i++) {
            const int s = i * 256 + t;
            const int r = s >> 3;
            const int cc = (s & 7) ^ (r & 7);
            async16(&Vs[bufi][s * 8], vg + (size_t)r * TSEQ + kv0s + cc * 8);
        }
    };

    floatx4 accO[2][8];
#pragma unroll
    for (int nt = 0; nt < 2; nt++)
#pragma unroll
        for (int dt = 0; dt < 8; dt++)
#pragma unroll
            for (int e = 0; e < 4; e++) accO[nt][dt][e] = 0.f;
    float mrun[2] = {-1e30f, -1e30f};
    float lrun[2] = {0.f, 0.f};

    const int ntiles = (16 - p) * 2;   // heavy-chunk span
    int buf = 0;

    stageK(0, 0);
    stageV(0, 0);
    asm volatile("s_waitcnt vmcnt(0)" ::: "memory");
    __builtin_amdgcn_s_barrier();

    const int pswz = (lr & 7) << 1;

    for (int ti = 0; ti < ntiles; ti++) {
        const int kv0 = ti * 64;
        if (ti + 1 < ntiles) {
            stageK(buf ^ 1, kv0 + 64);
            stageV(buf ^ 1, kv0 + 64);
        }

        const bool active = (kv0 <= q0w + 31);

        if (active) {
            float al[2] = {1.f, 1.f};
            floatx4 st[4][2];
#pragma unroll
            for (int mt = 0; mt < 4; mt++)
#pragma unroll
                for (int nt = 0; nt < 2; nt++)
#pragma unroll
                    for (int e = 0; e < 4; e++) st[mt][nt][e] = 0.f;
#pragma unroll
            for (int mt = 0; mt < 4; mt++) {
                const int r = mt * 16 + lr;
#pragma unroll
                for (int ks = 0; ks < 4; ks++) {
                    const int ch = (ks * 4 + hi) ^ (r & 7);
                    const short8 kf = *(const short8*)&Ks[buf][(r * 16 + ch) * 8];
                    st[mt][0] = __builtin_amdgcn_mfma_f32_16x16x32_bf16(kf, qf[0][ks], st[mt][0], 0, 0, 0);
                    st[mt][1] = __builtin_amdgcn_mfma_f32_16x16x32_bf16(kf, qf[1][ks], st[mt][1], 0, 0, 0);
                }
            }
            if (kv0 + 63 > q0w) {
#pragma unroll
                for (int nt = 0; nt < 2; nt++) {
                    const int qg = q0w + nt * 16 + lr;
#pragma unroll
                    for (int mt = 0; mt < 4; mt++)
#pragma unroll
                        for (int rg = 0; rg < 4; rg++) {
                            const int kvg = kv0 + mt * 16 + hi * 4 + rg;
                            if (kvg > qg) st[mt][nt][rg] = -1e30f;
                        }
                }
            }
            float pm[2];
#pragma unroll
            for (int nt = 0; nt < 2; nt++) {
                float m = -1e30f;
#pragma unroll
                for (int mt = 0; mt < 4; mt++)
#pragma unroll
                    for (int rg = 0; rg < 4; rg++) m = fmaxf(m, st[mt][nt][rg]);
                m = fmaxf(m, __shfl_xor(m, 16, 64));
                m = fmaxf(m, __shfl_xor(m, 32, 64));
                pm[nt] = m;
            }
            if (__any((pm[0] > mrun[0] + 8.f) || (pm[1] > mrun[1] + 8.f))) {
#pragma unroll
                for (int nt = 0; nt < 2; nt++) {
                    const float mn = fmaxf(mrun[nt], pm[nt]);
                    al[nt] = __expf(mrun[nt] - mn);
                    mrun[nt] = mn;
                }
#pragma unroll
                for (int rg = 0; rg < 4; rg++) {
                    const float a0 = __shfl(al[0], hi * 4 + rg, 64);
                    const float a1 = __shfl(al[1], hi * 4 + rg, 64);
#pragma unroll
                    for (int dt = 0; dt < 8; dt++) {
                        accO[0][dt][rg] *= a0;
                        accO[1][dt][rg] *= a1;
                    }
                }
            }
#pragma unroll
            for (int nt = 0; nt < 2; nt++) {
                float ls = 0.f;
                const int prow = nt * 16 + lr;
#pragma unroll
                for (int mt = 0; mt < 4; mt++) {
                    float pv[4];
#pragma unroll
                    for (int rg = 0; rg < 4; rg++) {
                        pv[rg] = __expf(st[mt][nt][rg] - mrun[nt]);
                        ls += pv[rg];
                    }
                    uint2 pw;
                    pw.x = (uint32_t)f2bf(pv[0]) | ((uint32_t)f2bf(pv[1]) << 16);
                    pw.y = (uint32_t)f2bf(pv[2]) | ((uint32_t)f2bf(pv[3]) << 16);
                    const int chunkx = (mt * 4 + hi) ^ pswz;
                    *(uint2*)&Ps[w][prow * 64 + chunkx * 4] = pw;
                }
                ls += __shfl_xor(ls, 16, 64);
                ls += __shfl_xor(ls, 32, 64);
                lrun[nt] = lrun[nt] * al[nt] + ls;
            }

            // PV from resident V buffer
#pragma unroll
            for (int ks2 = 0; ks2 < 2; ks2++) {
                const int chp = ((ks2 * 8 + hi * 2) ^ pswz) * 4;
                const short8 pa0 = *(const short8*)&Ps[w][(0 * 16 + lr) * 64 + chp];
                const short8 pa1 = *(const short8*)&Ps[w][(1 * 16 + lr) * 64 + chp];
#pragma unroll
                for (int dt = 0; dt < 8; dt++) {
                    const int r = dt * 16 + lr;
                    const int ch = (ks2 * 4 + hi) ^ (r & 7);
                    const short8 vf = *(const short8*)&Vs[buf][(r * 8 + ch) * 8];
                    accO[0][dt] = __builtin_amdgcn_mfma_f32_16x16x32_bf16(pa0, vf, accO[0][dt], 0, 0, 0);
                    accO[1][dt] = __builtin_amdgcn_mfma_f32_16x16x32_bf16(pa1, vf, accO[1][dt], 0, 0, 0);
                }
            }
        }

        asm volatile("s_waitcnt vmcnt(0)" ::: "memory");
        __builtin_amdgcn_s_barrier();
        buf ^= 1;
    }

#pragma unroll
    for (int nt = 0; nt < 2; nt++) {
        const float lv_own = 1.f / lrun[nt];
#pragma unroll
        for (int rg = 0; rg < 4; rg++) {
            const float lv = __shfl(lv_own, hi * 4 + rg, 64);
            unsigned short* orow = outb + (size_t)(b * TSEQ + q0w + nt * 16 + hi * 4 + rg) * DMODEL + h * DK;
#pragma unroll
            for (int dt = 0; dt < 8; dt++)
                orow[dt * 16 + lr] = f2bf(accO[nt][dt][rg] * lv);
        }
    }
}

// ===================== launch =====================
extern "C" void kernel_launch(void* const* d_in, const int* in_sizes, int n_in,
                              void* d_out, int out_size, void* d_ws, size_t ws_size,
                              hipStream_t stream)
{
    const float* x    = (const float*)d_in[0];
    const int*   pos  = (const int*)d_in[1];
    const float* Wqkv = (const float*)d_in[2];
    const float* Wo   = (const float*)d_in[3];
    float* out = (float*)d_out;

    unsigned short* qkvb  = (unsigned short*)d_ws;
    unsigned short* vtb   = qkvb + (size_t)25165824;
    unsigned short* xb    = vtb + (size_t)8388608;
    unsigned short* attnb = xb;                         // alias: xb dead after GEMM1
    unsigned short* wqkvb = xb + (size_t)8388608;
    unsigned short* wob   = wqkvb + (size_t)12582912;
    float2* tab = (float2*)(wob + (size_t)4194304);

    // merged cast (x, Wqkv, Wo) + RoPE table: 12288 + 512 blocks
    cast_rope_kernel<<<12800, 256, 0, stream>>>(x, Wqkv, Wo, pos, xb, wqkvb, wob, tab);

    // fused QKV projection + RoPE + V-transpose (4096 x 6144 x 2048)
    gemm_qkv_x<<<dim3(1024), 256, 0, stream>>>(xb, wqkvb, qkvb, vtb, tab);

    // paired half-chunk flash attention: 512 blocks x 256 thr, 2 blocks/CU
    attn_mfma5_kernel<<<dim3(512), 256, 0, stream>>>(qkvb, vtb, attnb);

    // out = attn @ Wo^T (4096 x 2048 x 2048), 512 tiles of 128x128
    gemm_o_x<<<dim3(512), 256, 0, stream>>>(attnb, wob, out);
}

// Round 15
// 251.045 us; speedup vs baseline: 1.4065x; 1.0148x over previous
//
#include <hip/hip_runtime.h>
#include <math.h>
#include <stdint.h>

#define NHEADS 16
#define DK 128
#define TSEQ 2048
#define DMODEL 2048

typedef __attribute__((ext_vector_type(8))) short short8;
typedef __attribute__((ext_vector_type(4))) float floatx4;

__device__ __forceinline__ float bf2f(unsigned short h) {
    return __uint_as_float(((unsigned int)h) << 16);
}
__device__ __forceinline__ unsigned short f2bf(float f) {
    unsigned int u = __float_as_uint(f);
    u += 0x7FFFu + ((u >> 16) & 1u);
    return (unsigned short)(u >> 16);
}
__device__ __forceinline__ void async16(unsigned short* lds, const unsigned short* g) {
    __builtin_amdgcn_global_load_lds(
        (const __attribute__((address_space(1))) uint32_t*)g,
        (__attribute__((address_space(3))) uint32_t*)lds, 16, 0, 0);
}
__device__ __forceinline__ float fexp2(float x) {
    return __builtin_amdgcn_exp2f(x);   // native v_exp_f32 (2^x)
}

// ===================== cast f32->bf16 (x, Wqkv) + RoPE table (Wo moved to attn) =====================
#define NX8 1048576
#define NW8 1572864
#define NO8 524288
#define NCAST2 (NX8 + NW8)
__global__ __launch_bounds__(256) void cast_rope_kernel(
    const float* __restrict__ x, const float* __restrict__ wqkv,
    const int* __restrict__ pos,
    unsigned short* __restrict__ xb, unsigned short* __restrict__ wqkvb,
    float2* __restrict__ tab)
{
    const int i = blockIdx.x * 256 + threadIdx.x;
    if (i < NCAST2) {
        const float* src; unsigned short* dst; int k;
        if (i < NX8) { src = x;    dst = xb;    k = i; }
        else         { src = wqkv; dst = wqkvb; k = i - NX8; }
        const float4* p4 = reinterpret_cast<const float4*>(src) + 2 * (size_t)k;
        const float4 a = p4[0], b = p4[1];
        uint32_t w0 = (uint32_t)f2bf(a.x) | ((uint32_t)f2bf(a.y) << 16);
        uint32_t w1 = (uint32_t)f2bf(a.z) | ((uint32_t)f2bf(a.w) << 16);
        uint32_t w2 = (uint32_t)f2bf(b.x) | ((uint32_t)f2bf(b.y) << 16);
        uint32_t w3 = (uint32_t)f2bf(b.z) | ((uint32_t)f2bf(b.w) << 16);
        uint4 o; o.x = w0; o.y = w1; o.z = w2; o.w = w3;
        *reinterpret_cast<uint4*>(dst + 8 * (size_t)k) = o;
    } else {
        const int idx = i - NCAST2;             // 0 .. 2048*64-1
        const int tt = idx >> 6, pi = idx & 63;
        const double inv_freq = exp(-log(10000.0) * (double)pi / 64.0);
        const double ang = (double)pos[tt] * inv_freq;
        tab[idx] = make_float2((float)cos(ang), (float)sin(ang));
    }
}

// ===================== fused QKV GEMM, 128x192 x 2-blocks/CU (unchanged) =====================
__global__ __launch_bounds__(256, 2) void gemm_qkv_x(
    const unsigned short* __restrict__ A, const unsigned short* __restrict__ B,
    unsigned short* __restrict__ qkvb, unsigned short* __restrict__ vt,
    const float2* __restrict__ tab)
{
    const int K = DMODEL, N = 3 * DMODEL;
    __shared__ unsigned short As[2][128 * 64];   // 32 KB
    __shared__ unsigned short Bs[2][192 * 64];   // 48 KB

    const int t = threadIdx.x;
    const int lane = t & 63, w = t >> 6;
    const int wr = w >> 1, wc = w & 1;
    const int lr = lane & 15, hi = lane >> 4;

    const int bid = (int)blockIdx.x;
    const int xcd = bid & 7, local = bid >> 3;
    const int row0 = (local & 31) * 128;
    const int col0 = ((xcd << 2) | (local >> 5)) * 192;

    const int rr = t >> 3;
    const int cc = ((t & 7) ^ (rr & 7)) << 3;
    const unsigned short* aP = A + (size_t)(row0 + rr) * K + cc;
    const unsigned short* bP = B + (size_t)(col0 + rr) * K + cc;
    const size_t rstep = (size_t)32 * K;

    floatx4 acc[4][6];
#pragma unroll
    for (int m = 0; m < 4; m++)
#pragma unroll
        for (int n = 0; n < 6; n++)
#pragma unroll
            for (int e = 0; e < 4; e++) acc[m][n][e] = 0.f;

#define STAGE(nb, k0n) do { \
        async16(&As[nb][t * 8],          aP + (k0n)); \
        async16(&As[nb][(t + 256) * 8],  aP + rstep + (k0n)); \
        async16(&As[nb][(t + 512) * 8],  aP + 2 * rstep + (k0n)); \
        async16(&As[nb][(t + 768) * 8],  aP + 3 * rstep + (k0n)); \
        async16(&Bs[nb][t * 8],          bP + (k0n)); \
        async16(&Bs[nb][(t + 256) * 8],  bP + rstep + (k0n)); \
        async16(&Bs[nb][(t + 512) * 8],  bP + 2 * rstep + (k0n)); \
        async16(&Bs[nb][(t + 768) * 8],  bP + 3 * rstep + (k0n)); \
        async16(&Bs[nb][(t + 1024) * 8], bP + 4 * rstep + (k0n)); \
        async16(&Bs[nb][(t + 1280) * 8], bP + 5 * rstep + (k0n)); \
    } while (0)

    const int NT = K >> 6;
    const int ch0 = (hi ^ (lr & 7)) * 8;
    const int ch1 = ((4 + hi) ^ (lr & 7)) * 8;

    short8 av[4], bv[6];

#define RD_AV(Ac, ch) do { \
        _Pragma("unroll") \
        for (int m = 0; m < 4; m++) \
            av[m] = *(const short8*)&(Ac)[(wr * 64 + m * 16 + lr) * 64 + (ch)]; \
    } while (0)
#define RD_BV(Bc, ch) do { \
        _Pragma("unroll") \
        for (int n = 0; n < 6; n++) \
            bv[n] = *(const short8*)&(Bc)[(wc * 96 + n * 16 + lr) * 64 + (ch)]; \
    } while (0)
#define MFMA_ALL() do { \
        _Pragma("unroll") \
        for (int m = 0; m < 4; m++) \
            _Pragma("unroll") \
            for (int n = 0; n < 6; n++) \
                acc[m][n] = __builtin_amdgcn_mfma_f32_16x16x32_bf16(av[m], bv[n], acc[m][n], 0, 0, 0); \
    } while (0)

    STAGE(0, 0);

    for (int kt = 0; kt < NT; ++kt) {
        const int cur = kt & 1;
        const unsigned short* __restrict__ Ac = &As[cur][0];
        const unsigned short* __restrict__ Bc = &Bs[cur][0];
        const bool more = (kt + 1 < NT);

        if (more) {
            STAGE(cur ^ 1, (kt + 1) << 6);
            asm volatile("s_waitcnt vmcnt(10)" ::: "memory");
        } else {
            asm volatile("s_waitcnt vmcnt(0)" ::: "memory");
        }
        __builtin_amdgcn_s_barrier();

        RD_AV(Ac, ch0); RD_BV(Bc, ch0);
        asm volatile("s_waitcnt lgkmcnt(0)" ::: "memory");
        __builtin_amdgcn_sched_barrier(0);
        __builtin_amdgcn_s_setprio(1);
        MFMA_ALL();
        __builtin_amdgcn_s_setprio(0);

        RD_AV(Ac, ch1); RD_BV(Bc, ch1);
        asm volatile("s_waitcnt lgkmcnt(0)" ::: "memory");
        __builtin_amdgcn_sched_barrier(0);
        __builtin_amdgcn_s_setprio(1);
        MFMA_ALL();
        __builtin_amdgcn_s_setprio(0);

        __builtin_amdgcn_s_barrier();
    }
#undef STAGE
#undef RD_AV
#undef RD_BV
#undef MFMA_ALL

    const int par = lr & 1;
#pragma unroll
    for (int mi = 0; mi < 4; mi++) {
        const int row = row0 + wr * 64 + mi * 16 + hi * 4;
        const int tt = row & (TSEQ - 1);
        const int bb = row >> 11;
#pragma unroll
        for (int ni = 0; ni < 6; ni++) {
            const int col = col0 + wc * 96 + ni * 16 + lr;
            if (col < 2 * DMODEL) {
                const int pi = (col & 127) >> 1;
#pragma unroll
                for (int j = 0; j < 4; j++) {
                    const float2 cs = tab[(tt + j) * 64 + pi];
                    const float v = acc[mi][ni][j];
                    const float p = __shfl_xor(v, 1, 64);
                    const float o = par ? (p * cs.y + v * cs.x)
                                        : (v * cs.x - p * cs.y);
                    qkvb[(size_t)(row + j) * N + col] = f2bf(o);
                }
            } else {
                const int vcol = col - 2 * DMODEL;
                const int h = vcol >> 7, d = vcol & 127;
                uint2 pw;
                pw.x = (uint32_t)f2bf(acc[mi][ni][0]) | ((uint32_t)f2bf(acc[mi][ni][1]) << 16);
                pw.y = (uint32_t)f2bf(acc[mi][ni][2]) | ((uint32_t)f2bf(acc[mi][ni][3]) << 16);
                *(uint2*)&vt[(size_t)((bb * NHEADS + h) * DK + d) * TSEQ + tt] = pw;
            }
        }
    }
}

// ===================== output projection, 128x128 x 2-blocks/CU, f32 out (unchanged) =====================
__global__ __launch_bounds__(256, 2) void gemm_o_x(
    const unsigned short* __restrict__ A, const unsigned short* __restrict__ B,
    float* __restrict__ C)
{
    const int K = DMODEL, N = DMODEL;
    __shared__ unsigned short As[2][128 * 64];
    __shared__ unsigned short Bs[2][128 * 64];

    const int t = threadIdx.x;
    const int lane = t & 63, w = t >> 6;
    const int wr = w >> 1, wc = w & 1;
    const int lr = lane & 15, hi = lane >> 4;

    const int bid = (int)blockIdx.x;
    const int xcd = bid & 7, local = bid >> 3;
    const int row0 = (local & 31) * 128;
    const int col0 = ((xcd << 1) | (local >> 5)) * 128;

    const int rr = t >> 3;
    const int cc = ((t & 7) ^ (rr & 7)) << 3;
    const unsigned short* aP = A + (size_t)(row0 + rr) * K + cc;
    const unsigned short* bP = B + (size_t)(col0 + rr) * K + cc;
    const size_t rstep = (size_t)32 * K;

    floatx4 acc[4][4];
#pragma unroll
    for (int m = 0; m < 4; m++)
#pragma unroll
        for (int n = 0; n < 4; n++)
#pragma unroll
            for (int e = 0; e < 4; e++) acc[m][n][e] = 0.f;

#define STAGE(nb, k0n) do { \
        async16(&As[nb][t * 8],          aP + (k0n)); \
        async16(&As[nb][(t + 256) * 8],  aP + rstep + (k0n)); \
        async16(&As[nb][(t + 512) * 8],  aP + 2 * rstep + (k0n)); \
        async16(&As[nb][(t + 768) * 8],  aP + 3 * rstep + (k0n)); \
        async16(&Bs[nb][t * 8],          bP + (k0n)); \
        async16(&Bs[nb][(t + 256) * 8],  bP + rstep + (k0n)); \
        async16(&Bs[nb][(t + 512) * 8],  bP + 2 * rstep + (k0n)); \
        async16(&Bs[nb][(t + 768) * 8],  bP + 3 * rstep + (k0n)); \
    } while (0)

    const int NT = K >> 6;
    const int ch0 = (hi ^ (lr & 7)) * 8;
    const int ch1 = ((4 + hi) ^ (lr & 7)) * 8;

    short8 av[4], bv[4];

#define RD_AV(Ac, ch) do { \
        _Pragma("unroll") \
        for (int m = 0; m < 4; m++) \
            av[m] = *(const short8*)&(Ac)[(wr * 64 + m * 16 + lr) * 64 + (ch)]; \
    } while (0)
#define RD_BV(Bc, ch) do { \
        _Pragma("unroll") \
        for (int n = 0; n < 4; n++) \
            bv[n] = *(const short8*)&(Bc)[(wc * 64 + n * 16 + lr) * 64 + (ch)]; \
    } while (0)
#define MFMA_ALL() do { \
        _Pragma("unroll") \
        for (int m = 0; m < 4; m++) \
            _Pragma("unroll") \
            for (int n = 0; n < 4; n++) \
                acc[m][n] = __builtin_amdgcn_mfma_f32_16x16x32_bf16(av[m], bv[n], acc[m][n], 0, 0, 0); \
    } while (0)

    STAGE(0, 0);

    for (int kt = 0; kt < NT; ++kt) {
        const int cur = kt & 1;
        const unsigned short* __restrict__ Ac = &As[cur][0];
        const unsigned short* __restrict__ Bc = &Bs[cur][0];
        const bool more = (kt + 1 < NT);

        if (more) {
            STAGE(cur ^ 1, (kt + 1) << 6);
            asm volatile("s_waitcnt vmcnt(8)" ::: "memory");
        } else {
            asm volatile("s_waitcnt vmcnt(0)" ::: "memory");
        }
        __builtin_amdgcn_s_barrier();

        RD_AV(Ac, ch0); RD_BV(Bc, ch0);
        asm volatile("s_waitcnt lgkmcnt(0)" ::: "memory");
        __builtin_amdgcn_sched_barrier(0);
        __builtin_amdgcn_s_setprio(1);
        MFMA_ALL();
        __builtin_amdgcn_s_setprio(0);

        RD_AV(Ac, ch1); RD_BV(Bc, ch1);
        asm volatile("s_waitcnt lgkmcnt(0)" ::: "memory");
        __builtin_amdgcn_sched_barrier(0);
        __builtin_amdgcn_s_setprio(1);
        MFMA_ALL();
        __builtin_amdgcn_s_setprio(0);

        __builtin_amdgcn_s_barrier();
    }
#undef STAGE
#undef RD_AV
#undef RD_BV
#undef MFMA_ALL

#pragma unroll
    for (int mi = 0; mi < 4; mi++) {
        const int row = row0 + wr * 64 + mi * 16 + hi * 4;
#pragma unroll
        for (int ni = 0; ni < 4; ni++) {
            const int col = col0 + wc * 64 + ni * 16 + lr;
#pragma unroll
            for (int j = 0; j < 4; j++)
                C[(size_t)(row + j) * N + col] = acc[mi][ni][j];
        }
    }
}

// ===================== MFMA flash attention v6: setprio + exp2 + fused Wo cast =====================
__global__ __launch_bounds__(256, 2) void attn_mfma6_kernel(
    const unsigned short* __restrict__ qkvb, const unsigned short* __restrict__ vt,
    unsigned short* __restrict__ outb,
    const float* __restrict__ wo, unsigned short* __restrict__ wob)
{
    __shared__ unsigned short Ks[2][64 * 128];   // 32 KB
    __shared__ unsigned short Vs[2][128 * 64];   // 32 KB
    __shared__ unsigned short Ps[4][32 * 64];    // 16 KB

    const int t = threadIdx.x;
    const int lane = t & 63, w = t >> 6;
    const int lr = lane & 15, hi = lane >> 4;
    const int bid  = (int)blockIdx.x;

    // ---- fused Wo cast: 512 blocks x 256 thr x 4 chunks of 8 f32 ----
    {
        const int ci = bid * 256 + t;           // 0..131071
#pragma unroll
        for (int i = 0; i < 4; i++) {
            const int k = ci + i * 131072;      // 0..524287 (8 f32 each)
            const float4* p4 = reinterpret_cast<const float4*>(wo) + 2 * (size_t)k;
            const float4 a = p4[0], b = p4[1];
            uint4 o;
            o.x = (uint32_t)f2bf(a.x) | ((uint32_t)f2bf(a.y) << 16);
            o.y = (uint32_t)f2bf(a.z) | ((uint32_t)f2bf(a.w) << 16);
            o.z = (uint32_t)f2bf(b.x) | ((uint32_t)f2bf(b.y) << 16);
            o.w = (uint32_t)f2bf(b.z) | ((uint32_t)f2bf(b.w) << 16);
            *reinterpret_cast<uint4*>(wob + 8 * (size_t)k) = o;
        }
    }

    const int bh   = bid & 31;
    const int rest = bid >> 5;
    const int p    = rest >> 1;
    const int half = rest & 1;
    const int b = bh >> 4, h = bh & 15;
    const int chunk = (w < 2) ? p : (15 - p);
    const int q0w = chunk * 128 + half * 64 + (w & 1) * 32;
    const float scale2 = 0.08838834764831845f * 1.4426950408889634f;   // 1/sqrt(128) * log2(e)
    const float THR = 8.f * 1.4426950408889634f;
    const size_t QROW = 3 * DMODEL;

    const unsigned short* kg = qkvb + (size_t)b * TSEQ * QROW + DMODEL + h * DK;
    const unsigned short* vg = vt + (size_t)bh * DK * TSEQ;

    short8 qf[2][4];
    {
        const unsigned short* qbase = qkvb + (size_t)(b * TSEQ + q0w) * QROW + h * DK;
#pragma unroll
        for (int nt = 0; nt < 2; nt++)
#pragma unroll
            for (int ks = 0; ks < 4; ks++) {
                short8 raw = *(const short8*)(qbase + (size_t)(nt * 16 + lr) * QROW + ks * 32 + hi * 8);
                short8 sc;
#pragma unroll
                for (int e = 0; e < 8; e++)
                    sc[e] = (short)f2bf(bf2f((unsigned short)raw[e]) * scale2);
                qf[nt][ks] = sc;
            }
    }

    auto stageK = [&](int bufi, int kv0s) {
#pragma unroll
        for (int i = 0; i < 4; i++) {
            const int s = i * 256 + t;
            const int r = s >> 4;
            const int cc = (s & 15) ^ (r & 7);
            async16(&Ks[bufi][s * 8], kg + (size_t)(kv0s + r) * QROW + cc * 8);
        }
    };
    auto stageV = [&](int bufi, int kv0s) {
#pragma unroll
        for (int i = 0; i < 4; i++) {
            const int s = i * 256 + t;
            const int r = s >> 3;
            const int cc = (s & 7) ^ (r & 7);
            async16(&Vs[bufi][s * 8], vg + (size_t)r * TSEQ + kv0s + cc * 8);
        }
    };

    floatx4 accO[2][8];
#pragma unroll
    for (int nt = 0; nt < 2; nt++)
#pragma unroll
        for (int dt = 0; dt < 8; dt++)
#pragma unroll
            for (int e = 0; e < 4; e++) accO[nt][dt][e] = 0.f;
    float mrun[2] = {-1e30f, -1e30f};
    float lrun[2] = {0.f, 0.f};

    const int ntiles = (16 - p) * 2;
    int buf = 0;

    stageK(0, 0);
    stageV(0, 0);
    asm volatile("s_waitcnt vmcnt(0)" ::: "memory");
    __builtin_amdgcn_s_barrier();

    const int pswz = (lr & 7) << 1;

    for (int ti = 0; ti < ntiles; ti++) {
        const int kv0 = ti * 64;
        if (ti + 1 < ntiles) {
            stageK(buf ^ 1, kv0 + 64);
            stageV(buf ^ 1, kv0 + 64);
        }

        const bool active = (kv0 <= q0w + 31);

        if (active) {
            float al[2] = {1.f, 1.f};
            floatx4 st[4][2];
#pragma unroll
            for (int mt = 0; mt < 4; mt++)
#pragma unroll
                for (int nt = 0; nt < 2; nt++)
#pragma unroll
                    for (int e = 0; e < 4; e++) st[mt][nt][e] = 0.f;
            __builtin_amdgcn_s_setprio(1);
#pragma unroll
            for (int mt = 0; mt < 4; mt++) {
                const int r = mt * 16 + lr;
#pragma unroll
                for (int ks = 0; ks < 4; ks++) {
                    const int ch = (ks * 4 + hi) ^ (r & 7);
                    const short8 kf = *(const short8*)&Ks[buf][(r * 16 + ch) * 8];
                    st[mt][0] = __builtin_amdgcn_mfma_f32_16x16x32_bf16(kf, qf[0][ks], st[mt][0], 0, 0, 0);
                    st[mt][1] = __builtin_amdgcn_mfma_f32_16x16x32_bf16(kf, qf[1][ks], st[mt][1], 0, 0, 0);
                }
            }
            __builtin_amdgcn_s_setprio(0);
            if (kv0 + 63 > q0w) {
#pragma unroll
                for (int nt = 0; nt < 2; nt++) {
                    const int qg = q0w + nt * 16 + lr;
#pragma unroll
                    for (int mt = 0; mt < 4; mt++)
#pragma unroll
                        for (int rg = 0; rg < 4; rg++) {
                            const int kvg = kv0 + mt * 16 + hi * 4 + rg;
                            if (kvg > qg) st[mt][nt][rg] = -1e30f;
                        }
                }
            }
            float pm[2];
#pragma unroll
            for (int nt = 0; nt < 2; nt++) {
                float m = -1e30f;
#pragma unroll
                for (int mt = 0; mt < 4; mt++)
#pragma unroll
                    for (int rg = 0; rg < 4; rg++) m = fmaxf(m, st[mt][nt][rg]);
                m = fmaxf(m, __shfl_xor(m, 16, 64));
                m = fmaxf(m, __shfl_xor(m, 32, 64));
                pm[nt] = m;
            }
            if (__any((pm[0] > mrun[0] + THR) || (pm[1] > mrun[1] + THR))) {
#pragma unroll
                for (int nt = 0; nt < 2; nt++) {
                    const float mn = fmaxf(mrun[nt], pm[nt]);
                    al[nt] = fexp2(mrun[nt] - mn);
                    mrun[nt] = mn;
                }
#pragma unroll
                for (int rg = 0; rg < 4; rg++) {
                    const float a0 = __shfl(al[0], hi * 4 + rg, 64);
                    const float a1 = __shfl(al[1], hi * 4 + rg, 64);
#pragma unroll
                    for (int dt = 0; dt < 8; dt++) {
                        accO[0][dt][rg] *= a0;
                        accO[1][dt][rg] *= a1;
                    }
                }
            }
#pragma unroll
            for (int nt = 0; nt < 2; nt++) {
                float ls = 0.f;
                const int prow = nt * 16 + lr;
#pragma unroll
                for (int mt = 0; mt < 4; mt++) {
                    float pv[4];
#pragma unroll
                    for (int rg = 0; rg < 4; rg++) {
                        pv[rg] = fexp2(st[mt][nt][rg] - mrun[nt]);
                        ls += pv[rg];
                    }
                    uint2 pw;
                    pw.x = (uint32_t)f2bf(pv[0]) | ((uint32_t)f2bf(pv[1]) << 16);
                    pw.y = (uint32_t)f2bf(pv[2]) | ((uint32_t)f2bf(pv[3]) << 16);
                    const int chunkx = (mt * 4 + hi) ^ pswz;
                    *(uint2*)&Ps[w][prow * 64 + chunkx * 4] = pw;
                }
                ls += __shfl_xor(ls, 16, 64);
                ls += __shfl_xor(ls, 32, 64);
                lrun[nt] = lrun[nt] * al[nt] + ls;
            }

            __builtin_amdgcn_s_setprio(1);
#pragma unroll
            for (int ks2 = 0; ks2 < 2; ks2++) {
                const int chp = ((ks2 * 8 + hi * 2) ^ pswz) * 4;
                const short8 pa0 = *(const short8*)&Ps[w][(0 * 16 + lr) * 64 + chp];
                const short8 pa1 = *(const short8*)&Ps[w][(1 * 16 + lr) * 64 + chp];
#pragma unroll
                for (int dt = 0; dt < 8; dt++) {
                    const int r = dt * 16 + lr;
                    const int ch = (ks2 * 4 + hi) ^ (r & 7);
                    const short8 vf = *(const short8*)&Vs[buf][(r * 8 + ch) * 8];
                    accO[0][dt] = __builtin_amdgcn_mfma_f32_16x16x32_bf16(pa0, vf, accO[0][dt], 0, 0, 0);
                    accO[1][dt] = __builtin_amdgcn_mfma_f32_16x16x32_bf16(pa1, vf, accO[1][dt], 0, 0, 0);
                }
            }
            __builtin_amdgcn_s_setprio(0);
        }

        asm volatile("s_waitcnt vmcnt(0)" ::: "memory");
        __builtin_amdgcn_s_barrier();
        buf ^= 1;
    }

#pragma unroll
    for (int nt = 0; nt < 2; nt++) {
        const float lv_own = 1.f / lrun[nt];
#pragma unroll
        for (int rg = 0; rg < 4; rg++) {
            const float lv = __shfl(lv_own, hi * 4 + rg, 64);
            unsigned short* orow = outb + (size_t)(b * TSEQ + q0w + nt * 16 + hi * 4 + rg) * DMODEL + h * DK;
#pragma unroll
            for (int dt = 0; dt < 8; dt++)
                orow[dt * 16 + lr] = f2bf(accO[nt][dt][rg] * lv);
        }
    }
}

// ===================== launch =====================
extern "C" void kernel_launch(void* const* d_in, const int* in_sizes, int n_in,
                              void* d_out, int out_size, void* d_ws, size_t ws_size,
                              hipStream_t stream)
{
    const float* x    = (const float*)d_in[0];
    const int*   pos  = (const int*)d_in[1];
    const float* Wqkv = (const float*)d_in[2];
    const float* Wo   = (const float*)d_in[3];
    float* out = (float*)d_out;

    unsigned short* qkvb  = (unsigned short*)d_ws;
    unsigned short* vtb   = qkvb + (size_t)25165824;
    unsigned short* xb    = vtb + (size_t)8388608;
    unsigned short* attnb = xb;                         // alias: xb dead after GEMM1
    unsigned short* wqkvb = xb + (size_t)8388608;
    unsigned short* wob   = wqkvb + (size_t)12582912;
    float2* tab = (float2*)(wob + (size_t)4194304);

    // cast (x, Wqkv) + RoPE table: 10240 + 512 blocks
    cast_rope_kernel<<<10752, 256, 0, stream>>>(x, Wqkv, pos, xb, wqkvb, tab);

    // fused QKV projection + RoPE + V-transpose (4096 x 6144 x 2048)
    gemm_qkv_x<<<dim3(1024), 256, 0, stream>>>(xb, wqkvb, qkvb, vtb, tab);

    // paired half-chunk flash attention (+ fused Wo cast): 512 blocks x 256 thr
    attn_mfma6_kernel<<<dim3(512), 256, 0, stream>>>(qkvb, vtb, attnb, Wo, wob);

    // out = attn @ Wo^T (4096 x 2048 x 2048), 512 tiles of 128x128
    gemm_o_x<<<dim3(512), 256, 0, stream>>>(attnb, wob, out);
}

// Round 16
// 250.664 us; speedup vs baseline: 1.4086x; 1.0015x over previous
//
#include <hip/hip_runtime.h>
#include <math.h>
#include <stdint.h>

#define NHEADS 16
#define DK 128
#define TSEQ 2048
#define DMODEL 2048

typedef __attribute__((ext_vector_type(8))) short short8;
typedef __attribute__((ext_vector_type(4))) float floatx4;

__device__ __forceinline__ float bf2f(unsigned short h) {
    return __uint_as_float(((unsigned int)h) << 16);
}
__device__ __forceinline__ unsigned short f2bf(float f) {
    unsigned int u = __float_as_uint(f);
    u += 0x7FFFu + ((u >> 16) & 1u);
    return (unsigned short)(u >> 16);
}
__device__ __forceinline__ void async16(unsigned short* lds, const unsigned short* g) {
    __builtin_amdgcn_global_load_lds(
        (const __attribute__((address_space(1))) uint32_t*)g,
        (__attribute__((address_space(3))) uint32_t*)lds, 16, 0, 0);
}
__device__ __forceinline__ float fexp2(float x) {
    return __builtin_amdgcn_exp2f(x);   // native v_exp_f32 (2^x)
}

// ===================== cast f32->bf16 (x, Wqkv) + RoPE table (Wo in attn) =====================
#define NX8 1048576
#define NW8 1572864
#define NCAST2 (NX8 + NW8)
__global__ __launch_bounds__(256) void cast_rope_kernel(
    const float* __restrict__ x, const float* __restrict__ wqkv,
    const int* __restrict__ pos,
    unsigned short* __restrict__ xb, unsigned short* __restrict__ wqkvb,
    float2* __restrict__ tab)
{
    const int i = blockIdx.x * 256 + threadIdx.x;
    if (i < NCAST2) {
        const float* src; unsigned short* dst; int k;
        if (i < NX8) { src = x;    dst = xb;    k = i; }
        else         { src = wqkv; dst = wqkvb; k = i - NX8; }
        const float4* p4 = reinterpret_cast<const float4*>(src) + 2 * (size_t)k;
        const float4 a = p4[0], b = p4[1];
        uint32_t w0 = (uint32_t)f2bf(a.x) | ((uint32_t)f2bf(a.y) << 16);
        uint32_t w1 = (uint32_t)f2bf(a.z) | ((uint32_t)f2bf(a.w) << 16);
        uint32_t w2 = (uint32_t)f2bf(b.x) | ((uint32_t)f2bf(b.y) << 16);
        uint32_t w3 = (uint32_t)f2bf(b.z) | ((uint32_t)f2bf(b.w) << 16);
        uint4 o; o.x = w0; o.y = w1; o.z = w2; o.w = w3;
        *reinterpret_cast<uint4*>(dst + 8 * (size_t)k) = o;
    } else {
        const int idx = i - NCAST2;             // 0 .. 2048*64-1
        const int tt = idx >> 6, pi = idx & 63;
        const double inv_freq = exp(-log(10000.0) * (double)pi / 64.0);
        const double ang = (double)pos[tt] * inv_freq;
        tab[idx] = make_float2((float)cos(ang), (float)sin(ang));
    }
}

// ===================== fused QKV GEMM, 128x192 x 2-blocks/CU (unchanged) =====================
__global__ __launch_bounds__(256, 2) void gemm_qkv_x(
    const unsigned short* __restrict__ A, const unsigned short* __restrict__ B,
    unsigned short* __restrict__ qkvb, unsigned short* __restrict__ vt,
    const float2* __restrict__ tab)
{
    const int K = DMODEL, N = 3 * DMODEL;
    __shared__ unsigned short As[2][128 * 64];   // 32 KB
    __shared__ unsigned short Bs[2][192 * 64];   // 48 KB

    const int t = threadIdx.x;
    const int lane = t & 63, w = t >> 6;
    const int wr = w >> 1, wc = w & 1;
    const int lr = lane & 15, hi = lane >> 4;

    const int bid = (int)blockIdx.x;
    const int xcd = bid & 7, local = bid >> 3;
    const int row0 = (local & 31) * 128;
    const int col0 = ((xcd << 2) | (local >> 5)) * 192;

    const int rr = t >> 3;
    const int cc = ((t & 7) ^ (rr & 7)) << 3;
    const unsigned short* aP = A + (size_t)(row0 + rr) * K + cc;
    const unsigned short* bP = B + (size_t)(col0 + rr) * K + cc;
    const size_t rstep = (size_t)32 * K;

    floatx4 acc[4][6];
#pragma unroll
    for (int m = 0; m < 4; m++)
#pragma unroll
        for (int n = 0; n < 6; n++)
#pragma unroll
            for (int e = 0; e < 4; e++) acc[m][n][e] = 0.f;

#define STAGE(nb, k0n) do { \
        async16(&As[nb][t * 8],          aP + (k0n)); \
        async16(&As[nb][(t + 256) * 8],  aP + rstep + (k0n)); \
        async16(&As[nb][(t + 512) * 8],  aP + 2 * rstep + (k0n)); \
        async16(&As[nb][(t + 768) * 8],  aP + 3 * rstep + (k0n)); \
        async16(&Bs[nb][t * 8],          bP + (k0n)); \
        async16(&Bs[nb][(t + 256) * 8],  bP + rstep + (k0n)); \
        async16(&Bs[nb][(t + 512) * 8],  bP + 2 * rstep + (k0n)); \
        async16(&Bs[nb][(t + 768) * 8],  bP + 3 * rstep + (k0n)); \
        async16(&Bs[nb][(t + 1024) * 8], bP + 4 * rstep + (k0n)); \
        async16(&Bs[nb][(t + 1280) * 8], bP + 5 * rstep + (k0n)); \
    } while (0)

    const int NT = K >> 6;
    const int ch0 = (hi ^ (lr & 7)) * 8;
    const int ch1 = ((4 + hi) ^ (lr & 7)) * 8;

    short8 av[4], bv[6];

#define RD_AV(Ac, ch) do { \
        _Pragma("unroll") \
        for (int m = 0; m < 4; m++) \
            av[m] = *(const short8*)&(Ac)[(wr * 64 + m * 16 + lr) * 64 + (ch)]; \
    } while (0)
#define RD_BV(Bc, ch) do { \
        _Pragma("unroll") \
        for (int n = 0; n < 6; n++) \
            bv[n] = *(const short8*)&(Bc)[(wc * 96 + n * 16 + lr) * 64 + (ch)]; \
    } while (0)
#define MFMA_ALL() do { \
        _Pragma("unroll") \
        for (int m = 0; m < 4; m++) \
            _Pragma("unroll") \
            for (int n = 0; n < 6; n++) \
                acc[m][n] = __builtin_amdgcn_mfma_f32_16x16x32_bf16(av[m], bv[n], acc[m][n], 0, 0, 0); \
    } while (0)

    STAGE(0, 0);

    for (int kt = 0; kt < NT; ++kt) {
        const int cur = kt & 1;
        const unsigned short* __restrict__ Ac = &As[cur][0];
        const unsigned short* __restrict__ Bc = &Bs[cur][0];
        const bool more = (kt + 1 < NT);

        if (more) {
            STAGE(cur ^ 1, (kt + 1) << 6);
            asm volatile("s_waitcnt vmcnt(10)" ::: "memory");
        } else {
            asm volatile("s_waitcnt vmcnt(0)" ::: "memory");
        }
        __builtin_amdgcn_s_barrier();

        RD_AV(Ac, ch0); RD_BV(Bc, ch0);
        asm volatile("s_waitcnt lgkmcnt(0)" ::: "memory");
        __builtin_amdgcn_sched_barrier(0);
        __builtin_amdgcn_s_setprio(1);
        MFMA_ALL();
        __builtin_amdgcn_s_setprio(0);

        RD_AV(Ac, ch1); RD_BV(Bc, ch1);
        asm volatile("s_waitcnt lgkmcnt(0)" ::: "memory");
        __builtin_amdgcn_sched_barrier(0);
        __builtin_amdgcn_s_setprio(1);
        MFMA_ALL();
        __builtin_amdgcn_s_setprio(0);

        __builtin_amdgcn_s_barrier();
    }
#undef STAGE
#undef RD_AV
#undef RD_BV
#undef MFMA_ALL

    const int par = lr & 1;
#pragma unroll
    for (int mi = 0; mi < 4; mi++) {
        const int row = row0 + wr * 64 + mi * 16 + hi * 4;
        const int tt = row & (TSEQ - 1);
        const int bb = row >> 11;
#pragma unroll
        for (int ni = 0; ni < 6; ni++) {
            const int col = col0 + wc * 96 + ni * 16 + lr;
            if (col < 2 * DMODEL) {
                const int pi = (col & 127) >> 1;
#pragma unroll
                for (int j = 0; j < 4; j++) {
                    const float2 cs = tab[(tt + j) * 64 + pi];
                    const float v = acc[mi][ni][j];
                    const float p = __shfl_xor(v, 1, 64);
                    const float o = par ? (p * cs.y + v * cs.x)
                                        : (v * cs.x - p * cs.y);
                    qkvb[(size_t)(row + j) * N + col] = f2bf(o);
                }
            } else {
                const int vcol = col - 2 * DMODEL;
                const int h = vcol >> 7, d = vcol & 127;
                uint2 pw;
                pw.x = (uint32_t)f2bf(acc[mi][ni][0]) | ((uint32_t)f2bf(acc[mi][ni][1]) << 16);
                pw.y = (uint32_t)f2bf(acc[mi][ni][2]) | ((uint32_t)f2bf(acc[mi][ni][3]) << 16);
                *(uint2*)&vt[(size_t)((bb * NHEADS + h) * DK + d) * TSEQ + tt] = pw;
            }
        }
    }
}

// ===================== output projection, 128x128 x 2-blocks/CU, f32 out (unchanged) =====================
__global__ __launch_bounds__(256, 2) void gemm_o_x(
    const unsigned short* __restrict__ A, const unsigned short* __restrict__ B,
    float* __restrict__ C)
{
    const int K = DMODEL, N = DMODEL;
    __shared__ unsigned short As[2][128 * 64];
    __shared__ unsigned short Bs[2][128 * 64];

    const int t = threadIdx.x;
    const int lane = t & 63, w = t >> 6;
    const int wr = w >> 1, wc = w & 1;
    const int lr = lane & 15, hi = lane >> 4;

    const int bid = (int)blockIdx.x;
    const int xcd = bid & 7, local = bid >> 3;
    const int row0 = (local & 31) * 128;
    const int col0 = ((xcd << 1) | (local >> 5)) * 128;

    const int rr = t >> 3;
    const int cc = ((t & 7) ^ (rr & 7)) << 3;
    const unsigned short* aP = A + (size_t)(row0 + rr) * K + cc;
    const unsigned short* bP = B + (size_t)(col0 + rr) * K + cc;
    const size_t rstep = (size_t)32 * K;

    floatx4 acc[4][4];
#pragma unroll
    for (int m = 0; m < 4; m++)
#pragma unroll
        for (int n = 0; n < 4; n++)
#pragma unroll
            for (int e = 0; e < 4; e++) acc[m][n][e] = 0.f;

#define STAGE(nb, k0n) do { \
        async16(&As[nb][t * 8],          aP + (k0n)); \
        async16(&As[nb][(t + 256) * 8],  aP + rstep + (k0n)); \
        async16(&As[nb][(t + 512) * 8],  aP + 2 * rstep + (k0n)); \
        async16(&As[nb][(t + 768) * 8],  aP + 3 * rstep + (k0n)); \
        async16(&Bs[nb][t * 8],          bP + (k0n)); \
        async16(&Bs[nb][(t + 256) * 8],  bP + rstep + (k0n)); \
        async16(&Bs[nb][(t + 512) * 8],  bP + 2 * rstep + (k0n)); \
        async16(&Bs[nb][(t + 768) * 8],  bP + 3 * rstep + (k0n)); \
    } while (0)

    const int NT = K >> 6;
    const int ch0 = (hi ^ (lr & 7)) * 8;
    const int ch1 = ((4 + hi) ^ (lr & 7)) * 8;

    short8 av[4], bv[4];

#define RD_AV(Ac, ch) do { \
        _Pragma("unroll") \
        for (int m = 0; m < 4; m++) \
            av[m] = *(const short8*)&(Ac)[(wr * 64 + m * 16 + lr) * 64 + (ch)]; \
    } while (0)
#define RD_BV(Bc, ch) do { \
        _Pragma("unroll") \
        for (int n = 0; n < 4; n++) \
            bv[n] = *(const short8*)&(Bc)[(wc * 64 + n * 16 + lr) * 64 + (ch)]; \
    } while (0)
#define MFMA_ALL() do { \
        _Pragma("unroll") \
        for (int m = 0; m < 4; m++) \
            _Pragma("unroll") \
            for (int n = 0; n < 4; n++) \
                acc[m][n] = __builtin_amdgcn_mfma_f32_16x16x32_bf16(av[m], bv[n], acc[m][n], 0, 0, 0); \
    } while (0)

    STAGE(0, 0);

    for (int kt = 0; kt < NT; ++kt) {
        const int cur = kt & 1;
        const unsigned short* __restrict__ Ac = &As[cur][0];
        const unsigned short* __restrict__ Bc = &Bs[cur][0];
        const bool more = (kt + 1 < NT);

        if (more) {
            STAGE(cur ^ 1, (kt + 1) << 6);
            asm volatile("s_waitcnt vmcnt(8)" ::: "memory");
        } else {
            asm volatile("s_waitcnt vmcnt(0)" ::: "memory");
        }
        __builtin_amdgcn_s_barrier();

        RD_AV(Ac, ch0); RD_BV(Bc, ch0);
        asm volatile("s_waitcnt lgkmcnt(0)" ::: "memory");
        __builtin_amdgcn_sched_barrier(0);
        __builtin_amdgcn_s_setprio(1);
        MFMA_ALL();
        __builtin_amdgcn_s_setprio(0);

        RD_AV(Ac, ch1); RD_BV(Bc, ch1);
        asm volatile("s_waitcnt lgkmcnt(0)" ::: "memory");
        __builtin_amdgcn_sched_barrier(0);
        __builtin_amdgcn_s_setprio(1);
        MFMA_ALL();
        __builtin_amdgcn_s_setprio(0);

        __builtin_amdgcn_s_barrier();
    }
#undef STAGE
#undef RD_AV
#undef RD_BV
#undef MFMA_ALL

#pragma unroll
    for (int mi = 0; mi < 4; mi++) {
        const int row = row0 + wr * 64 + mi * 16 + hi * 4;
#pragma unroll
        for (int ni = 0; ni < 4; ni++) {
            const int col = col0 + wc * 64 + ni * 16 + lr;
#pragma unroll
            for (int j = 0; j < 4; j++)
                C[(size_t)(row + j) * N + col] = acc[mi][ni][j];
        }
    }
}

// ===================== MFMA flash attention v7: CU-complementary pairing =====================
// 512 blocks of 256 thr, 2 blocks/CU. Blocks bid and bid+256 share a CU; the
// p-remap makes their pair indices complementary (p, 7-p) so EVERY CU runs
// exactly 50 tile-iterations. Waves 0-1 chunk p, waves 2-3 chunk 15-p;
// half selects 64-row half. K+V dbuf, single vmcnt(0)+barrier per tile.
__global__ __launch_bounds__(256, 2) void attn_mfma7_kernel(
    const unsigned short* __restrict__ qkvb, const unsigned short* __restrict__ vt,
    unsigned short* __restrict__ outb,
    const float* __restrict__ wo, unsigned short* __restrict__ wob)
{
    __shared__ unsigned short Ks[2][64 * 128];   // 32 KB
    __shared__ unsigned short Vs[2][128 * 64];   // 32 KB
    __shared__ unsigned short Ps[4][32 * 64];    // 16 KB

    const int t = threadIdx.x;
    const int lane = t & 63, w = t >> 6;
    const int lr = lane & 15, hi = lane >> 4;
    const int bid  = (int)blockIdx.x;

    // ---- fused Wo cast: 512 blocks x 256 thr x 4 chunks of 8 f32 ----
    {
        const int ci = bid * 256 + t;           // 0..131071
#pragma unroll
        for (int i = 0; i < 4; i++) {
            const int k = ci + i * 131072;      // 0..524287 (8 f32 each)
            const float4* p4 = reinterpret_cast<const float4*>(wo) + 2 * (size_t)k;
            const float4 a = p4[0], b = p4[1];
            uint4 o;
            o.x = (uint32_t)f2bf(a.x) | ((uint32_t)f2bf(a.y) << 16);
            o.y = (uint32_t)f2bf(a.z) | ((uint32_t)f2bf(a.w) << 16);
            o.z = (uint32_t)f2bf(b.x) | ((uint32_t)f2bf(b.y) << 16);
            o.w = (uint32_t)f2bf(b.z) | ((uint32_t)f2bf(b.w) << 16);
            *reinterpret_cast<uint4*>(wob + 8 * (size_t)k) = o;
        }
    }

    const int bh   = bid & 31;
    const int rest = bid >> 5;                   // 0..15
    // CU-complementary p-map: bid and bid+256 (rest and rest+8) get p and 7-p.
    const int p    = (rest < 8) ? (rest >> 1) : (7 - ((rest - 8) >> 1));
    const int half = rest & 1;
    const int b = bh >> 4, h = bh & 15;
    const int chunk = (w < 2) ? p : (15 - p);
    const int q0w = chunk * 128 + half * 64 + (w & 1) * 32;
    const float scale2 = 0.08838834764831845f * 1.4426950408889634f;   // 1/sqrt(128) * log2(e)
    const float THR = 8.f * 1.4426950408889634f;
    const size_t QROW = 3 * DMODEL;

    const unsigned short* kg = qkvb + (size_t)b * TSEQ * QROW + DMODEL + h * DK;
    const unsigned short* vg = vt + (size_t)bh * DK * TSEQ;

    short8 qf[2][4];
    {
        const unsigned short* qbase = qkvb + (size_t)(b * TSEQ + q0w) * QROW + h * DK;
#pragma unroll
        for (int nt = 0; nt < 2; nt++)
#pragma unroll
            for (int ks = 0; ks < 4; ks++) {
                short8 raw = *(const short8*)(qbase + (size_t)(nt * 16 + lr) * QROW + ks * 32 + hi * 8);
                short8 sc;
#pragma unroll
                for (int e = 0; e < 8; e++)
                    sc[e] = (short)f2bf(bf2f((unsigned short)raw[e]) * scale2);
                qf[nt][ks] = sc;
            }
    }

    auto stageK = [&](int bufi, int kv0s) {
#pragma unroll
        for (int i = 0; i < 4; i++) {
            const int s = i * 256 + t;
            const int r = s >> 4;
            const int cc = (s & 15) ^ (r & 7);
            async16(&Ks[bufi][s * 8], kg + (size_t)(kv0s + r) * QROW + cc * 8);
        }
    };
    auto stageV = [&](int bufi, int kv0s) {
#pragma unroll
        for (int i = 0; i < 4; i++) {
            const int s = i * 256 + t;
            const int r = s >> 3;
            const int cc = (s & 7) ^ (r & 7);
            async16(&Vs[bufi][s * 8], vg + (size_t)r * TSEQ + kv0s + cc * 8);
        }
    };

    floatx4 accO[2][8];
#pragma unroll
    for (int nt = 0; nt < 2; nt++)
#pragma unroll
        for (int dt = 0; dt < 8; dt++)
#pragma unroll
            for (int e = 0; e < 4; e++) accO[nt][dt][e] = 0.f;
    float mrun[2] = {-1e30f, -1e30f};
    float lrun[2] = {0.f, 0.f};

    const int ntiles = (16 - p) * 2;
    int buf = 0;

    stageK(0, 0);
    stageV(0, 0);
    asm volatile("s_waitcnt vmcnt(0)" ::: "memory");
    __builtin_amdgcn_s_barrier();

    const int pswz = (lr & 7) << 1;

    for (int ti = 0; ti < ntiles; ti++) {
        const int kv0 = ti * 64;
        if (ti + 1 < ntiles) {
            stageK(buf ^ 1, kv0 + 64);
            stageV(buf ^ 1, kv0 + 64);
        }

        const bool active = (kv0 <= q0w + 31);

        if (active) {
            float al[2] = {1.f, 1.f};
            floatx4 st[4][2];
#pragma unroll
            for (int mt = 0; mt < 4; mt++)
#pragma unroll
                for (int nt = 0; nt < 2; nt++)
#pragma unroll
                    for (int e = 0; e < 4; e++) st[mt][nt][e] = 0.f;
            __builtin_amdgcn_s_setprio(1);
#pragma unroll
            for (int mt = 0; mt < 4; mt++) {
                const int r = mt * 16 + lr;
#pragma unroll
                for (int ks = 0; ks < 4; ks++) {
                    const int ch = (ks * 4 + hi) ^ (r & 7);
                    const short8 kf = *(const short8*)&Ks[buf][(r * 16 + ch) * 8];
                    st[mt][0] = __builtin_amdgcn_mfma_f32_16x16x32_bf16(kf, qf[0][ks], st[mt][0], 0, 0, 0);
                    st[mt][1] = __builtin_amdgcn_mfma_f32_16x16x32_bf16(kf, qf[1][ks], st[mt][1], 0, 0, 0);
                }
            }
            __builtin_amdgcn_s_setprio(0);
            if (kv0 + 63 > q0w) {
#pragma unroll
                for (int nt = 0; nt < 2; nt++) {
                    const int qg = q0w + nt * 16 + lr;
#pragma unroll
                    for (int mt = 0; mt < 4; mt++)
#pragma unroll
                        for (int rg = 0; rg < 4; rg++) {
                            const int kvg = kv0 + mt * 16 + hi * 4 + rg;
                            if (kvg > qg) st[mt][nt][rg] = -1e30f;
                        }
                }
            }
            float pm[2];
#pragma unroll
            for (int nt = 0; nt < 2; nt++) {
                float m = -1e30f;
#pragma unroll
                for (int mt = 0; mt < 4; mt++)
#pragma unroll
                    for (int rg = 0; rg < 4; rg++) m = fmaxf(m, st[mt][nt][rg]);
                m = fmaxf(m, __shfl_xor(m, 16, 64));
                m = fmaxf(m, __shfl_xor(m, 32, 64));
                pm[nt] = m;
            }
            if (__any((pm[0] > mrun[0] + THR) || (pm[1] > mrun[1] + THR))) {
#pragma unroll
                for (int nt = 0; nt < 2; nt++) {
                    const float mn = fmaxf(mrun[nt], pm[nt]);
                    al[nt] = fexp2(mrun[nt] - mn);
                    mrun[nt] = mn;
                }
#pragma unroll
                for (int rg = 0; rg < 4; rg++) {
                    const float a0 = __shfl(al[0], hi * 4 + rg, 64);
                    const float a1 = __shfl(al[1], hi * 4 + rg, 64);
#pragma unroll
                    for (int dt = 0; dt < 8; dt++) {
                        accO[0][dt][rg] *= a0;
                        accO[1][dt][rg] *= a1;
                    }
                }
            }
#pragma unroll
            for (int nt = 0; nt < 2; nt++) {
                float ls = 0.f;
                const int prow = nt * 16 + lr;
#pragma unroll
                for (int mt = 0; mt < 4; mt++) {
                    float pv[4];
#pragma unroll
                    for (int rg = 0; rg < 4; rg++) {
                        pv[rg] = fexp2(st[mt][nt][rg] - mrun[nt]);
                        ls += pv[rg];
                    }
                    uint2 pw;
                    pw.x = (uint32_t)f2bf(pv[0]) | ((uint32_t)f2bf(pv[1]) << 16);
                    pw.y = (uint32_t)f2bf(pv[2]) | ((uint32_t)f2bf(pv[3]) << 16);
                    const int chunkx = (mt * 4 + hi) ^ pswz;
                    *(uint2*)&Ps[w][prow * 64 + chunkx * 4] = pw;
                }
                ls += __shfl_xor(ls, 16, 64);
                ls += __shfl_xor(ls, 32, 64);
                lrun[nt] = lrun[nt] * al[nt] + ls;
            }

            __builtin_amdgcn_s_setprio(1);
#pragma unroll
            for (int ks2 = 0; ks2 < 2; ks2++) {
                const int chp = ((ks2 * 8 + hi * 2) ^ pswz) * 4;
                const short8 pa0 = *(const short8*)&Ps[w][(0 * 16 + lr) * 64 + chp];
                const short8 pa1 = *(const short8*)&Ps[w][(1 * 16 + lr) * 64 + chp];
#pragma unroll
                for (int dt = 0; dt < 8; dt++) {
                    const int r = dt * 16 + lr;
                    const int ch = (ks2 * 4 + hi) ^ (r & 7);
                    const short8 vf = *(const short8*)&Vs[buf][(r * 8 + ch) * 8];
                    accO[0][dt] = __builtin_amdgcn_mfma_f32_16x16x32_bf16(pa0, vf, accO[0][dt], 0, 0, 0);
                    accO[1][dt] = __builtin_amdgcn_mfma_f32_16x16x32_bf16(pa1, vf, accO[1][dt], 0, 0, 0);
                }
            }
            __builtin_amdgcn_s_setprio(0);
        }

        asm volatile("s_waitcnt vmcnt(0)" ::: "memory");
        __builtin_amdgcn_s_barrier();
        buf ^= 1;
    }

#pragma unroll
    for (int nt = 0; nt < 2; nt++) {
        const float lv_own = 1.f / lrun[nt];
#pragma unroll
        for (int rg = 0; rg < 4; rg++) {
            const float lv = __shfl(lv_own, hi * 4 + rg, 64);
            unsigned short* orow = outb + (size_t)(b * TSEQ + q0w + nt * 16 + hi * 4 + rg) * DMODEL + h * DK;
#pragma unroll
            for (int dt = 0; dt < 8; dt++)
                orow[dt * 16 + lr] = f2bf(accO[nt][dt][rg] * lv);
        }
    }
}

// ===================== launch =====================
extern "C" void kernel_launch(void* const* d_in, const int* in_sizes, int n_in,
                              void* d_out, int out_size, void* d_ws, size_t ws_size,
                              hipStream_t stream)
{
    const float* x    = (const float*)d_in[0];
    const int*   pos  = (const int*)d_in[1];
    const float* Wqkv = (const float*)d_in[2];
    const float* Wo   = (const float*)d_in[3];
    float* out = (float*)d_out;

    unsigned short* qkvb  = (unsigned short*)d_ws;
    unsigned short* vtb   = qkvb + (size_t)25165824;
    unsigned short* xb    = vtb + (size_t)8388608;
    unsigned short* attnb = xb;                         // alias: xb dead after GEMM1
    unsigned short* wqkvb = xb + (size_t)8388608;
    unsigned short* wob   = wqkvb + (size_t)12582912;
    float2* tab = (float2*)(wob + (size_t)4194304);

    // cast (x, Wqkv) + RoPE table: 10240 + 512 blocks
    cast_rope_kernel<<<10752, 256, 0, stream>>>(x, Wqkv, pos, xb, wqkvb, tab);

    // fused QKV projection + RoPE + V-transpose (4096 x 6144 x 2048)
    gemm_qkv_x<<<dim3(1024), 256, 0, stream>>>(xb, wqkvb, qkvb, vtb, tab);

    // CU-balanced paired attention (+ fused Wo cast): 512 blocks x 256 thr
    attn_mfma7_kernel<<<dim3(512), 256, 0, stream>>>(qkvb, vtb, attnb, Wo, wob);

    // out = attn @ Wo^T (4096 x 2048 x 2048), 512 tiles of 128x128
    gemm_o_x<<<dim3(512), 256, 0, stream>>>(attnb, wob, out);
}

// Round 17
// 246.442 us; speedup vs baseline: 1.4328x; 1.0171x over previous
//
#include <hip/hip_runtime.h>
#include <math.h>
#include <stdint.h>

#define NHEADS 16
#define DK 128
#define TSEQ 2048
#define DMODEL 2048

typedef __attribute__((ext_vector_type(8))) short short8;
typedef __attribute__((ext_vector_type(4))) float floatx4;

__device__ __forceinline__ float bf2f(unsigned short h) {
    return __uint_as_float(((unsigned int)h) << 16);
}
__device__ __forceinline__ unsigned short f2bf(float f) {
    unsigned int u = __float_as_uint(f);
    u += 0x7FFFu + ((u >> 16) & 1u);
    return (unsigned short)(u >> 16);
}
__device__ __forceinline__ void async16(unsigned short* lds, const unsigned short* g) {
    __builtin_amdgcn_global_load_lds(
        (const __attribute__((address_space(1))) uint32_t*)g,
        (__attribute__((address_space(3))) uint32_t*)lds, 16, 0, 0);
}
__device__ __forceinline__ float fexp2(float x) {
    return __builtin_amdgcn_exp2f(x);   // native v_exp_f32 (2^x)
}

// ===================== cast f32->bf16 (x, Wqkv) + RoPE table (Wo in attn) =====================
#define NX8 1048576
#define NW8 1572864
#define NCAST2 (NX8 + NW8)
__global__ __launch_bounds__(256) void cast_rope_kernel(
    const float* __restrict__ x, const float* __restrict__ wqkv,
    const int* __restrict__ pos,
    unsigned short* __restrict__ xb, unsigned short* __restrict__ wqkvb,
    float2* __restrict__ tab)
{
    const int i = blockIdx.x * 256 + threadIdx.x;
    if (i < NCAST2) {
        const float* src; unsigned short* dst; int k;
        if (i < NX8) { src = x;    dst = xb;    k = i; }
        else         { src = wqkv; dst = wqkvb; k = i - NX8; }
        const float4* p4 = reinterpret_cast<const float4*>(src) + 2 * (size_t)k;
        const float4 a = p4[0], b = p4[1];
        uint32_t w0 = (uint32_t)f2bf(a.x) | ((uint32_t)f2bf(a.y) << 16);
        uint32_t w1 = (uint32_t)f2bf(a.z) | ((uint32_t)f2bf(a.w) << 16);
        uint32_t w2 = (uint32_t)f2bf(b.x) | ((uint32_t)f2bf(b.y) << 16);
        uint32_t w3 = (uint32_t)f2bf(b.z) | ((uint32_t)f2bf(b.w) << 16);
        uint4 o; o.x = w0; o.y = w1; o.z = w2; o.w = w3;
        *reinterpret_cast<uint4*>(dst + 8 * (size_t)k) = o;
    } else {
        const int idx = i - NCAST2;             // 0 .. 2048*64-1
        const int tt = idx >> 6, pi = idx & 63;
        const double inv_freq = exp(-log(10000.0) * (double)pi / 64.0);
        const double ang = (double)pos[tt] * inv_freq;
        tab[idx] = make_float2((float)cos(ang), (float)sin(ang));
    }
}

// ===================== fused QKV GEMM, 128x192 x 2-blocks/CU, compiler-scheduled inner loop =====================
__global__ __launch_bounds__(256, 2) void gemm_qkv_x(
    const unsigned short* __restrict__ A, const unsigned short* __restrict__ B,
    unsigned short* __restrict__ qkvb, unsigned short* __restrict__ vt,
    const float2* __restrict__ tab)
{
    const int K = DMODEL, N = 3 * DMODEL;
    __shared__ unsigned short As[2][128 * 64];   // 32 KB
    __shared__ unsigned short Bs[2][192 * 64];   // 48 KB

    const int t = threadIdx.x;
    const int lane = t & 63, w = t >> 6;
    const int wr = w >> 1, wc = w & 1;
    const int lr = lane & 15, hi = lane >> 4;

    const int bid = (int)blockIdx.x;
    const int xcd = bid & 7, local = bid >> 3;
    const int row0 = (local & 31) * 128;
    const int col0 = ((xcd << 2) | (local >> 5)) * 192;

    const int rr = t >> 3;
    const int cc = ((t & 7) ^ (rr & 7)) << 3;
    const unsigned short* aP = A + (size_t)(row0 + rr) * K + cc;
    const unsigned short* bP = B + (size_t)(col0 + rr) * K + cc;
    const size_t rstep = (size_t)32 * K;

    floatx4 acc[4][6];
#pragma unroll
    for (int m = 0; m < 4; m++)
#pragma unroll
        for (int n = 0; n < 6; n++)
#pragma unroll
            for (int e = 0; e < 4; e++) acc[m][n][e] = 0.f;

#define STAGE(nb, k0n) do { \
        async16(&As[nb][t * 8],          aP + (k0n)); \
        async16(&As[nb][(t + 256) * 8],  aP + rstep + (k0n)); \
        async16(&As[nb][(t + 512) * 8],  aP + 2 * rstep + (k0n)); \
        async16(&As[nb][(t + 768) * 8],  aP + 3 * rstep + (k0n)); \
        async16(&Bs[nb][t * 8],          bP + (k0n)); \
        async16(&Bs[nb][(t + 256) * 8],  bP + rstep + (k0n)); \
        async16(&Bs[nb][(t + 512) * 8],  bP + 2 * rstep + (k0n)); \
        async16(&Bs[nb][(t + 768) * 8],  bP + 3 * rstep + (k0n)); \
        async16(&Bs[nb][(t + 1024) * 8], bP + 4 * rstep + (k0n)); \
        async16(&Bs[nb][(t + 1280) * 8], bP + 5 * rstep + (k0n)); \
    } while (0)

    const int NT = K >> 6;
    const int ch0 = (hi ^ (lr & 7)) * 8;
    const int ch1 = ((4 + hi) ^ (lr & 7)) * 8;

    short8 av[4], bv[6];

#define RD_AV(Ac, ch) do { \
        _Pragma("unroll") \
        for (int m = 0; m < 4; m++) \
            av[m] = *(const short8*)&(Ac)[(wr * 64 + m * 16 + lr) * 64 + (ch)]; \
    } while (0)
#define RD_BV(Bc, ch) do { \
        _Pragma("unroll") \
        for (int n = 0; n < 6; n++) \
            bv[n] = *(const short8*)&(Bc)[(wc * 96 + n * 16 + lr) * 64 + (ch)]; \
    } while (0)
#define MFMA_ALL() do { \
        _Pragma("unroll") \
        for (int m = 0; m < 4; m++) \
            _Pragma("unroll") \
            for (int n = 0; n < 6; n++) \
                acc[m][n] = __builtin_amdgcn_mfma_f32_16x16x32_bf16(av[m], bv[n], acc[m][n], 0, 0, 0); \
    } while (0)

    STAGE(0, 0);

    for (int kt = 0; kt < NT; ++kt) {
        const int cur = kt & 1;
        const unsigned short* __restrict__ Ac = &As[cur][0];
        const unsigned short* __restrict__ Bc = &Bs[cur][0];
        const bool more = (kt + 1 < NT);

        if (more) {
            STAGE(cur ^ 1, (kt + 1) << 6);
            asm volatile("s_waitcnt vmcnt(10)" ::: "memory");   // prior tile's 10 landed
        } else {
            asm volatile("s_waitcnt vmcnt(0)" ::: "memory");
        }
        __builtin_amdgcn_s_barrier();
        asm volatile("" ::: "memory");   // compiler fence: no LDS reads above barrier

        // compiler-scheduled: ds_reads interleave with MFMAs via counted lgkmcnt
        RD_AV(Ac, ch0); RD_BV(Bc, ch0);
        MFMA_ALL();
        RD_AV(Ac, ch1); RD_BV(Bc, ch1);
        MFMA_ALL();

        asm volatile("" ::: "memory");
        __builtin_amdgcn_s_barrier();   // all reads of buf[cur] done -> next iter may overwrite
    }
#undef STAGE
#undef RD_AV
#undef RD_BV
#undef MFMA_ALL

    const int par = lr & 1;
#pragma unroll
    for (int mi = 0; mi < 4; mi++) {
        const int row = row0 + wr * 64 + mi * 16 + hi * 4;
        const int tt = row & (TSEQ - 1);
        const int bb = row >> 11;
#pragma unroll
        for (int ni = 0; ni < 6; ni++) {
            const int col = col0 + wc * 96 + ni * 16 + lr;
            if (col < 2 * DMODEL) {
                const int pi = (col & 127) >> 1;
#pragma unroll
                for (int j = 0; j < 4; j++) {
                    const float2 cs = tab[(tt + j) * 64 + pi];
                    const float v = acc[mi][ni][j];
                    const float p = __shfl_xor(v, 1, 64);
                    const float o = par ? (p * cs.y + v * cs.x)
                                        : (v * cs.x - p * cs.y);
                    qkvb[(size_t)(row + j) * N + col] = f2bf(o);
                }
            } else {
                const int vcol = col - 2 * DMODEL;
                const int h = vcol >> 7, d = vcol & 127;
                uint2 pw;
                pw.x = (uint32_t)f2bf(acc[mi][ni][0]) | ((uint32_t)f2bf(acc[mi][ni][1]) << 16);
                pw.y = (uint32_t)f2bf(acc[mi][ni][2]) | ((uint32_t)f2bf(acc[mi][ni][3]) << 16);
                *(uint2*)&vt[(size_t)((bb * NHEADS + h) * DK + d) * TSEQ + tt] = pw;
            }
        }
    }
}

// ===================== output projection, 128x128 x 2-blocks/CU, compiler-scheduled =====================
__global__ __launch_bounds__(256, 2) void gemm_o_x(
    const unsigned short* __restrict__ A, const unsigned short* __restrict__ B,
    float* __restrict__ C)
{
    const int K = DMODEL, N = DMODEL;
    __shared__ unsigned short As[2][128 * 64];
    __shared__ unsigned short Bs[2][128 * 64];

    const int t = threadIdx.x;
    const int lane = t & 63, w = t >> 6;
    const int wr = w >> 1, wc = w & 1;
    const int lr = lane & 15, hi = lane >> 4;

    const int bid = (int)blockIdx.x;
    const int xcd = bid & 7, local = bid >> 3;
    const int row0 = (local & 31) * 128;
    const int col0 = ((xcd << 1) | (local >> 5)) * 128;

    const int rr = t >> 3;
    const int cc = ((t & 7) ^ (rr & 7)) << 3;
    const unsigned short* aP = A + (size_t)(row0 + rr) * K + cc;
    const unsigned short* bP = B + (size_t)(col0 + rr) * K + cc;
    const size_t rstep = (size_t)32 * K;

    floatx4 acc[4][4];
#pragma unroll
    for (int m = 0; m < 4; m++)
#pragma unroll
        for (int n = 0; n < 4; n++)
#pragma unroll
            for (int e = 0; e < 4; e++) acc[m][n][e] = 0.f;

#define STAGE(nb, k0n) do { \
        async16(&As[nb][t * 8],          aP + (k0n)); \
        async16(&As[nb][(t + 256) * 8],  aP + rstep + (k0n)); \
        async16(&As[nb][(t + 512) * 8],  aP + 2 * rstep + (k0n)); \
        async16(&As[nb][(t + 768) * 8],  aP + 3 * rstep + (k0n)); \
        async16(&Bs[nb][t * 8],          bP + (k0n)); \
        async16(&Bs[nb][(t + 256) * 8],  bP + rstep + (k0n)); \
        async16(&Bs[nb][(t + 512) * 8],  bP + 2 * rstep + (k0n)); \
        async16(&Bs[nb][(t + 768) * 8],  bP + 3 * rstep + (k0n)); \
    } while (0)

    const int NT = K >> 6;
    const int ch0 = (hi ^ (lr & 7)) * 8;
    const int ch1 = ((4 + hi) ^ (lr & 7)) * 8;

    short8 av[4], bv[4];

#define RD_AV(Ac, ch) do { \
        _Pragma("unroll") \
        for (int m = 0; m < 4; m++) \
            av[m] = *(const short8*)&(Ac)[(wr * 64 + m * 16 + lr) * 64 + (ch)]; \
    } while (0)
#define RD_BV(Bc, ch) do { \
        _Pragma("unroll") \
        for (int n = 0; n < 4; n++) \
            bv[n] = *(const short8*)&(Bc)[(wc * 64 + n * 16 + lr) * 64 + (ch)]; \
    } while (0)
#define MFMA_ALL() do { \
        _Pragma("unroll") \
        for (int m = 0; m < 4; m++) \
            _Pragma("unroll") \
            for (int n = 0; n < 4; n++) \
                acc[m][n] = __builtin_amdgcn_mfma_f32_16x16x32_bf16(av[m], bv[n], acc[m][n], 0, 0, 0); \
    } while (0)

    STAGE(0, 0);

    for (int kt = 0; kt < NT; ++kt) {
        const int cur = kt & 1;
        const unsigned short* __restrict__ Ac = &As[cur][0];
        const unsigned short* __restrict__ Bc = &Bs[cur][0];
        const bool more = (kt + 1 < NT);

        if (more) {
            STAGE(cur ^ 1, (kt + 1) << 6);
            asm volatile("s_waitcnt vmcnt(8)" ::: "memory");
        } else {
            asm volatile("s_waitcnt vmcnt(0)" ::: "memory");
        }
        __builtin_amdgcn_s_barrier();
        asm volatile("" ::: "memory");

        RD_AV(Ac, ch0); RD_BV(Bc, ch0);
        MFMA_ALL();
        RD_AV(Ac, ch1); RD_BV(Bc, ch1);
        MFMA_ALL();

        asm volatile("" ::: "memory");
        __builtin_amdgcn_s_barrier();
    }
#undef STAGE
#undef RD_AV
#undef RD_BV
#undef MFMA_ALL

#pragma unroll
    for (int mi = 0; mi < 4; mi++) {
        const int row = row0 + wr * 64 + mi * 16 + hi * 4;
#pragma unroll
        for (int ni = 0; ni < 4; ni++) {
            const int col = col0 + wc * 64 + ni * 16 + lr;
#pragma unroll
            for (int j = 0; j < 4; j++)
                C[(size_t)(row + j) * N + col] = acc[mi][ni][j];
        }
    }
}

// ===================== MFMA flash attention v7 (unchanged from round 16) =====================
__global__ __launch_bounds__(256, 2) void attn_mfma7_kernel(
    const unsigned short* __restrict__ qkvb, const unsigned short* __restrict__ vt,
    unsigned short* __restrict__ outb,
    const float* __restrict__ wo, unsigned short* __restrict__ wob)
{
    __shared__ unsigned short Ks[2][64 * 128];   // 32 KB
    __shared__ unsigned short Vs[2][128 * 64];   // 32 KB
    __shared__ unsigned short Ps[4][32 * 64];    // 16 KB

    const int t = threadIdx.x;
    const int lane = t & 63, w = t >> 6;
    const int lr = lane & 15, hi = lane >> 4;
    const int bid  = (int)blockIdx.x;

    // ---- fused Wo cast ----
    {
        const int ci = bid * 256 + t;
#pragma unroll
        for (int i = 0; i < 4; i++) {
            const int k = ci + i * 131072;
            const float4* p4 = reinterpret_cast<const float4*>(wo) + 2 * (size_t)k;
            const float4 a = p4[0], b = p4[1];
            uint4 o;
            o.x = (uint32_t)f2bf(a.x) | ((uint32_t)f2bf(a.y) << 16);
            o.y = (uint32_t)f2bf(a.z) | ((uint32_t)f2bf(a.w) << 16);
            o.z = (uint32_t)f2bf(b.x) | ((uint32_t)f2bf(b.y) << 16);
            o.w = (uint32_t)f2bf(b.z) | ((uint32_t)f2bf(b.w) << 16);
            *reinterpret_cast<uint4*>(wob + 8 * (size_t)k) = o;
        }
    }

    const int bh   = bid & 31;
    const int rest = bid >> 5;
    const int p    = (rest < 8) ? (rest >> 1) : (7 - ((rest - 8) >> 1));
    const int half = rest & 1;
    const int b = bh >> 4, h = bh & 15;
    const int chunk = (w < 2) ? p : (15 - p);
    const int q0w = chunk * 128 + half * 64 + (w & 1) * 32;
    const float scale2 = 0.08838834764831845f * 1.4426950408889634f;
    const float THR = 8.f * 1.4426950408889634f;
    const size_t QROW = 3 * DMODEL;

    const unsigned short* kg = qkvb + (size_t)b * TSEQ * QROW + DMODEL + h * DK;
    const unsigned short* vg = vt + (size_t)bh * DK * TSEQ;

    short8 qf[2][4];
    {
        const unsigned short* qbase = qkvb + (size_t)(b * TSEQ + q0w) * QROW + h * DK;
#pragma unroll
        for (int nt = 0; nt < 2; nt++)
#pragma unroll
            for (int ks = 0; ks < 4; ks++) {
                short8 raw = *(const short8*)(qbase + (size_t)(nt * 16 + lr) * QROW + ks * 32 + hi * 8);
                short8 sc;
#pragma unroll
                for (int e = 0; e < 8; e++)
                    sc[e] = (short)f2bf(bf2f((unsigned short)raw[e]) * scale2);
                qf[nt][ks] = sc;
            }
    }

    auto stageK = [&](int bufi, int kv0s) {
#pragma unroll
        for (int i = 0; i < 4; i++) {
            const int s = i * 256 + t;
            const int r = s >> 4;
            const int cc = (s & 15) ^ (r & 7);
            async16(&Ks[bufi][s * 8], kg + (size_t)(kv0s + r) * QROW + cc * 8);
        }
    };
    auto stageV = [&](int bufi, int kv0s) {
#pragma unroll
        for (int i = 0; i < 4; i++) {
            const int s = i * 256 + t;
            const int r = s >> 3;
            const int cc = (s & 7) ^ (r & 7);
            async16(&Vs[bufi][s * 8], vg + (size_t)r * TSEQ + kv0s + cc * 8);
        }
    };

    floatx4 accO[2][8];
#pragma unroll
    for (int nt = 0; nt < 2; nt++)
#pragma unroll
        for (int dt = 0; dt < 8; dt++)
#pragma unroll
            for (int e = 0; e < 4; e++) accO[nt][dt][e] = 0.f;
    float mrun[2] = {-1e30f, -1e30f};
    float lrun[2] = {0.f, 0.f};

    const int ntiles = (16 - p) * 2;
    int buf = 0;

    stageK(0, 0);
    stageV(0, 0);
    asm volatile("s_waitcnt vmcnt(0)" ::: "memory");
    __builtin_amdgcn_s_barrier();

    const int pswz = (lr & 7) << 1;

    for (int ti = 0; ti < ntiles; ti++) {
        const int kv0 = ti * 64;
        if (ti + 1 < ntiles) {
            stageK(buf ^ 1, kv0 + 64);
            stageV(buf ^ 1, kv0 + 64);
        }

        const bool active = (kv0 <= q0w + 31);

        if (active) {
            float al[2] = {1.f, 1.f};
            floatx4 st[4][2];
#pragma unroll
            for (int mt = 0; mt < 4; mt++)
#pragma unroll
                for (int nt = 0; nt < 2; nt++)
#pragma unroll
                    for (int e = 0; e < 4; e++) st[mt][nt][e] = 0.f;
            __builtin_amdgcn_s_setprio(1);
#pragma unroll
            for (int mt = 0; mt < 4; mt++) {
                const int r = mt * 16 + lr;
#pragma unroll
                for (int ks = 0; ks < 4; ks++) {
                    const int ch = (ks * 4 + hi) ^ (r & 7);
                    const short8 kf = *(const short8*)&Ks[buf][(r * 16 + ch) * 8];
                    st[mt][0] = __builtin_amdgcn_mfma_f32_16x16x32_bf16(kf, qf[0][ks], st[mt][0], 0, 0, 0);
                    st[mt][1] = __builtin_amdgcn_mfma_f32_16x16x32_bf16(kf, qf[1][ks], st[mt][1], 0, 0, 0);
                }
            }
            __builtin_amdgcn_s_setprio(0);
            if (kv0 + 63 > q0w) {
#pragma unroll
                for (int nt = 0; nt < 2; nt++) {
                    const int qg = q0w + nt * 16 + lr;
#pragma unroll
                    for (int mt = 0; mt < 4; mt++)
#pragma unroll
                        for (int rg = 0; rg < 4; rg++) {
                            const int kvg = kv0 + mt * 16 + hi * 4 + rg;
                            if (kvg > qg) st[mt][nt][rg] = -1e30f;
                        }
                }
            }
            float pm[2];
#pragma unroll
            for (int nt = 0; nt < 2; nt++) {
                float m = -1e30f;
#pragma unroll
                for (int mt = 0; mt < 4; mt++)
#pragma unroll
                    for (int rg = 0; rg < 4; rg++) m = fmaxf(m, st[mt][nt][rg]);
                m = fmaxf(m, __shfl_xor(m, 16, 64));
                m = fmaxf(m, __shfl_xor(m, 32, 64));
                pm[nt] = m;
            }
            if (__any((pm[0] > mrun[0] + THR) || (pm[1] > mrun[1] + THR))) {
#pragma unroll
                for (int nt = 0; nt < 2; nt++) {
                    const float mn = fmaxf(mrun[nt], pm[nt]);
                    al[nt] = fexp2(mrun[nt] - mn);
                    mrun[nt] = mn;
                }
#pragma unroll
                for (int rg = 0; rg < 4; rg++) {
                    const float a0 = __shfl(al[0], hi * 4 + rg, 64);
                    const float a1 = __shfl(al[1], hi * 4 + rg, 64);
#pragma unroll
                    for (int dt = 0; dt < 8; dt++) {
                        accO[0][dt][rg] *= a0;
                        accO[1][dt][rg] *= a1;
                    }
                }
            }
#pragma unroll
            for (int nt = 0; nt < 2; nt++) {
                float ls = 0.f;
                const int prow = nt * 16 + lr;
#pragma unroll
                for (int mt = 0; mt < 4; mt++) {
                    float pv[4];
#pragma unroll
                    for (int rg = 0; rg < 4; rg++) {
                        pv[rg] = fexp2(st[mt][nt][rg] - mrun[nt]);
                        ls += pv[rg];
                    }
                    uint2 pw;
                    pw.x = (uint32_t)f2bf(pv[0]) | ((uint32_t)f2bf(pv[1]) << 16);
                    pw.y = (uint32_t)f2bf(pv[2]) | ((uint32_t)f2bf(pv[3]) << 16);
                    const int chunkx = (mt * 4 + hi) ^ pswz;
                    *(uint2*)&Ps[w][prow * 64 + chunkx * 4] = pw;
                }
                ls += __shfl_xor(ls, 16, 64);
                ls += __shfl_xor(ls, 32, 64);
                lrun[nt] = lrun[nt] * al[nt] + ls;
            }

            __builtin_amdgcn_s_setprio(1);
#pragma unroll
            for (int ks2 = 0; ks2 < 2; ks2++) {
                const int chp = ((ks2 * 8 + hi * 2) ^ pswz) * 4;
                const short8 pa0 = *(const short8*)&Ps[w][(0 * 16 + lr) * 64 + chp];
                const short8 pa1 = *(const short8*)&Ps[w][(1 * 16 + lr) * 64 + chp];
#pragma unroll
                for (int dt = 0; dt < 8; dt++) {
                    const int r = dt * 16 + lr;
                    const int ch = (ks2 * 4 + hi) ^ (r & 7);
                    const short8 vf = *(const short8*)&Vs[buf][(r * 8 + ch) * 8];
                    accO[0][dt] = __builtin_amdgcn_mfma_f32_16x16x32_bf16(pa0, vf, accO[0][dt], 0, 0, 0);
                    accO[1][dt] = __builtin_amdgcn_mfma_f32_16x16x32_bf16(pa1, vf, accO[1][dt], 0, 0, 0);
                }
            }
            __builtin_amdgcn_s_setprio(0);
        }

        asm volatile("s_waitcnt vmcnt(0)" ::: "memory");
        __builtin_amdgcn_s_barrier();
        buf ^= 1;
    }

#pragma unroll
    for (int nt = 0; nt < 2; nt++) {
        const float lv_own = 1.f / lrun[nt];
#pragma unroll
        for (int rg = 0; rg < 4; rg++) {
            const float lv = __shfl(lv_own, hi * 4 + rg, 64);
            unsigned short* orow = outb + (size_t)(b * TSEQ + q0w + nt * 16 + hi * 4 + rg) * DMODEL + h * DK;
#pragma unroll
            for (int dt = 0; dt < 8; dt++)
                orow[dt * 16 + lr] = f2bf(accO[nt][dt][rg] * lv);
        }
    }
}

// ===================== launch =====================
extern "C" void kernel_launch(void* const* d_in, const int* in_sizes, int n_in,
                              void* d_out, int out_size, void* d_ws, size_t ws_size,
                              hipStream_t stream)
{
    const float* x    = (const float*)d_in[0];
    const int*   pos  = (const int*)d_in[1];
    const float* Wqkv = (const float*)d_in[2];
    const float* Wo   = (const float*)d_in[3];
    float* out = (float*)d_out;

    unsigned short* qkvb  = (unsigned short*)d_ws;
    unsigned short* vtb   = qkvb + (size_t)25165824;
    unsigned short* xb    = vtb + (size_t)8388608;
    unsigned short* attnb = xb;                         // alias: xb dead after GEMM1
    unsigned short* wqkvb = xb + (size_t)8388608;
    unsigned short* wob   = wqkvb + (size_t)12582912;
    float2* tab = (float2*)(wob + (size_t)4194304);

    // cast (x, Wqkv) + RoPE table
    cast_rope_kernel<<<10752, 256, 0, stream>>>(x, Wqkv, pos, xb, wqkvb, tab);

    // fused QKV projection + RoPE + V-transpose (4096 x 6144 x 2048)
    gemm_qkv_x<<<dim3(1024), 256, 0, stream>>>(xb, wqkvb, qkvb, vtb, tab);

    // CU-balanced paired attention (+ fused Wo cast): 512 blocks x 256 thr
    attn_mfma7_kernel<<<dim3(512), 256, 0, stream>>>(qkvb, vtb, attnb, Wo, wob);

    // out = attn @ Wo^T (4096 x 2048 x 2048), 512 tiles of 128x128
    gemm_o_x<<<dim3(512), 256, 0, stream>>>(attnb, wob, out);
}

// Round 18
// 245.193 us; speedup vs baseline: 1.4401x; 1.0051x over previous
//
#include <hip/hip_runtime.h>
#include <math.h>
#include <stdint.h>

#define NHEADS 16
#define DK 128
#define TSEQ 2048
#define DMODEL 2048

typedef __attribute__((ext_vector_type(8))) short short8;
typedef __attribute__((ext_vector_type(4))) float floatx4;

__device__ __forceinline__ float bf2f(unsigned short h) {
    return __uint_as_float(((unsigned int)h) << 16);
}
__device__ __forceinline__ unsigned short f2bf(float f) {
    unsigned int u = __float_as_uint(f);
    u += 0x7FFFu + ((u >> 16) & 1u);
    return (unsigned short)(u >> 16);
}
__device__ __forceinline__ void async16(unsigned short* lds, const unsigned short* g) {
    __builtin_amdgcn_global_load_lds(
        (const __attribute__((address_space(1))) uint32_t*)g,
        (__attribute__((address_space(3))) uint32_t*)lds, 16, 0, 0);
}
__device__ __forceinline__ float fexp2(float x) {
    return __builtin_amdgcn_exp2f(x);   // native v_exp_f32 (2^x)
}

// ===================== cast f32->bf16 (x, Wqkv) + RoPE table (fast path) =====================
#define NX8 1048576
#define NW8 1572864
#define NCAST2 (NX8 + NW8)
__global__ __launch_bounds__(256) void cast_rope_kernel(
    const float* __restrict__ x, const float* __restrict__ wqkv,
    const int* __restrict__ pos,
    unsigned short* __restrict__ xb, unsigned short* __restrict__ wqkvb,
    float2* __restrict__ tab)
{
    const int i = blockIdx.x * 256 + threadIdx.x;
    if (i < NCAST2) {
        const float* src; unsigned short* dst; int k;
        if (i < NX8) { src = x;    dst = xb;    k = i; }
        else         { src = wqkv; dst = wqkvb; k = i - NX8; }
        const float4* p4 = reinterpret_cast<const float4*>(src) + 2 * (size_t)k;
        const float4 a = p4[0], b = p4[1];
        uint32_t w0 = (uint32_t)f2bf(a.x) | ((uint32_t)f2bf(a.y) << 16);
        uint32_t w1 = (uint32_t)f2bf(a.z) | ((uint32_t)f2bf(a.w) << 16);
        uint32_t w2 = (uint32_t)f2bf(b.x) | ((uint32_t)f2bf(b.y) << 16);
        uint32_t w3 = (uint32_t)f2bf(b.z) | ((uint32_t)f2bf(b.w) << 16);
        uint4 o; o.x = w0; o.y = w1; o.z = w2; o.w = w3;
        *reinterpret_cast<uint4*>(dst + 8 * (size_t)k) = o;
    } else {
        // RoPE table without f64 transcendentals:
        // inv_freq via f32 exp2 (rel err ~6e-8); angle product + arg reduction in
        // f64 ALU ops (exact); hardware sinf/cosf on reduced arg. >= f32-reference accuracy.
        const int idx = i - NCAST2;             // 0 .. 2048*64-1
        const int tt = idx >> 6, pi = idx & 63;
        const float inv_freq = fexp2(-(float)pi * 0.20762050593046f);   // 2^(-pi*log2(1e4)/64)
        const double ang = (double)pos[tt] * (double)inv_freq;
        const double kq = rint(ang * 0.15915494309189535);              // 1/(2*pi)
        const float r = (float)(ang - kq * 6.283185307179586);
        tab[idx] = make_float2(cosf(r), sinf(r));
    }
}

// ===================== fused QKV GEMM, 128x192 x 2-blocks/CU, compiler-scheduled inner loop =====================
__global__ __launch_bounds__(256, 2) void gemm_qkv_x(
    const unsigned short* __restrict__ A, const unsigned short* __restrict__ B,
    unsigned short* __restrict__ qkvb, unsigned short* __restrict__ vt,
    const float2* __restrict__ tab)
{
    const int K = DMODEL, N = 3 * DMODEL;
    __shared__ unsigned short As[2][128 * 64];   // 32 KB
    __shared__ unsigned short Bs[2][192 * 64];   // 48 KB

    const int t = threadIdx.x;
    const int lane = t & 63, w = t >> 6;
    const int wr = w >> 1, wc = w & 1;
    const int lr = lane & 15, hi = lane >> 4;

    const int bid = (int)blockIdx.x;
    const int xcd = bid & 7, local = bid >> 3;
    const int row0 = (local & 31) * 128;
    const int col0 = ((xcd << 2) | (local >> 5)) * 192;

    const int rr = t >> 3;
    const int cc = ((t & 7) ^ (rr & 7)) << 3;
    const unsigned short* aP = A + (size_t)(row0 + rr) * K + cc;
    const unsigned short* bP = B + (size_t)(col0 + rr) * K + cc;
    const size_t rstep = (size_t)32 * K;

    floatx4 acc[4][6];
#pragma unroll
    for (int m = 0; m < 4; m++)
#pragma unroll
        for (int n = 0; n < 6; n++)
#pragma unroll
            for (int e = 0; e < 4; e++) acc[m][n][e] = 0.f;

#define STAGE(nb, k0n) do { \
        async16(&As[nb][t * 8],          aP + (k0n)); \
        async16(&As[nb][(t + 256) * 8],  aP + rstep + (k0n)); \
        async16(&As[nb][(t + 512) * 8],  aP + 2 * rstep + (k0n)); \
        async16(&As[nb][(t + 768) * 8],  aP + 3 * rstep + (k0n)); \
        async16(&Bs[nb][t * 8],          bP + (k0n)); \
        async16(&Bs[nb][(t + 256) * 8],  bP + rstep + (k0n)); \
        async16(&Bs[nb][(t + 512) * 8],  bP + 2 * rstep + (k0n)); \
        async16(&Bs[nb][(t + 768) * 8],  bP + 3 * rstep + (k0n)); \
        async16(&Bs[nb][(t + 1024) * 8], bP + 4 * rstep + (k0n)); \
        async16(&Bs[nb][(t + 1280) * 8], bP + 5 * rstep + (k0n)); \
    } while (0)

    const int NT = K >> 6;
    const int ch0 = (hi ^ (lr & 7)) * 8;
    const int ch1 = ((4 + hi) ^ (lr & 7)) * 8;

    short8 av[4], bv[6];

#define RD_AV(Ac, ch) do { \
        _Pragma("unroll") \
        for (int m = 0; m < 4; m++) \
            av[m] = *(const short8*)&(Ac)[(wr * 64 + m * 16 + lr) * 64 + (ch)]; \
    } while (0)
#define RD_BV(Bc, ch) do { \
        _Pragma("unroll") \
        for (int n = 0; n < 6; n++) \
            bv[n] = *(const short8*)&(Bc)[(wc * 96 + n * 16 + lr) * 64 + (ch)]; \
    } while (0)
#define MFMA_ALL() do { \
        _Pragma("unroll") \
        for (int m = 0; m < 4; m++) \
            _Pragma("unroll") \
            for (int n = 0; n < 6; n++) \
                acc[m][n] = __builtin_amdgcn_mfma_f32_16x16x32_bf16(av[m], bv[n], acc[m][n], 0, 0, 0); \
    } while (0)

    STAGE(0, 0);

    for (int kt = 0; kt < NT; ++kt) {
        const int cur = kt & 1;
        const unsigned short* __restrict__ Ac = &As[cur][0];
        const unsigned short* __restrict__ Bc = &Bs[cur][0];
        const bool more = (kt + 1 < NT);

        if (more) {
            STAGE(cur ^ 1, (kt + 1) << 6);
            asm volatile("s_waitcnt vmcnt(10)" ::: "memory");   // prior tile's 10 landed
        } else {
            asm volatile("s_waitcnt vmcnt(0)" ::: "memory");
        }
        __builtin_amdgcn_s_barrier();
        asm volatile("" ::: "memory");   // compiler fence: no LDS reads above barrier

        // compiler-scheduled: ds_reads interleave with MFMAs via counted lgkmcnt
        RD_AV(Ac, ch0); RD_BV(Bc, ch0);
        MFMA_ALL();
        RD_AV(Ac, ch1); RD_BV(Bc, ch1);
        MFMA_ALL();

        asm volatile("" ::: "memory");
        __builtin_amdgcn_s_barrier();   // all reads of buf[cur] done -> next iter may overwrite
    }
#undef STAGE
#undef RD_AV
#undef RD_BV
#undef MFMA_ALL

    const int par = lr & 1;
#pragma unroll
    for (int mi = 0; mi < 4; mi++) {
        const int row = row0 + wr * 64 + mi * 16 + hi * 4;
        const int tt = row & (TSEQ - 1);
        const int bb = row >> 11;
#pragma unroll
        for (int ni = 0; ni < 6; ni++) {
            const int col = col0 + wc * 96 + ni * 16 + lr;
            if (col < 2 * DMODEL) {
                const int pi = (col & 127) >> 1;
#pragma unroll
                for (int j = 0; j < 4; j++) {
                    const float2 cs = tab[(tt + j) * 64 + pi];
                    const float v = acc[mi][ni][j];
                    const float p = __shfl_xor(v, 1, 64);
                    const float o = par ? (p * cs.y + v * cs.x)
                                        : (v * cs.x - p * cs.y);
                    qkvb[(size_t)(row + j) * N + col] = f2bf(o);
                }
            } else {
                const int vcol = col - 2 * DMODEL;
                const int h = vcol >> 7, d = vcol & 127;
                uint2 pw;
                pw.x = (uint32_t)f2bf(acc[mi][ni][0]) | ((uint32_t)f2bf(acc[mi][ni][1]) << 16);
                pw.y = (uint32_t)f2bf(acc[mi][ni][2]) | ((uint32_t)f2bf(acc[mi][ni][3]) << 16);
                *(uint2*)&vt[(size_t)((bb * NHEADS + h) * DK + d) * TSEQ + tt] = pw;
            }
        }
    }
}

// ===================== output projection, 128x128 x 2-blocks/CU, compiler-scheduled =====================
__global__ __launch_bounds__(256, 2) void gemm_o_x(
    const unsigned short* __restrict__ A, const unsigned short* __restrict__ B,
    float* __restrict__ C)
{
    const int K = DMODEL, N = DMODEL;
    __shared__ unsigned short As[2][128 * 64];
    __shared__ unsigned short Bs[2][128 * 64];

    const int t = threadIdx.x;
    const int lane = t & 63, w = t >> 6;
    const int wr = w >> 1, wc = w & 1;
    const int lr = lane & 15, hi = lane >> 4;

    const int bid = (int)blockIdx.x;
    const int xcd = bid & 7, local = bid >> 3;
    const int row0 = (local & 31) * 128;
    const int col0 = ((xcd << 1) | (local >> 5)) * 128;

    const int rr = t >> 3;
    const int cc = ((t & 7) ^ (rr & 7)) << 3;
    const unsigned short* aP = A + (size_t)(row0 + rr) * K + cc;
    const unsigned short* bP = B + (size_t)(col0 + rr) * K + cc;
    const size_t rstep = (size_t)32 * K;

    floatx4 acc[4][4];
#pragma unroll
    for (int m = 0; m < 4; m++)
#pragma unroll
        for (int n = 0; n < 4; n++)
#pragma unroll
            for (int e = 0; e < 4; e++) acc[m][n][e] = 0.f;

#define STAGE(nb, k0n) do { \
        async16(&As[nb][t * 8],          aP + (k0n)); \
        async16(&As[nb][(t + 256) * 8],  aP + rstep + (k0n)); \
        async16(&As[nb][(t + 512) * 8],  aP + 2 * rstep + (k0n)); \
        async16(&As[nb][(t + 768) * 8],  aP + 3 * rstep + (k0n)); \
        async16(&Bs[nb][t * 8],          bP + (k0n)); \
        async16(&Bs[nb][(t + 256) * 8],  bP + rstep + (k0n)); \
        async16(&Bs[nb][(t + 512) * 8],  bP + 2 * rstep + (k0n)); \
        async16(&Bs[nb][(t + 768) * 8],  bP + 3 * rstep + (k0n)); \
    } while (0)

    const int NT = K >> 6;
    const int ch0 = (hi ^ (lr & 7)) * 8;
    const int ch1 = ((4 + hi) ^ (lr & 7)) * 8;

    short8 av[4], bv[4];

#define RD_AV(Ac, ch) do { \
        _Pragma("unroll") \
        for (int m = 0; m < 4; m++) \
            av[m] = *(const short8*)&(Ac)[(wr * 64 + m * 16 + lr) * 64 + (ch)]; \
    } while (0)
#define RD_BV(Bc, ch) do { \
        _Pragma("unroll") \
        for (int n = 0; n < 4; n++) \
            bv[n] = *(const short8*)&(Bc)[(wc * 64 + n * 16 + lr) * 64 + (ch)]; \
    } while (0)
#define MFMA_ALL() do { \
        _Pragma("unroll") \
        for (int m = 0; m < 4; m++) \
            _Pragma("unroll") \
            for (int n = 0; n < 4; n++) \
                acc[m][n] = __builtin_amdgcn_mfma_f32_16x16x32_bf16(av[m], bv[n], acc[m][n], 0, 0, 0); \
    } while (0)

    STAGE(0, 0);

    for (int kt = 0; kt < NT; ++kt) {
        const int cur = kt & 1;
        const unsigned short* __restrict__ Ac = &As[cur][0];
        const unsigned short* __restrict__ Bc = &Bs[cur][0];
        const bool more = (kt + 1 < NT);

        if (more) {
            STAGE(cur ^ 1, (kt + 1) << 6);
            asm volatile("s_waitcnt vmcnt(8)" ::: "memory");
        } else {
            asm volatile("s_waitcnt vmcnt(0)" ::: "memory");
        }
        __builtin_amdgcn_s_barrier();
        asm volatile("" ::: "memory");

        RD_AV(Ac, ch0); RD_BV(Bc, ch0);
        MFMA_ALL();
        RD_AV(Ac, ch1); RD_BV(Bc, ch1);
        MFMA_ALL();

        asm volatile("" ::: "memory");
        __builtin_amdgcn_s_barrier();
    }
#undef STAGE
#undef RD_AV
#undef RD_BV
#undef MFMA_ALL

#pragma unroll
    for (int mi = 0; mi < 4; mi++) {
        const int row = row0 + wr * 64 + mi * 16 + hi * 4;
#pragma unroll
        for (int ni = 0; ni < 4; ni++) {
            const int col = col0 + wc * 64 + ni * 16 + lr;
#pragma unroll
            for (int j = 0; j < 4; j++)
                C[(size_t)(row + j) * N + col] = acc[mi][ni][j];
        }
    }
}

// ===================== MFMA flash attention v7 (unchanged) =====================
__global__ __launch_bounds__(256, 2) void attn_mfma7_kernel(
    const unsigned short* __restrict__ qkvb, const unsigned short* __restrict__ vt,
    unsigned short* __restrict__ outb,
    const float* __restrict__ wo, unsigned short* __restrict__ wob)
{
    __shared__ unsigned short Ks[2][64 * 128];   // 32 KB
    __shared__ unsigned short Vs[2][128 * 64];   // 32 KB
    __shared__ unsigned short Ps[4][32 * 64];    // 16 KB

    const int t = threadIdx.x;
    const int lane = t & 63, w = t >> 6;
    const int lr = lane & 15, hi = lane >> 4;
    const int bid  = (int)blockIdx.x;

    // ---- fused Wo cast ----
    {
        const int ci = bid * 256 + t;
#pragma unroll
        for (int i = 0; i < 4; i++) {
            const int k = ci + i * 131072;
            const float4* p4 = reinterpret_cast<const float4*>(wo) + 2 * (size_t)k;
            const float4 a = p4[0], b = p4[1];
            uint4 o;
            o.x = (uint32_t)f2bf(a.x) | ((uint32_t)f2bf(a.y) << 16);
            o.y = (uint32_t)f2bf(a.z) | ((uint32_t)f2bf(a.w) << 16);
            o.z = (uint32_t)f2bf(b.x) | ((uint32_t)f2bf(b.y) << 16);
            o.w = (uint32_t)f2bf(b.z) | ((uint32_t)f2bf(b.w) << 16);
            *reinterpret_cast<uint4*>(wob + 8 * (size_t)k) = o;
        }
    }

    const int bh   = bid & 31;
    const int rest = bid >> 5;
    const int p    = (rest < 8) ? (rest >> 1) : (7 - ((rest - 8) >> 1));
    const int half = rest & 1;
    const int b = bh >> 4, h = bh & 15;
    const int chunk = (w < 2) ? p : (15 - p);
    const int q0w = chunk * 128 + half * 64 + (w & 1) * 32;
    const float scale2 = 0.08838834764831845f * 1.4426950408889634f;
    const float THR = 8.f * 1.4426950408889634f;
    const size_t QROW = 3 * DMODEL;

    const unsigned short* kg = qkvb + (size_t)b * TSEQ * QROW + DMODEL + h * DK;
    const unsigned short* vg = vt + (size_t)bh * DK * TSEQ;

    short8 qf[2][4];
    {
        const unsigned short* qbase = qkvb + (size_t)(b * TSEQ + q0w) * QROW + h * DK;
#pragma unroll
        for (int nt = 0; nt < 2; nt++)
#pragma unroll
            for (int ks = 0; ks < 4; ks++) {
                short8 raw = *(const short8*)(qbase + (size_t)(nt * 16 + lr) * QROW + ks * 32 + hi * 8);
                short8 sc;
#pragma unroll
                for (int e = 0; e < 8; e++)
                    sc[e] = (short)f2bf(bf2f((unsigned short)raw[e]) * scale2);
                qf[nt][ks] = sc;
            }
    }

    auto stageK = [&](int bufi, int kv0s) {
#pragma unroll
        for (int i = 0; i < 4; i++) {
            const int s = i * 256 + t;
            const int r = s >> 4;
            const int cc = (s & 15) ^ (r & 7);
            async16(&Ks[bufi][s * 8], kg + (size_t)(kv0s + r) * QROW + cc * 8);
        }
    };
    auto stageV = [&](int bufi, int kv0s) {
#pragma unroll
        for (int i = 0; i < 4; i++) {
            const int s = i * 256 + t;
            const int r = s >> 3;
            const int cc = (s & 7) ^ (r & 7);
            async16(&Vs[bufi][s * 8], vg + (size_t)r * TSEQ + kv0s + cc * 8);
        }
    };

    floatx4 accO[2][8];
#pragma unroll
    for (int nt = 0; nt < 2; nt++)
#pragma unroll
        for (int dt = 0; dt < 8; dt++)
#pragma unroll
            for (int e = 0; e < 4; e++) accO[nt][dt][e] = 0.f;
    float mrun[2] = {-1e30f, -1e30f};
    float lrun[2] = {0.f, 0.f};

    const int ntiles = (16 - p) * 2;
    int buf = 0;

    stageK(0, 0);
    stageV(0, 0);
    asm volatile("s_waitcnt vmcnt(0)" ::: "memory");
    __builtin_amdgcn_s_barrier();

    const int pswz = (lr & 7) << 1;

    for (int ti = 0; ti < ntiles; ti++) {
        const int kv0 = ti * 64;
        if (ti + 1 < ntiles) {
            stageK(buf ^ 1, kv0 + 64);
            stageV(buf ^ 1, kv0 + 64);
        }

        const bool active = (kv0 <= q0w + 31);

        if (active) {
            float al[2] = {1.f, 1.f};
            floatx4 st[4][2];
#pragma unroll
            for (int mt = 0; mt < 4; mt++)
#pragma unroll
                for (int nt = 0; nt < 2; nt++)
#pragma unroll
                    for (int e = 0; e < 4; e++) st[mt][nt][e] = 0.f;
            __builtin_amdgcn_s_setprio(1);
#pragma unroll
            for (int mt = 0; mt < 4; mt++) {
                const int r = mt * 16 + lr;
#pragma unroll
                for (int ks = 0; ks < 4; ks++) {
                    const int ch = (ks * 4 + hi) ^ (r & 7);
                    const short8 kf = *(const short8*)&Ks[buf][(r * 16 + ch) * 8];
                    st[mt][0] = __builtin_amdgcn_mfma_f32_16x16x32_bf16(kf, qf[0][ks], st[mt][0], 0, 0, 0);
                    st[mt][1] = __builtin_amdgcn_mfma_f32_16x16x32_bf16(kf, qf[1][ks], st[mt][1], 0, 0, 0);
                }
            }
            __builtin_amdgcn_s_setprio(0);
            if (kv0 + 63 > q0w) {
#pragma unroll
                for (int nt = 0; nt < 2; nt++) {
                    const int qg = q0w + nt * 16 + lr;
#pragma unroll
                    for (int mt = 0; mt < 4; mt++)
#pragma unroll
                        for (int rg = 0; rg < 4; rg++) {
                            const int kvg = kv0 + mt * 16 + hi * 4 + rg;
                            if (kvg > qg) st[mt][nt][rg] = -1e30f;
                        }
                }
            }
            float pm[2];
#pragma unroll
            for (int nt = 0; nt < 2; nt++) {
                float m = -1e30f;
#pragma unroll
                for (int mt = 0; mt < 4; mt++)
#pragma unroll
                    for (int rg = 0; rg < 4; rg++) m = fmaxf(m, st[mt][nt][rg]);
                m = fmaxf(m, __shfl_xor(m, 16, 64));
                m = fmaxf(m, __shfl_xor(m, 32, 64));
                pm[nt] = m;
            }
            if (__any((pm[0] > mrun[0] + THR) || (pm[1] > mrun[1] + THR))) {
#pragma unroll
                for (int nt = 0; nt < 2; nt++) {
                    const float mn = fmaxf(mrun[nt], pm[nt]);
                    al[nt] = fexp2(mrun[nt] - mn);
                    mrun[nt] = mn;
                }
#pragma unroll
                for (int rg = 0; rg < 4; rg++) {
                    const float a0 = __shfl(al[0], hi * 4 + rg, 64);
                    const float a1 = __shfl(al[1], hi * 4 + rg, 64);
#pragma unroll
                    for (int dt = 0; dt < 8; dt++) {
                        accO[0][dt][rg] *= a0;
                        accO[1][dt][rg] *= a1;
                    }
                }
            }
#pragma unroll
            for (int nt = 0; nt < 2; nt++) {
                float ls = 0.f;
                const int prow = nt * 16 + lr;
#pragma unroll
                for (int mt = 0; mt < 4; mt++) {
                    float pv[4];
#pragma unroll
                    for (int rg = 0; rg < 4; rg++) {
                        pv[rg] = fexp2(st[mt][nt][rg] - mrun[nt]);
                        ls += pv[rg];
                    }
                    uint2 pw;
                    pw.x = (uint32_t)f2bf(pv[0]) | ((uint32_t)f2bf(pv[1]) << 16);
                    pw.y = (uint32_t)f2bf(pv[2]) | ((uint32_t)f2bf(pv[3]) << 16);
                    const int chunkx = (mt * 4 + hi) ^ pswz;
                    *(uint2*)&Ps[w][prow * 64 + chunkx * 4] = pw;
                }
                ls += __shfl_xor(ls, 16, 64);
                ls += __shfl_xor(ls, 32, 64);
                lrun[nt] = lrun[nt] * al[nt] + ls;
            }

            __builtin_amdgcn_s_setprio(1);
#pragma unroll
            for (int ks2 = 0; ks2 < 2; ks2++) {
                const int chp = ((ks2 * 8 + hi * 2) ^ pswz) * 4;
                const short8 pa0 = *(const short8*)&Ps[w][(0 * 16 + lr) * 64 + chp];
                const short8 pa1 = *(const short8*)&Ps[w][(1 * 16 + lr) * 64 + chp];
#pragma unroll
                for (int dt = 0; dt < 8; dt++) {
                    const int r = dt * 16 + lr;
                    const int ch = (ks2 * 4 + hi) ^ (r & 7);
                    const short8 vf = *(const short8*)&Vs[buf][(r * 8 + ch) * 8];
                    accO[0][dt] = __builtin_amdgcn_mfma_f32_16x16x32_bf16(pa0, vf, accO[0][dt], 0, 0, 0);
                    accO[1][dt] = __builtin_amdgcn_mfma_f32_16x16x32_bf16(pa1, vf, accO[1][dt], 0, 0, 0);
                }
            }
            __builtin_amdgcn_s_setprio(0);
        }

        asm volatile("s_waitcnt vmcnt(0)" ::: "memory");
        __builtin_amdgcn_s_barrier();
        buf ^= 1;
    }

#pragma unroll
    for (int nt = 0; nt < 2; nt++) {
        const float lv_own = 1.f / lrun[nt];
#pragma unroll
        for (int rg = 0; rg < 4; rg++) {
            const float lv = __shfl(lv_own, hi * 4 + rg, 64);
            unsigned short* orow = outb + (size_t)(b * TSEQ + q0w + nt * 16 + hi * 4 + rg) * DMODEL + h * DK;
#pragma unroll
            for (int dt = 0; dt < 8; dt++)
                orow[dt * 16 + lr] = f2bf(accO[nt][dt][rg] * lv);
        }
    }
}

// ===================== launch =====================
extern "C" void kernel_launch(void* const* d_in, const int* in_sizes, int n_in,
                              void* d_out, int out_size, void* d_ws, size_t ws_size,
                              hipStream_t stream)
{
    const float* x    = (const float*)d_in[0];
    const int*   pos  = (const int*)d_in[1];
    const float* Wqkv = (const float*)d_in[2];
    const float* Wo   = (const float*)d_in[3];
    float* out = (float*)d_out;

    unsigned short* qkvb  = (unsigned short*)d_ws;
    unsigned short* vtb   = qkvb + (size_t)25165824;
    unsigned short* xb    = vtb + (size_t)8388608;
    unsigned short* attnb = xb;                         // alias: xb dead after GEMM1
    unsigned short* wqkvb = xb + (size_t)8388608;
    unsigned short* wob   = wqkvb + (size_t)12582912;
    float2* tab = (float2*)(wob + (size_t)4194304);

    // cast (x, Wqkv) + fast RoPE table
    cast_rope_kernel<<<10752, 256, 0, stream>>>(x, Wqkv, pos, xb, wqkvb, tab);

    // fused QKV projection + RoPE + V-transpose (4096 x 6144 x 2048)
    gemm_qkv_x<<<dim3(1024), 256, 0, stream>>>(xb, wqkvb, qkvb, vtb, tab);

    // CU-balanced paired attention (+ fused Wo cast): 512 blocks x 256 thr
    attn_mfma7_kernel<<<dim3(512), 256, 0, stream>>>(qkvb, vtb, attnb, Wo, wob);

    // out = attn @ Wo^T (4096 x 2048 x 2048), 512 tiles of 128x128
    gemm_o_x<<<dim3(512), 256, 0, stream>>>(attnb, wob, out);
}